// Round 15
// baseline (310.882 us; speedup 1.0000x reference)
//
#include <hip/hip_runtime.h>
#include <math.h>
#include <stdint.h>

// Problem constants: B=8, N=1024, C=1024, H=16, Dh=64
#define SEQ   1024
#define BATCH 8
#define CDIM  1024
#define HEADS 16
#define DHEAD 64

typedef __bf16 bf16;
typedef _Float16 f16;
typedef __attribute__((ext_vector_type(8))) _Float16 f16x8;
typedef __attribute__((ext_vector_type(4))) float f32x4;

// async global->LDS, 16B per lane. LDS dest = wave-uniform base + lane*16.
static __device__ __forceinline__ void gl16(const void* g, void* l) {
    __builtin_amdgcn_global_load_lds(
        (const __attribute__((address_space(1))) void*)(uintptr_t)g,
        (__attribute__((address_space(3))) void*)(uintptr_t)l,
        16, 0, 0);
}

// ===========================================================================
// cvt_all: fused fp32 -> fp16 for x (1048576 vec8), w_in (393216), w_out
// (131072). One launch instead of three.
// ===========================================================================
__global__ __launch_bounds__(256)
void cvt_all(const float* __restrict__ x,  const float* __restrict__ wi,
             const float* __restrict__ wo, f16* __restrict__ xo,
             f16* __restrict__ wio, f16* __restrict__ woo)
{
    const int N1 = 1048576, N2 = 393216;   // vec8 counts for x, w_in
    const int NT = N1 + N2 + 131072;
    int i = blockIdx.x * blockDim.x + threadIdx.x;
    const int stride = gridDim.x * blockDim.x;
    for (; i < NT; i += stride) {
        const float* src; f16* dst; int off;
        if (i < N1)            { src = x;  dst = xo;  off = i; }
        else if (i < N1 + N2)  { src = wi; dst = wio; off = i - N1; }
        else                   { src = wo; dst = woo; off = i - N1 - N2; }
        const f32x4 v0 = *(const f32x4*)(src + (size_t)off * 8);
        const f32x4 v1 = *(const f32x4*)(src + (size_t)off * 8 + 4);
        f16x8 o;
#pragma unroll
        for (int j = 0; j < 4; j++) {
            o[j]     = (f16)v0[j];
            o[j + 4] = (f16)v1[j];
        }
        *(f16x8*)(dst + (size_t)off * 8) = o;
    }
}

// ===========================================================================
// Wide fp16 MFMA GEMM: BM=128 x BN=256, BK=32, 4 waves (2x2), per-wave
// 64x128 output (acc[4][8] -> 32 MFMA/K-step).  2-buffer counted-vmcnt
// pipeline (depth-1 prefetch): per iter { STAGE(next) ; vmcnt(6) ; barrier ;
// COMPUTE(cur) ; barrier }.  Loads stay in flight across barriers; buffer
// overwritten only after the end-barrier proving all reads of it completed.
// LDS 2x(8KB A + 16KB B) = 48KB -> 3 blocks/CU; QKV grid 768 blocks =
// exactly one full residency round (tail eliminated vs r13's 1.5 rounds).
// MODE 0: fp32 row-major store (+bias) to out0 [M][Ncols].
// MODE 1: QKV scatter as fp16 (q x0.125 -> qg[BH][N][64],
//         k -> kgp[BH][N][64], v transposed -> vgp[BH][64][N]).
// ===========================================================================
template<int MODE>
__global__ __launch_bounds__(256, 3)
void gemm_wide(const f16* __restrict__ Ag, const f16* __restrict__ Bg,
               const float* __restrict__ bias, float* __restrict__ out0,
               f16* __restrict__ qg, f16* __restrict__ kgp,
               f16* __restrict__ vgp, int Ncols, int K)
{
    __shared__ f16 As[2][4][128][8];   // 8KB per buffer; byte = (ks*128+row)*16
    __shared__ f16 Bs[2][4][256][8];   // 16KB per buffer; byte = (ks*256+row)*16

    const int m0 = blockIdx.y * 128;
    const int n0 = blockIdx.x * 256;

    const int tid  = threadIdx.x;
    const int wid  = tid >> 6;
    const int lane = tid & 63;
    const int wr   = (wid >> 1) * 64;    // 0/64 (M)
    const int wc   = (wid & 1) * 128;    // 0/128 (N)
    const int l16  = lane & 15;
    const int kgf  = lane >> 4;

    // A staging: chunk c0 = tid -> (ks=tid>>7, row=tid&127); c1 = c0 + 256
    const int akg = tid >> 7, arow = tid & 127;
    const f16* aP = Ag + (size_t)(m0 + arow) * K + akg * 8;
    // B staging: row = tid, ks = j (0..3)
    const f16* bP = Bg + (size_t)(n0 + tid) * K;
    const int loff = wid << 10;          // lane-linear wave base within a chunk set

#define STAGE(buf, kt)                                               \
    do {                                                             \
        gl16(aP + (kt),      (char*)As[buf] + loff);                 \
        gl16(aP + (kt) + 16, (char*)As[buf] + loff + 4096);          \
        gl16(bP + (kt),      (char*)Bs[buf] + loff);                 \
        gl16(bP + (kt) + 8,  (char*)Bs[buf] + loff + 4096);         \
        gl16(bP + (kt) + 16, (char*)Bs[buf] + loff + 8192);         \
        gl16(bP + (kt) + 24, (char*)Bs[buf] + loff + 12288);        \
    } while (0)

#define COMPUTE(buf)                                                         \
    do {                                                                     \
        f16x8 fa[4], fb[8];                                                  \
        _Pragma("unroll")                                                    \
        for (int i = 0; i < 4; i++)                                          \
            fa[i] = *(const f16x8*)&As[buf][kgf][wr + i * 16 + l16][0];      \
        _Pragma("unroll")                                                    \
        for (int j = 0; j < 8; j++)                                          \
            fb[j] = *(const f16x8*)&Bs[buf][kgf][wc + j * 16 + l16][0];      \
        _Pragma("unroll")                                                    \
        for (int i = 0; i < 4; i++)                                          \
            _Pragma("unroll")                                                \
            for (int j = 0; j < 8; j++)                                      \
                acc[i][j] = __builtin_amdgcn_mfma_f32_16x16x32_f16(          \
                    fa[i], fb[j], acc[i][j], 0, 0, 0);                       \
    } while (0)

    f32x4 acc[4][8];
#pragma unroll
    for (int i = 0; i < 4; i++)
#pragma unroll
        for (int j = 0; j < 8; j++) acc[i][j] = (f32x4)0.f;

    const int T = K >> 5;   // 32 K-tiles

    STAGE(0, 0);

    int cur = 0;
    for (int t = 0; t < T; t++) {
        if (t + 1 < T) {
            STAGE(cur ^ 1, (t + 1) << 5);   // outstanding <= 12
            asm volatile("s_waitcnt vmcnt(6)" ::: "memory");   // tile t landed
        } else {
            asm volatile("s_waitcnt vmcnt(0)" ::: "memory");
        }
        __builtin_amdgcn_sched_barrier(0);
        __builtin_amdgcn_s_barrier();       // all waves' tile-t writes visible
        __builtin_amdgcn_sched_barrier(0);
        COMPUTE(cur);
        __builtin_amdgcn_sched_barrier(0);
        __builtin_amdgcn_s_barrier();       // buf[cur] reusable next iter
        cur ^= 1;
    }

#undef STAGE
#undef COMPUTE

    // epilogue. D layout (verified r4): col=lane&15, row=(lane>>4)*4+reg.
#pragma unroll
    for (int j = 0; j < 8; j++) {
        const int d  = n0 + wc + j * 16 + l16;
        const float bv = bias[d];
        int s = 0, hh = 0, dh = 0;
        if (MODE == 1) {
            s  = d >> 10;
            hh = (d >> 6) & 15;
            dh = d & 63;
        }
#pragma unroll
        for (int i = 0; i < 4; i++) {
            const int mbase = m0 + wr + i * 16 + (lane >> 4) * 4;
#pragma unroll
            for (int r = 0; r < 4; r++) {
                const float v = acc[i][j][r] + bv;
                const int m = mbase + r;
                if (MODE == 0) {
                    out0[(size_t)m * Ncols + d] = v;
                } else {
                    const int b = m >> 10, n = m & 1023;
                    const size_t bho = (size_t)((b << 4) + hh) << 16;
                    if (s == 0)
                        qg[bho + ((size_t)n << 6) + dh] = (f16)(v * 0.125f);
                    else if (s == 1)
                        kgp[bho + ((size_t)n << 6) + dh] = (f16)v;
                    else
                        vgp[bho + ((size_t)dh << 10) + n] = (f16)v;
                }
            }
        }
    }
}

// ===========================================================================
// MFMA flash attention (structure verified r6/r8 -- frozen). One block =
// 64 q-rows of one (b,h); 4 waves x 16 q-rows. fp16 MFMA QK^T/PV, fp32
// online softmax. Output plain fp16 O to [B][N][C].
// ===========================================================================
__global__ __launch_bounds__(256, 4)
void attn_mfma(const f16* __restrict__ qf, const f16* __restrict__ kf,
               const f16* __restrict__ vtf, f16* __restrict__ og)
{
    __shared__ f16 Kl[8][64][8];    // [d/8][kcol][8]
    __shared__ f16 Vl[8][64][8];    // [k/8][drow][8]
    __shared__ f16 Pl[4][16][72];   // per-wave P: [wave][qrow][kcol], stride 72

    const int tid  = threadIdx.x;
    const int wid  = tid >> 6;
    const int lane = tid & 63;
    const int l16  = lane & 15;
    const int kg   = lane >> 4;      // 0..3
    const int bh   = blockIdx.y;
    const int q0   = blockIdx.x << 6;

    const size_t bhoff = (size_t)bh << 16;   // bh * 1024 * 64
    const f16* qb = qf  + bhoff;
    const f16* kb = kf  + bhoff;
    const f16* vb = vtf + bhoff;

    // Q fragments: row = q0+wid*16+l16, d = kg*8 + j (+32 for second half)
    f16x8 qfr[2];
    {
        const f16* qrow = qb + ((size_t)(q0 + wid * 16 + l16) << 6);
        qfr[0] = *(const f16x8*)(qrow + kg * 8);
        qfr[1] = *(const f16x8*)(qrow + 32 + kg * 8);
    }

    // staging assignment: 512 chunks of 16B per buffer, 2 per thread
    const int c0 = tid,        col0 = c0 & 63, slot0 = c0 >> 6;
    const int c1 = tid + 256,  col1 = c1 & 63, slot1 = c1 >> 6;

    float mrow[4], lrow[4];
    f32x4 accO[4];
#pragma unroll
    for (int r = 0; r < 4; r++) { mrow[r] = -INFINITY; lrow[r] = 0.f; }
#pragma unroll
    for (int t = 0; t < 4; t++) accO[t] = (f32x4)0.f;

    // prologue: k-tile 0 loads
    f16x8 rk0 = *(const f16x8*)(kb + ((size_t)col0 << 6) + slot0 * 8);
    f16x8 rk1 = *(const f16x8*)(kb + ((size_t)col1 << 6) + slot1 * 8);
    f16x8 rv0 = *(const f16x8*)(vb + ((size_t)col0 << 10) + slot0 * 8);
    f16x8 rv1 = *(const f16x8*)(vb + ((size_t)col1 << 10) + slot1 * 8);

    for (int kt = 0; kt < 16; kt++) {
        __syncthreads();   // previous iter's K/V fragment reads complete
        *(f16x8*)&Kl[slot0][col0][0] = rk0;
        *(f16x8*)&Kl[slot1][col1][0] = rk1;
        *(f16x8*)&Vl[slot0][col0][0] = rv0;
        *(f16x8*)&Vl[slot1][col1][0] = rv1;
        __syncthreads();

        // issue next tile's global loads; latency hides under compute
        if (kt < 15) {
            const int n1 = (kt + 1) << 6;
            rk0 = *(const f16x8*)(kb + ((size_t)(n1 + col0) << 6) + slot0 * 8);
            rk1 = *(const f16x8*)(kb + ((size_t)(n1 + col1) << 6) + slot1 * 8);
            rv0 = *(const f16x8*)(vb + ((size_t)col0 << 10) + n1 + slot0 * 8);
            rv1 = *(const f16x8*)(vb + ((size_t)col1 << 10) + n1 + slot1 * 8);
        }

        // ---- QK^T: wave's 16 rows x 64 cols, 4 col-tiles x 2 d-halves ----
        f32x4 accS[4];
#pragma unroll
        for (int t = 0; t < 4; t++) accS[t] = (f32x4)0.f;
#pragma unroll
        for (int t = 0; t < 4; t++) {
            const f16x8 kf0 = *(const f16x8*)&Kl[kg][t * 16 + l16][0];
            const f16x8 kf1 = *(const f16x8*)&Kl[4 + kg][t * 16 + l16][0];
            accS[t] = __builtin_amdgcn_mfma_f32_16x16x32_f16(qfr[0], kf0, accS[t], 0, 0, 0);
            accS[t] = __builtin_amdgcn_mfma_f32_16x16x32_f16(qfr[1], kf1, accS[t], 0, 0, 0);
        }

        // ---- online softmax; rows r -> q-row 4*kg + r, register-local ----
#pragma unroll
        for (int r = 0; r < 4; r++) {
            float sm = fmaxf(fmaxf(accS[0][r], accS[1][r]),
                             fmaxf(accS[2][r], accS[3][r]));
            sm = fmaxf(sm, __shfl_xor(sm, 1, 16));
            sm = fmaxf(sm, __shfl_xor(sm, 2, 16));
            sm = fmaxf(sm, __shfl_xor(sm, 4, 16));
            sm = fmaxf(sm, __shfl_xor(sm, 8, 16));
            const float mn = fmaxf(mrow[r], sm);
            const float al = __expf(mrow[r] - mn);
            float p0 = __expf(accS[0][r] - mn);
            float p1 = __expf(accS[1][r] - mn);
            float p2 = __expf(accS[2][r] - mn);
            float p3 = __expf(accS[3][r] - mn);
            float rs = (p0 + p1) + (p2 + p3);
            rs += __shfl_xor(rs, 1, 16);
            rs += __shfl_xor(rs, 2, 16);
            rs += __shfl_xor(rs, 4, 16);
            rs += __shfl_xor(rs, 8, 16);
            lrow[r] = lrow[r] * al + rs;
            mrow[r] = mn;
            accO[0][r] *= al;
            accO[1][r] *= al;
            accO[2][r] *= al;
            accO[3][r] *= al;
            const int prow = kg * 4 + r;
            Pl[wid][prow][l16]      = (f16)p0;
            Pl[wid][prow][16 + l16] = (f16)p1;
            Pl[wid][prow][32 + l16] = (f16)p2;
            Pl[wid][prow][48 + l16] = (f16)p3;
        }

        // ---- PV: O(16x64) += P(16x64) * V(64x64), via Vt fragments ----
#pragma unroll
        for (int h = 0; h < 2; h++) {
            const f16x8 pa = *(const f16x8*)&Pl[wid][l16][h * 32 + kg * 8];
#pragma unroll
            for (int t = 0; t < 4; t++) {
                const f16x8 vf = *(const f16x8*)&Vl[h * 4 + kg][t * 16 + l16][0];
                accO[t] = __builtin_amdgcn_mfma_f32_16x16x32_f16(pa, vf, accO[t], 0, 0, 0);
            }
        }
    }

    // ---- epilogue: normalize, fp16 store to [B][N][C] ----
    const int b = bh >> 4, hh = bh & 15;
#pragma unroll
    for (int r = 0; r < 4; r++) {
        const float inv = 1.0f / lrow[r];
        const int n = q0 + wid * 16 + kg * 4 + r;
        const size_t base = ((((size_t)b << 10) + n) << 10) + hh * 64;
#pragma unroll
        for (int t = 0; t < 4; t++)
            og[base + t * 16 + l16] = (f16)(accO[t][r] * inv);
    }
}

// ===========================================================================
// Fallback fp32 path (baseline, audited) — used only if ws_size < 96MB.
// ===========================================================================
#define TILE 128
#define KB   16
#define LSTR (TILE + 4)

template<int MODE>
__global__ __launch_bounds__(256, 2)
void gemm_bt(const float* __restrict__ A, const float* __restrict__ Bm,
             const float* __restrict__ bias, float* __restrict__ out0,
             float* __restrict__ qg, float* __restrict__ kg, float* __restrict__ vg,
             int M, int Ncols, int K)
{
    __shared__ float As[KB][LSTR];
    __shared__ float Bs[KB][LSTR];

    const int tid = threadIdx.x;
    const int tr  = tid >> 4;
    const int tc  = tid & 15;
    const int m0  = blockIdx.y * TILE;
    const int n0  = blockIdx.x * TILE;

    const int lrow = tid >> 2;
    const int lcol = (tid & 3) << 2;

    const float* Ap = A  + (size_t)(m0 + lrow) * K + lcol;
    const float* Bp = Bm + (size_t)(n0 + lrow) * K + lcol;
    const size_t rstep = (size_t)64 * K;

    float acc[8][8];
#pragma unroll
    for (int i = 0; i < 8; i++)
#pragma unroll
        for (int j = 0; j < 8; j++) acc[i][j] = 0.f;

    for (int kt = 0; kt < K; kt += KB) {
        float4 a0 = *(const float4*)(Ap + kt);
        float4 a1 = *(const float4*)(Ap + rstep + kt);
        float4 b0 = *(const float4*)(Bp + kt);
        float4 b1 = *(const float4*)(Bp + rstep + kt);
        __syncthreads();
        As[lcol + 0][lrow]      = a0.x;
        As[lcol + 1][lrow]      = a0.y;
        As[lcol + 2][lrow]      = a0.z;
        As[lcol + 3][lrow]      = a0.w;
        As[lcol + 0][lrow + 64] = a1.x;
        As[lcol + 1][lrow + 64] = a1.y;
        As[lcol + 2][lrow + 64] = a1.z;
        As[lcol + 3][lrow + 64] = a1.w;
        Bs[lcol + 0][lrow]      = b0.x;
        Bs[lcol + 1][lrow]      = b0.y;
        Bs[lcol + 2][lrow]      = b0.z;
        Bs[lcol + 3][lrow]      = b0.w;
        Bs[lcol + 0][lrow + 64] = b1.x;
        Bs[lcol + 1][lrow + 64] = b1.y;
        Bs[lcol + 2][lrow + 64] = b1.z;
        Bs[lcol + 3][lrow + 64] = b1.w;
        __syncthreads();
#pragma unroll
        for (int kk = 0; kk < KB; kk++) {
            float ar[8], br[8];
            *(float4*)&ar[0] = *(const float4*)&As[kk][tr << 2];
            *(float4*)&ar[4] = *(const float4*)&As[kk][64 + (tr << 2)];
            *(float4*)&br[0] = *(const float4*)&Bs[kk][tc << 2];
            *(float4*)&br[4] = *(const float4*)&Bs[kk][64 + (tc << 2)];
#pragma unroll
            for (int i = 0; i < 8; i++)
#pragma unroll
                for (int j = 0; j < 8; j++)
                    acc[i][j] = fmaf(ar[i], br[j], acc[i][j]);
        }
    }

#pragma unroll
    for (int rg = 0; rg < 2; rg++) {
#pragma unroll
        for (int ri = 0; ri < 4; ri++) {
            const int m = m0 + rg * 64 + (tr << 2) + ri;
#pragma unroll
            for (int cg = 0; cg < 2; cg++) {
                const int d = n0 + cg * 64 + (tc << 2);
                const float4 bb = *(const float4*)&bias[d];
                float v0 = acc[rg * 4 + ri][cg * 4 + 0] + bb.x;
                float v1 = acc[rg * 4 + ri][cg * 4 + 1] + bb.y;
                float v2 = acc[rg * 4 + ri][cg * 4 + 2] + bb.z;
                float v3 = acc[rg * 4 + ri][cg * 4 + 3] + bb.w;
                if (MODE == 0) {
                    *(float4*)&out0[(size_t)m * Ncols + d] = make_float4(v0, v1, v2, v3);
                } else {
                    const int s  = d >> 10;
                    const int h  = (d >> 6) & 15;
                    const int dh = d & 63;
                    const int b  = m >> 10;
                    const int n  = m & 1023;
                    float* dst = (s == 0) ? qg : ((s == 1) ? kg : vg);
                    if (s == 0) { v0 *= 0.125f; v1 *= 0.125f; v2 *= 0.125f; v3 *= 0.125f; }
                    const size_t idx = (((size_t)((b << 4) + h) << 10) + n) * 64 + dh;
                    *(float4*)&dst[idx] = make_float4(v0, v1, v2, v3);
                }
            }
        }
    }
}

__global__ __launch_bounds__(256, 2)
void attn_flash_f32(const float* __restrict__ qg, const float* __restrict__ kg,
                    const float* __restrict__ vg, float* __restrict__ og)
{
    __shared__ float Qs[64][68];
    __shared__ float KPs[64][68];
    __shared__ float Vs[64][68];

    const int tid = threadIdx.x;
    const int tr  = tid >> 4;
    const int tc  = tid & 15;
    const int bh  = blockIdx.y;
    const int q0  = blockIdx.x << 6;

    const float* qb = qg + ((size_t)bh * SEQ + q0) * DHEAD;
    const float* kb = kg + (size_t)bh * SEQ * DHEAD;
    const float* vb = vg + (size_t)bh * SEQ * DHEAD;

    const int lr = tid >> 4;
    const int lc = (tid & 15) << 2;

#pragma unroll
    for (int i = 0; i < 4; i++) {
        const int r = lr + (i << 4);
        float4 t = *(const float4*)(qb + r * 64 + lc);
        Qs[lc + 0][r] = t.x;
        Qs[lc + 1][r] = t.y;
        Qs[lc + 2][r] = t.z;
        Qs[lc + 3][r] = t.w;
    }

    float m[4], l[4], acc[4][4];
#pragma unroll
    for (int i = 0; i < 4; i++) {
        m[i] = -INFINITY; l[i] = 0.f;
#pragma unroll
        for (int j = 0; j < 4; j++) acc[i][j] = 0.f;
    }

    for (int kt = 0; kt < 16; kt++) {
        __syncthreads();
        const float* kbt = kb + (size_t)(kt << 6) * 64;
        const float* vbt = vb + (size_t)(kt << 6) * 64;
#pragma unroll
        for (int i = 0; i < 4; i++) {
            const int r = lr + (i << 4);
            float4 t = *(const float4*)(kbt + r * 64 + lc);
            KPs[lc + 0][r] = t.x;
            KPs[lc + 1][r] = t.y;
            KPs[lc + 2][r] = t.z;
            KPs[lc + 3][r] = t.w;
            float4 tv = *(const float4*)(vbt + r * 64 + lc);
            *(float4*)&Vs[r][lc] = tv;
        }
        __syncthreads();

        float s[4][4];
#pragma unroll
        for (int i = 0; i < 4; i++)
#pragma unroll
            for (int j = 0; j < 4; j++) s[i][j] = 0.f;
#pragma unroll 4
        for (int d = 0; d < 64; d++) {
            float qa[4], ka[4];
            *(float4*)qa = *(const float4*)&Qs[d][tr << 2];
            *(float4*)ka = *(const float4*)&KPs[d][tc << 2];
#pragma unroll
            for (int ri = 0; ri < 4; ri++)
#pragma unroll
                for (int ci = 0; ci < 4; ci++)
                    s[ri][ci] = fmaf(qa[ri], ka[ci], s[ri][ci]);
        }
        __syncthreads();

#pragma unroll
        for (int ri = 0; ri < 4; ri++) {
            float tm = fmaxf(fmaxf(s[ri][0], s[ri][1]), fmaxf(s[ri][2], s[ri][3]));
            tm = fmaxf(tm, __shfl_xor(tm, 1, 16));
            tm = fmaxf(tm, __shfl_xor(tm, 2, 16));
            tm = fmaxf(tm, __shfl_xor(tm, 4, 16));
            tm = fmaxf(tm, __shfl_xor(tm, 8, 16));
            const float mn = fmaxf(m[ri], tm);
            const float alpha = __expf(m[ri] - mn);
            const float p0 = __expf(s[ri][0] - mn);
            const float p1 = __expf(s[ri][1] - mn);
            const float p2 = __expf(s[ri][2] - mn);
            const float p3 = __expf(s[ri][3] - mn);
            float rs = (p0 + p1) + (p2 + p3);
            rs += __shfl_xor(rs, 1, 16);
            rs += __shfl_xor(rs, 2, 16);
            rs += __shfl_xor(rs, 4, 16);
            rs += __shfl_xor(rs, 8, 16);
            l[ri] = l[ri] * alpha + rs;
            m[ri] = mn;
            acc[ri][0] *= alpha; acc[ri][1] *= alpha;
            acc[ri][2] *= alpha; acc[ri][3] *= alpha;
            *(float4*)&KPs[(tr << 2) + ri][tc << 2] = make_float4(p0, p1, p2, p3);
        }
        __syncthreads();

#pragma unroll 4
        for (int c = 0; c < 64; c += 4) {
            float pr[4][4], vv[4][4];
            *(float4*)pr[0] = *(const float4*)&KPs[(tr << 2) + 0][c];
            *(float4*)pr[1] = *(const float4*)&KPs[(tr << 2) + 1][c];
            *(float4*)pr[2] = *(const float4*)&KPs[(tr << 2) + 2][c];
            *(float4*)pr[3] = *(const float4*)&KPs[(tr << 2) + 3][c];
            *(float4*)vv[0] = *(const float4*)&Vs[c + 0][tc << 2];
            *(float4*)vv[1] = *(const float4*)&Vs[c + 1][tc << 2];
            *(float4*)vv[2] = *(const float4*)&Vs[c + 2][tc << 2];
            *(float4*)vv[3] = *(const float4*)&Vs[c + 3][tc << 2];
#pragma unroll
            for (int ri = 0; ri < 4; ri++)
#pragma unroll
                for (int j = 0; j < 4; j++) {
                    float a = acc[ri][j];
                    a = fmaf(pr[ri][0], vv[0][j], a);
                    a = fmaf(pr[ri][1], vv[1][j], a);
                    a = fmaf(pr[ri][2], vv[2][j], a);
                    a = fmaf(pr[ri][3], vv[3][j], a);
                    acc[ri][j] = a;
                }
        }
    }

    const int b = bh >> 4, h = bh & 15;
#pragma unroll
    for (int ri = 0; ri < 4; ri++) {
        const float inv = 1.0f / l[ri];
        const int n = q0 + (tr << 2) + ri;
        const size_t idx = (((size_t)b * SEQ + n) << 10) + (h << 6) + (tc << 2);
        *(float4*)&og[idx] = make_float4(acc[ri][0] * inv, acc[ri][1] * inv,
                                         acc[ri][2] * inv, acc[ri][3] * inv);
    }
}

// ===========================================================================
extern "C" void kernel_launch(void* const* d_in, const int* in_sizes, int n_in,
                              void* d_out, int out_size, void* d_ws, size_t ws_size,
                              hipStream_t stream)
{
    const float* x     = (const float*)d_in[0];   // [8,1024,1024]
    const float* w_in  = (const float*)d_in[1];   // [3072,1024]
    const float* b_in  = (const float*)d_in[2];   // [3072]
    const float* w_out = (const float*)d_in[3];   // [1024,1024]
    const float* b_out = (const float*)d_in[4];   // [1024]
    float* out = (float*)d_out;                   // [8,1024,1024]
    (void)in_sizes; (void)n_in; (void)out_size;

    const size_t MB  = 1024 * 1024;
    const size_t per = (size_t)BATCH * HEADS * SEQ * DHEAD;  // 8M elements
    const int    M   = BATCH * SEQ;                          // 8192
    char* ws = (char*)d_ws;

    if (ws_size >= 96 * MB) {
        // --- fp16 MFMA path ---
        f16* qf16  = (f16*)(ws + 0 * MB);    // 16MB [BH][N][64]
        f16* kf16  = (f16*)(ws + 16 * MB);   // 16MB [BH][N][64]
        f16* vtf16 = (f16*)(ws + 32 * MB);   // 16MB [BH][64][N]
        f16* xf16  = (f16*)(ws + 48 * MB);   // 16MB (dead after QKV GEMM)
        f16* of16  = xf16;                   // aliased: born after attention
        f16* wif16 = (f16*)(ws + 64 * MB);   // 6MB
        f16* wof16 = (f16*)(ws + 70 * MB);   // 2MB -> 72MB total

        cvt_all<<<1536, 256, 0, stream>>>(x, w_in, w_out, xf16, wif16, wof16);

        // QKV: 128x256 tile, 768 blocks at 3/CU = one full residency round
        gemm_wide<1><<<dim3(3 * CDIM / 256, M / 128), 256, 0, stream>>>(
            xf16, wif16, b_in, nullptr, qf16, kf16, vtf16, 3 * CDIM, CDIM);

        attn_mfma<<<dim3(SEQ / 64, BATCH * HEADS), 256, 0, stream>>>(
            qf16, kf16, vtf16, of16);

        // out-proj: same wide kernel, MODE 0 (256 blocks, all resident)
        gemm_wide<0><<<dim3(CDIM / 256, M / 128), 256, 0, stream>>>(
            of16, wof16, b_out, out, nullptr, nullptr, nullptr, CDIM, CDIM);
    } else {
        // --- fp32 fallback path (128MB) ---
        float* qws = (float*)d_ws;
        float* kws = qws + per;
        float* vws = kws + per;
        float* aws = vws + per;

        gemm_bt<1><<<dim3(3 * CDIM / TILE, M / TILE), 256, 0, stream>>>(
            x, w_in, b_in, nullptr, qws, kws, vws, M, 3 * CDIM, CDIM);

        attn_flash_f32<<<dim3(SEQ / 64, BATCH * HEADS), 256, 0, stream>>>(
            qws, kws, vws, aws);

        gemm_bt<0><<<dim3(CDIM / TILE, M / TILE), 256, 0, stream>>>(
            aws, w_out, b_out, out, nullptr, nullptr, nullptr, M, CDIM, CDIM);
    }
}

// Round 16
// 266.918 us; speedup vs baseline: 1.1647x; 1.1647x over previous
//
#include <hip/hip_runtime.h>
#include <math.h>
#include <stdint.h>

// Problem constants: B=8, N=1024, C=1024, H=16, Dh=64
#define SEQ   1024
#define BATCH 8
#define CDIM  1024
#define HEADS 16
#define DHEAD 64

typedef __bf16 bf16;
typedef _Float16 f16;
typedef __attribute__((ext_vector_type(8))) _Float16 f16x8;
typedef __attribute__((ext_vector_type(4))) float f32x4;

// async global->LDS, 16B per lane. LDS dest = wave-uniform base + lane*16.
static __device__ __forceinline__ void gl16(const void* g, void* l) {
    __builtin_amdgcn_global_load_lds(
        (const __attribute__((address_space(1))) void*)(uintptr_t)g,
        (__attribute__((address_space(3))) void*)(uintptr_t)l,
        16, 0, 0);
}

// ===========================================================================
// cvt_all: fused fp32 -> fp16 for x (1048576 vec8), w_in (393216), w_out
// (131072). One launch instead of three.
// ===========================================================================
__global__ __launch_bounds__(256)
void cvt_all(const float* __restrict__ x,  const float* __restrict__ wi,
             const float* __restrict__ wo, f16* __restrict__ xo,
             f16* __restrict__ wio, f16* __restrict__ woo)
{
    const int N1 = 1048576, N2 = 393216;   // vec8 counts for x, w_in
    const int NT = N1 + N2 + 131072;
    int i = blockIdx.x * blockDim.x + threadIdx.x;
    const int stride = gridDim.x * blockDim.x;
    for (; i < NT; i += stride) {
        const float* src; f16* dst; int off;
        if (i < N1)            { src = x;  dst = xo;  off = i; }
        else if (i < N1 + N2)  { src = wi; dst = wio; off = i - N1; }
        else                   { src = wo; dst = woo; off = i - N1 - N2; }
        const f32x4 v0 = *(const f32x4*)(src + (size_t)off * 8);
        const f32x4 v1 = *(const f32x4*)(src + (size_t)off * 8 + 4);
        f16x8 o;
#pragma unroll
        for (int j = 0; j < 4; j++) {
            o[j]     = (f16)v0[j];
            o[j + 4] = (f16)v1[j];
        }
        *(f16x8*)(dst + (size_t)off * 8) = o;
    }
}

// ===========================================================================
// Wide fp16 MFMA GEMM, 3-buffer counted-vmcnt depth-2 pipeline (the r13
// schedule that measured 125us on QKV -- depth-2 gives each load two compute
// phases to hide under; depth-1 (r15) regressed 33%).
// BM=128 x BN=256, BK=32, 4 waves (2x2), per-wave 64x128 (acc[4][8],
// 32 MFMA/K-step).  Per iter t: STAGE(t+2); vmcnt(12) [tile t landed];
// s_barrier; COMPUTE(t); s_barrier.  Loads in flight across barriers.
// Buffer t%3 overwritten by STAGE(t+3) at iter t+1, behind iter t's end
// barrier which proves all reads of it completed.
// LDS 3x(8KB A + 16KB B) = 72KB -> 2 blocks/CU.
// MODE 0: fp32 row-major store (+bias) to out0 [M][Ncols].
// MODE 1: QKV scatter as fp16 (q x0.125 -> qg[BH][N][64],
//         k -> kgp[BH][N][64], v transposed -> vgp[BH][64][N]).
// ===========================================================================
template<int MODE>
__global__ __launch_bounds__(256, 2)
void gemm_w3(const f16* __restrict__ Ag, const f16* __restrict__ Bg,
             const float* __restrict__ bias, float* __restrict__ out0,
             f16* __restrict__ qg, f16* __restrict__ kgp,
             f16* __restrict__ vgp, int Ncols, int K)
{
    __shared__ f16 As[3][4][128][8];   // 8KB per buffer; byte = (ks*128+row)*16
    __shared__ f16 Bs[3][4][256][8];   // 16KB per buffer; byte = (ks*256+row)*16

    const int m0 = blockIdx.y * 128;
    const int n0 = blockIdx.x * 256;

    const int tid  = threadIdx.x;
    const int wid  = tid >> 6;
    const int lane = tid & 63;
    const int wr   = (wid >> 1) * 64;    // 0/64 (M)
    const int wc   = (wid & 1) * 128;    // 0/128 (N)
    const int l16  = lane & 15;
    const int kgf  = lane >> 4;

    // A staging: chunk c0 = tid -> (ks=tid>>7, row=tid&127); c1 = c0 + 256
    const int akg = tid >> 7, arow = tid & 127;
    const f16* aP = Ag + (size_t)(m0 + arow) * K + akg * 8;
    // B staging: row = tid, ks = j (0..3)
    const f16* bP = Bg + (size_t)(n0 + tid) * K;
    const int loff = wid << 10;          // lane-linear wave base within a chunk set

#define STAGE(buf, kt)                                               \
    do {                                                             \
        gl16(aP + (kt),      (char*)As[buf] + loff);                 \
        gl16(aP + (kt) + 16, (char*)As[buf] + loff + 4096);          \
        gl16(bP + (kt),      (char*)Bs[buf] + loff);                 \
        gl16(bP + (kt) + 8,  (char*)Bs[buf] + loff + 4096);         \
        gl16(bP + (kt) + 16, (char*)Bs[buf] + loff + 8192);         \
        gl16(bP + (kt) + 24, (char*)Bs[buf] + loff + 12288);        \
    } while (0)

#define COMPUTE(buf)                                                         \
    do {                                                                     \
        f16x8 fa[4], fb[8];                                                  \
        _Pragma("unroll")                                                    \
        for (int i = 0; i < 4; i++)                                          \
            fa[i] = *(const f16x8*)&As[buf][kgf][wr + i * 16 + l16][0];      \
        _Pragma("unroll")                                                    \
        for (int j = 0; j < 8; j++)                                          \
            fb[j] = *(const f16x8*)&Bs[buf][kgf][wc + j * 16 + l16][0];      \
        _Pragma("unroll")                                                    \
        for (int i = 0; i < 4; i++)                                          \
            _Pragma("unroll")                                                \
            for (int j = 0; j < 8; j++)                                      \
                acc[i][j] = __builtin_amdgcn_mfma_f32_16x16x32_f16(          \
                    fa[i], fb[j], acc[i][j], 0, 0, 0);                       \
    } while (0)

    f32x4 acc[4][8];
#pragma unroll
    for (int i = 0; i < 4; i++)
#pragma unroll
        for (int j = 0; j < 8; j++) acc[i][j] = (f32x4)0.f;

    const int T = K >> 5;   // 32 K-tiles

    STAGE(0, 0);
    STAGE(1, 32);

    int cur = 0;
    for (int t = 0; t < T - 2; t++) {
        const int nbuf = (cur == 0) ? 2 : (cur - 1);   // (t+2) % 3
        STAGE(nbuf, (t + 2) << 5);
        asm volatile("s_waitcnt vmcnt(12)" ::: "memory");  // tile t landed
        __builtin_amdgcn_sched_barrier(0);
        __builtin_amdgcn_s_barrier();
        __builtin_amdgcn_sched_barrier(0);
        COMPUTE(cur);
        __builtin_amdgcn_sched_barrier(0);
        __builtin_amdgcn_s_barrier();
        cur = (cur == 2) ? 0 : (cur + 1);
    }

    asm volatile("s_waitcnt vmcnt(6)" ::: "memory");       // tile T-2 landed
    __builtin_amdgcn_sched_barrier(0);
    __builtin_amdgcn_s_barrier();
    __builtin_amdgcn_sched_barrier(0);
    COMPUTE(cur);
    __builtin_amdgcn_sched_barrier(0);
    __builtin_amdgcn_s_barrier();
    cur = (cur == 2) ? 0 : (cur + 1);

    asm volatile("s_waitcnt vmcnt(0)" ::: "memory");
    __builtin_amdgcn_sched_barrier(0);
    __builtin_amdgcn_s_barrier();
    __builtin_amdgcn_sched_barrier(0);
    COMPUTE(cur);

#undef STAGE
#undef COMPUTE

    // epilogue. D layout (verified r4): col=lane&15, row=(lane>>4)*4+reg.
#pragma unroll
    for (int j = 0; j < 8; j++) {
        const int d  = n0 + wc + j * 16 + l16;
        const float bv = bias[d];
        int s = 0, hh = 0, dh = 0;
        if (MODE == 1) {
            s  = d >> 10;
            hh = (d >> 6) & 15;
            dh = d & 63;
        }
#pragma unroll
        for (int i = 0; i < 4; i++) {
            const int mbase = m0 + wr + i * 16 + (lane >> 4) * 4;
#pragma unroll
            for (int r = 0; r < 4; r++) {
                const float v = acc[i][j][r] + bv;
                const int m = mbase + r;
                if (MODE == 0) {
                    out0[(size_t)m * Ncols + d] = v;
                } else {
                    const int b = m >> 10, n = m & 1023;
                    const size_t bho = (size_t)((b << 4) + hh) << 16;
                    if (s == 0)
                        qg[bho + ((size_t)n << 6) + dh] = (f16)(v * 0.125f);
                    else if (s == 1)
                        kgp[bho + ((size_t)n << 6) + dh] = (f16)v;
                    else
                        vgp[bho + ((size_t)dh << 10) + n] = (f16)v;
                }
            }
        }
    }
}

// ===========================================================================
// MFMA flash attention (structure verified r6/r8 -- frozen). One block =
// 64 q-rows of one (b,h); 4 waves x 16 q-rows. fp16 MFMA QK^T/PV, fp32
// online softmax. Output plain fp16 O to [B][N][C].
// ===========================================================================
__global__ __launch_bounds__(256, 4)
void attn_mfma(const f16* __restrict__ qf, const f16* __restrict__ kf,
               const f16* __restrict__ vtf, f16* __restrict__ og)
{
    __shared__ f16 Kl[8][64][8];    // [d/8][kcol][8]
    __shared__ f16 Vl[8][64][8];    // [k/8][drow][8]
    __shared__ f16 Pl[4][16][72];   // per-wave P: [wave][qrow][kcol], stride 72

    const int tid  = threadIdx.x;
    const int wid  = tid >> 6;
    const int lane = tid & 63;
    const int l16  = lane & 15;
    const int kg   = lane >> 4;      // 0..3
    const int bh   = blockIdx.y;
    const int q0   = blockIdx.x << 6;

    const size_t bhoff = (size_t)bh << 16;   // bh * 1024 * 64
    const f16* qb = qf  + bhoff;
    const f16* kb = kf  + bhoff;
    const f16* vb = vtf + bhoff;

    // Q fragments: row = q0+wid*16+l16, d = kg*8 + j (+32 for second half)
    f16x8 qfr[2];
    {
        const f16* qrow = qb + ((size_t)(q0 + wid * 16 + l16) << 6);
        qfr[0] = *(const f16x8*)(qrow + kg * 8);
        qfr[1] = *(const f16x8*)(qrow + 32 + kg * 8);
    }

    // staging assignment: 512 chunks of 16B per buffer, 2 per thread
    const int c0 = tid,        col0 = c0 & 63, slot0 = c0 >> 6;
    const int c1 = tid + 256,  col1 = c1 & 63, slot1 = c1 >> 6;

    float mrow[4], lrow[4];
    f32x4 accO[4];
#pragma unroll
    for (int r = 0; r < 4; r++) { mrow[r] = -INFINITY; lrow[r] = 0.f; }
#pragma unroll
    for (int t = 0; t < 4; t++) accO[t] = (f32x4)0.f;

    // prologue: k-tile 0 loads
    f16x8 rk0 = *(const f16x8*)(kb + ((size_t)col0 << 6) + slot0 * 8);
    f16x8 rk1 = *(const f16x8*)(kb + ((size_t)col1 << 6) + slot1 * 8);
    f16x8 rv0 = *(const f16x8*)(vb + ((size_t)col0 << 10) + slot0 * 8);
    f16x8 rv1 = *(const f16x8*)(vb + ((size_t)col1 << 10) + slot1 * 8);

    for (int kt = 0; kt < 16; kt++) {
        __syncthreads();   // previous iter's K/V fragment reads complete
        *(f16x8*)&Kl[slot0][col0][0] = rk0;
        *(f16x8*)&Kl[slot1][col1][0] = rk1;
        *(f16x8*)&Vl[slot0][col0][0] = rv0;
        *(f16x8*)&Vl[slot1][col1][0] = rv1;
        __syncthreads();

        // issue next tile's global loads; latency hides under compute
        if (kt < 15) {
            const int n1 = (kt + 1) << 6;
            rk0 = *(const f16x8*)(kb + ((size_t)(n1 + col0) << 6) + slot0 * 8);
            rk1 = *(const f16x8*)(kb + ((size_t)(n1 + col1) << 6) + slot1 * 8);
            rv0 = *(const f16x8*)(vb + ((size_t)col0 << 10) + n1 + slot0 * 8);
            rv1 = *(const f16x8*)(vb + ((size_t)col1 << 10) + n1 + slot1 * 8);
        }

        // ---- QK^T: wave's 16 rows x 64 cols, 4 col-tiles x 2 d-halves ----
        f32x4 accS[4];
#pragma unroll
        for (int t = 0; t < 4; t++) accS[t] = (f32x4)0.f;
#pragma unroll
        for (int t = 0; t < 4; t++) {
            const f16x8 kf0 = *(const f16x8*)&Kl[kg][t * 16 + l16][0];
            const f16x8 kf1 = *(const f16x8*)&Kl[4 + kg][t * 16 + l16][0];
            accS[t] = __builtin_amdgcn_mfma_f32_16x16x32_f16(qfr[0], kf0, accS[t], 0, 0, 0);
            accS[t] = __builtin_amdgcn_mfma_f32_16x16x32_f16(qfr[1], kf1, accS[t], 0, 0, 0);
        }

        // ---- online softmax; rows r -> q-row 4*kg + r, register-local ----
#pragma unroll
        for (int r = 0; r < 4; r++) {
            float sm = fmaxf(fmaxf(accS[0][r], accS[1][r]),
                             fmaxf(accS[2][r], accS[3][r]));
            sm = fmaxf(sm, __shfl_xor(sm, 1, 16));
            sm = fmaxf(sm, __shfl_xor(sm, 2, 16));
            sm = fmaxf(sm, __shfl_xor(sm, 4, 16));
            sm = fmaxf(sm, __shfl_xor(sm, 8, 16));
            const float mn = fmaxf(mrow[r], sm);
            const float al = __expf(mrow[r] - mn);
            float p0 = __expf(accS[0][r] - mn);
            float p1 = __expf(accS[1][r] - mn);
            float p2 = __expf(accS[2][r] - mn);
            float p3 = __expf(accS[3][r] - mn);
            float rs = (p0 + p1) + (p2 + p3);
            rs += __shfl_xor(rs, 1, 16);
            rs += __shfl_xor(rs, 2, 16);
            rs += __shfl_xor(rs, 4, 16);
            rs += __shfl_xor(rs, 8, 16);
            lrow[r] = lrow[r] * al + rs;
            mrow[r] = mn;
            accO[0][r] *= al;
            accO[1][r] *= al;
            accO[2][r] *= al;
            accO[3][r] *= al;
            const int prow = kg * 4 + r;
            Pl[wid][prow][l16]      = (f16)p0;
            Pl[wid][prow][16 + l16] = (f16)p1;
            Pl[wid][prow][32 + l16] = (f16)p2;
            Pl[wid][prow][48 + l16] = (f16)p3;
        }

        // ---- PV: O(16x64) += P(16x64) * V(64x64), via Vt fragments ----
#pragma unroll
        for (int h = 0; h < 2; h++) {
            const f16x8 pa = *(const f16x8*)&Pl[wid][l16][h * 32 + kg * 8];
#pragma unroll
            for (int t = 0; t < 4; t++) {
                const f16x8 vf = *(const f16x8*)&Vl[h * 4 + kg][t * 16 + l16][0];
                accO[t] = __builtin_amdgcn_mfma_f32_16x16x32_f16(pa, vf, accO[t], 0, 0, 0);
            }
        }
    }

    // ---- epilogue: normalize, fp16 store to [B][N][C] ----
    const int b = bh >> 4, hh = bh & 15;
#pragma unroll
    for (int r = 0; r < 4; r++) {
        const float inv = 1.0f / lrow[r];
        const int n = q0 + wid * 16 + kg * 4 + r;
        const size_t base = ((((size_t)b << 10) + n) << 10) + hh * 64;
#pragma unroll
        for (int t = 0; t < 4; t++)
            og[base + t * 16 + l16] = (f16)(accO[t][r] * inv);
    }
}

// ===========================================================================
// Fallback fp32 path (baseline, audited) — used only if ws_size < 96MB.
// ===========================================================================
#define TILE 128
#define KB   16
#define LSTR (TILE + 4)

template<int MODE>
__global__ __launch_bounds__(256, 2)
void gemm_bt(const float* __restrict__ A, const float* __restrict__ Bm,
             const float* __restrict__ bias, float* __restrict__ out0,
             float* __restrict__ qg, float* __restrict__ kg, float* __restrict__ vg,
             int M, int Ncols, int K)
{
    __shared__ float As[KB][LSTR];
    __shared__ float Bs[KB][LSTR];

    const int tid = threadIdx.x;
    const int tr  = tid >> 4;
    const int tc  = tid & 15;
    const int m0  = blockIdx.y * TILE;
    const int n0  = blockIdx.x * TILE;

    const int lrow = tid >> 2;
    const int lcol = (tid & 3) << 2;

    const float* Ap = A  + (size_t)(m0 + lrow) * K + lcol;
    const float* Bp = Bm + (size_t)(n0 + lrow) * K + lcol;
    const size_t rstep = (size_t)64 * K;

    float acc[8][8];
#pragma unroll
    for (int i = 0; i < 8; i++)
#pragma unroll
        for (int j = 0; j < 8; j++) acc[i][j] = 0.f;

    for (int kt = 0; kt < K; kt += KB) {
        float4 a0 = *(const float4*)(Ap + kt);
        float4 a1 = *(const float4*)(Ap + rstep + kt);
        float4 b0 = *(const float4*)(Bp + kt);
        float4 b1 = *(const float4*)(Bp + rstep + kt);
        __syncthreads();
        As[lcol + 0][lrow]      = a0.x;
        As[lcol + 1][lrow]      = a0.y;
        As[lcol + 2][lrow]      = a0.z;
        As[lcol + 3][lrow]      = a0.w;
        As[lcol + 0][lrow + 64] = a1.x;
        As[lcol + 1][lrow + 64] = a1.y;
        As[lcol + 2][lrow + 64] = a1.z;
        As[lcol + 3][lrow + 64] = a1.w;
        Bs[lcol + 0][lrow]      = b0.x;
        Bs[lcol + 1][lrow]      = b0.y;
        Bs[lcol + 2][lrow]      = b0.z;
        Bs[lcol + 3][lrow]      = b0.w;
        Bs[lcol + 0][lrow + 64] = b1.x;
        Bs[lcol + 1][lrow + 64] = b1.y;
        Bs[lcol + 2][lrow + 64] = b1.z;
        Bs[lcol + 3][lrow + 64] = b1.w;
        __syncthreads();
#pragma unroll
        for (int kk = 0; kk < KB; kk++) {
            float ar[8], br[8];
            *(float4*)&ar[0] = *(const float4*)&As[kk][tr << 2];
            *(float4*)&ar[4] = *(const float4*)&As[kk][64 + (tr << 2)];
            *(float4*)&br[0] = *(const float4*)&Bs[kk][tc << 2];
            *(float4*)&br[4] = *(const float4*)&Bs[kk][64 + (tc << 2)];
#pragma unroll
            for (int i = 0; i < 8; i++)
#pragma unroll
                for (int j = 0; j < 8; j++)
                    acc[i][j] = fmaf(ar[i], br[j], acc[i][j]);
        }
    }

#pragma unroll
    for (int rg = 0; rg < 2; rg++) {
#pragma unroll
        for (int ri = 0; ri < 4; ri++) {
            const int m = m0 + rg * 64 + (tr << 2) + ri;
#pragma unroll
            for (int cg = 0; cg < 2; cg++) {
                const int d = n0 + cg * 64 + (tc << 2);
                const float4 bb = *(const float4*)&bias[d];
                float v0 = acc[rg * 4 + ri][cg * 4 + 0] + bb.x;
                float v1 = acc[rg * 4 + ri][cg * 4 + 1] + bb.y;
                float v2 = acc[rg * 4 + ri][cg * 4 + 2] + bb.z;
                float v3 = acc[rg * 4 + ri][cg * 4 + 3] + bb.w;
                if (MODE == 0) {
                    *(float4*)&out0[(size_t)m * Ncols + d] = make_float4(v0, v1, v2, v3);
                } else {
                    const int s  = d >> 10;
                    const int h  = (d >> 6) & 15;
                    const int dh = d & 63;
                    const int b  = m >> 10;
                    const int n  = m & 1023;
                    float* dst = (s == 0) ? qg : ((s == 1) ? kg : vg);
                    if (s == 0) { v0 *= 0.125f; v1 *= 0.125f; v2 *= 0.125f; v3 *= 0.125f; }
                    const size_t idx = (((size_t)((b << 4) + h) << 10) + n) * 64 + dh;
                    *(float4*)&dst[idx] = make_float4(v0, v1, v2, v3);
                }
            }
        }
    }
}

__global__ __launch_bounds__(256, 2)
void attn_flash_f32(const float* __restrict__ qg, const float* __restrict__ kg,
                    const float* __restrict__ vg, float* __restrict__ og)
{
    __shared__ float Qs[64][68];
    __shared__ float KPs[64][68];
    __shared__ float Vs[64][68];

    const int tid = threadIdx.x;
    const int tr  = tid >> 4;
    const int tc  = tid & 15;
    const int bh  = blockIdx.y;
    const int q0  = blockIdx.x << 6;

    const float* qb = qg + ((size_t)bh * SEQ + q0) * DHEAD;
    const float* kb = kg + (size_t)bh * SEQ * DHEAD;
    const float* vb = vg + (size_t)bh * SEQ * DHEAD;

    const int lr = tid >> 4;
    const int lc = (tid & 15) << 2;

#pragma unroll
    for (int i = 0; i < 4; i++) {
        const int r = lr + (i << 4);
        float4 t = *(const float4*)(qb + r * 64 + lc);
        Qs[lc + 0][r] = t.x;
        Qs[lc + 1][r] = t.y;
        Qs[lc + 2][r] = t.z;
        Qs[lc + 3][r] = t.w;
    }

    float m[4], l[4], acc[4][4];
#pragma unroll
    for (int i = 0; i < 4; i++) {
        m[i] = -INFINITY; l[i] = 0.f;
#pragma unroll
        for (int j = 0; j < 4; j++) acc[i][j] = 0.f;
    }

    for (int kt = 0; kt < 16; kt++) {
        __syncthreads();
        const float* kbt = kb + (size_t)(kt << 6) * 64;
        const float* vbt = vb + (size_t)(kt << 6) * 64;
#pragma unroll
        for (int i = 0; i < 4; i++) {
            const int r = lr + (i << 4);
            float4 t = *(const float4*)(kbt + r * 64 + lc);
            KPs[lc + 0][r] = t.x;
            KPs[lc + 1][r] = t.y;
            KPs[lc + 2][r] = t.z;
            KPs[lc + 3][r] = t.w;
            float4 tv = *(const float4*)(vbt + r * 64 + lc);
            *(float4*)&Vs[r][lc] = tv;
        }
        __syncthreads();

        float s[4][4];
#pragma unroll
        for (int i = 0; i < 4; i++)
#pragma unroll
            for (int j = 0; j < 4; j++) s[i][j] = 0.f;
#pragma unroll 4
        for (int d = 0; d < 64; d++) {
            float qa[4], ka[4];
            *(float4*)qa = *(const float4*)&Qs[d][tr << 2];
            *(float4*)ka = *(const float4*)&KPs[d][tc << 2];
#pragma unroll
            for (int ri = 0; ri < 4; ri++)
#pragma unroll
                for (int ci = 0; ci < 4; ci++)
                    s[ri][ci] = fmaf(qa[ri], ka[ci], s[ri][ci]);
        }
        __syncthreads();

#pragma unroll
        for (int ri = 0; ri < 4; ri++) {
            float tm = fmaxf(fmaxf(s[ri][0], s[ri][1]), fmaxf(s[ri][2], s[ri][3]));
            tm = fmaxf(tm, __shfl_xor(tm, 1, 16));
            tm = fmaxf(tm, __shfl_xor(tm, 2, 16));
            tm = fmaxf(tm, __shfl_xor(tm, 4, 16));
            tm = fmaxf(tm, __shfl_xor(tm, 8, 16));
            const float mn = fmaxf(m[ri], tm);
            const float alpha = __expf(m[ri] - mn);
            const float p0 = __expf(s[ri][0] - mn);
            const float p1 = __expf(s[ri][1] - mn);
            const float p2 = __expf(s[ri][2] - mn);
            const float p3 = __expf(s[ri][3] - mn);
            float rs = (p0 + p1) + (p2 + p3);
            rs += __shfl_xor(rs, 1, 16);
            rs += __shfl_xor(rs, 2, 16);
            rs += __shfl_xor(rs, 4, 16);
            rs += __shfl_xor(rs, 8, 16);
            l[ri] = l[ri] * alpha + rs;
            m[ri] = mn;
            acc[ri][0] *= alpha; acc[ri][1] *= alpha;
            acc[ri][2] *= alpha; acc[ri][3] *= alpha;
            *(float4*)&KPs[(tr << 2) + ri][tc << 2] = make_float4(p0, p1, p2, p3);
        }
        __syncthreads();

#pragma unroll 4
        for (int c = 0; c < 64; c += 4) {
            float pr[4][4], vv[4][4];
            *(float4*)pr[0] = *(const float4*)&KPs[(tr << 2) + 0][c];
            *(float4*)pr[1] = *(const float4*)&KPs[(tr << 2) + 1][c];
            *(float4*)pr[2] = *(const float4*)&KPs[(tr << 2) + 2][c];
            *(float4*)pr[3] = *(const float4*)&KPs[(tr << 2) + 3][c];
            *(float4*)vv[0] = *(const float4*)&Vs[c + 0][tc << 2];
            *(float4*)vv[1] = *(const float4*)&Vs[c + 1][tc << 2];
            *(float4*)vv[2] = *(const float4*)&Vs[c + 2][tc << 2];
            *(float4*)vv[3] = *(const float4*)&Vs[c + 3][tc << 2];
#pragma unroll
            for (int ri = 0; ri < 4; ri++)
#pragma unroll
                for (int j = 0; j < 4; j++) {
                    float a = acc[ri][j];
                    a = fmaf(pr[ri][0], vv[0][j], a);
                    a = fmaf(pr[ri][1], vv[1][j], a);
                    a = fmaf(pr[ri][2], vv[2][j], a);
                    a = fmaf(pr[ri][3], vv[3][j], a);
                    acc[ri][j] = a;
                }
        }
    }

    const int b = bh >> 4, h = bh & 15;
#pragma unroll
    for (int ri = 0; ri < 4; ri++) {
        const float inv = 1.0f / l[ri];
        const int n = q0 + (tr << 2) + ri;
        const size_t idx = (((size_t)b * SEQ + n) << 10) + (h << 6) + (tc << 2);
        *(float4*)&og[idx] = make_float4(acc[ri][0] * inv, acc[ri][1] * inv,
                                         acc[ri][2] * inv, acc[ri][3] * inv);
    }
}

// ===========================================================================
extern "C" void kernel_launch(void* const* d_in, const int* in_sizes, int n_in,
                              void* d_out, int out_size, void* d_ws, size_t ws_size,
                              hipStream_t stream)
{
    const float* x     = (const float*)d_in[0];   // [8,1024,1024]
    const float* w_in  = (const float*)d_in[1];   // [3072,1024]
    const float* b_in  = (const float*)d_in[2];   // [3072]
    const float* w_out = (const float*)d_in[3];   // [1024,1024]
    const float* b_out = (const float*)d_in[4];   // [1024]
    float* out = (float*)d_out;                   // [8,1024,1024]
    (void)in_sizes; (void)n_in; (void)out_size;

    const size_t MB  = 1024 * 1024;
    const size_t per = (size_t)BATCH * HEADS * SEQ * DHEAD;  // 8M elements
    const int    M   = BATCH * SEQ;                          // 8192
    char* ws = (char*)d_ws;

    if (ws_size >= 96 * MB) {
        // --- fp16 MFMA path ---
        f16* qf16  = (f16*)(ws + 0 * MB);    // 16MB [BH][N][64]
        f16* kf16  = (f16*)(ws + 16 * MB);   // 16MB [BH][N][64]
        f16* vtf16 = (f16*)(ws + 32 * MB);   // 16MB [BH][64][N]
        f16* xf16  = (f16*)(ws + 48 * MB);   // 16MB (dead after QKV GEMM)
        f16* of16  = xf16;                   // aliased: born after attention
        f16* wif16 = (f16*)(ws + 64 * MB);   // 6MB
        f16* wof16 = (f16*)(ws + 70 * MB);   // 2MB -> 72MB total

        cvt_all<<<1536, 256, 0, stream>>>(x, w_in, w_out, xf16, wif16, wof16);

        // QKV: r13-verified 3-buffer wide kernel (768 blocks)
        gemm_w3<1><<<dim3(3 * CDIM / 256, M / 128), 256, 0, stream>>>(
            xf16, wif16, b_in, nullptr, qf16, kf16, vtf16, 3 * CDIM, CDIM);

        attn_mfma<<<dim3(SEQ / 64, BATCH * HEADS), 256, 0, stream>>>(
            qf16, kf16, vtf16, of16);

        // out-proj: same 3-buffer wide schedule, MODE 0 (256 blocks)
        gemm_w3<0><<<dim3(CDIM / 256, M / 128), 256, 0, stream>>>(
            of16, wof16, b_out, out, nullptr, nullptr, nullptr, CDIM, CDIM);
    } else {
        // --- fp32 fallback path (128MB) ---
        float* qws = (float*)d_ws;
        float* kws = qws + per;
        float* vws = kws + per;
        float* aws = vws + per;

        gemm_bt<1><<<dim3(3 * CDIM / TILE, M / TILE), 256, 0, stream>>>(
            x, w_in, b_in, nullptr, qws, kws, vws, M, 3 * CDIM, CDIM);

        attn_flash_f32<<<dim3(SEQ / 64, BATCH * HEADS), 256, 0, stream>>>(
            qws, kws, vws, aws);

        gemm_bt<0><<<dim3(CDIM / TILE, M / TILE), 256, 0, stream>>>(
            aws, w_out, b_out, out, nullptr, nullptr, nullptr, M, CDIM, CDIM);
    }
}

// Round 17
// 263.079 us; speedup vs baseline: 1.1817x; 1.0146x over previous
//
#include <hip/hip_runtime.h>
#include <math.h>
#include <stdint.h>

// Problem constants: B=8, N=1024, C=1024, H=16, Dh=64
#define SEQ   1024
#define BATCH 8
#define CDIM  1024
#define HEADS 16
#define DHEAD 64

typedef __bf16 bf16;
typedef _Float16 f16;
typedef __attribute__((ext_vector_type(8))) _Float16 f16x8;
typedef __attribute__((ext_vector_type(4))) float f32x4;

// async global->LDS, 16B per lane. LDS dest = wave-uniform base + lane*16.
static __device__ __forceinline__ void gl16(const void* g, void* l) {
    __builtin_amdgcn_global_load_lds(
        (const __attribute__((address_space(1))) void*)(uintptr_t)g,
        (__attribute__((address_space(3))) void*)(uintptr_t)l,
        16, 0, 0);
}

// ===========================================================================
// cvt_all: fused fp32 -> fp16 for x (1048576 vec8), w_in (393216), w_out
// (131072). One launch instead of three.
// ===========================================================================
__global__ __launch_bounds__(256)
void cvt_all(const float* __restrict__ x,  const float* __restrict__ wi,
             const float* __restrict__ wo, f16* __restrict__ xo,
             f16* __restrict__ wio, f16* __restrict__ woo)
{
    const int N1 = 1048576, N2 = 393216;   // vec8 counts for x, w_in
    const int NT = N1 + N2 + 131072;
    int i = blockIdx.x * blockDim.x + threadIdx.x;
    const int stride = gridDim.x * blockDim.x;
    for (; i < NT; i += stride) {
        const float* src; f16* dst; int off;
        if (i < N1)            { src = x;  dst = xo;  off = i; }
        else if (i < N1 + N2)  { src = wi; dst = wio; off = i - N1; }
        else                   { src = wo; dst = woo; off = i - N1 - N2; }
        const f32x4 v0 = *(const f32x4*)(src + (size_t)off * 8);
        const f32x4 v1 = *(const f32x4*)(src + (size_t)off * 8 + 4);
        f16x8 o;
#pragma unroll
        for (int j = 0; j < 4; j++) {
            o[j]     = (f16)v0[j];
            o[j + 4] = (f16)v1[j];
        }
        *(f16x8*)(dst + (size_t)off * 8) = o;
    }
}

// ===========================================================================
// Wide fp16 MFMA GEMM, 3-buffer counted-vmcnt depth-2 pipeline (r13/r16
// verified: 125us QKV, reproduced twice).  BM=128 x BN=256, BK=32, 4 waves
// (2x2), per-wave 64x128 (acc[4][8], 32 MFMA/K-step).
// Per iter t: STAGE(t+2); vmcnt(12); s_barrier; COMPUTE(t); s_barrier.
// NEW (r17): s_setprio(1) around the MFMA cluster (T5) -- the 2 co-resident
// blocks per CU sit at uncorrelated pipeline phases, giving the CU scheduler
// a role-split to arbitrate (stage-issuing vs MFMA-entering waves).
// LDS 3x(8KB A + 16KB B) = 72KB -> 2 blocks/CU.
// MODE 0: fp32 row-major store (+bias). MODE 1: QKV scatter as fp16.
// ===========================================================================
template<int MODE>
__global__ __launch_bounds__(256, 2)
void gemm_w3(const f16* __restrict__ Ag, const f16* __restrict__ Bg,
             const float* __restrict__ bias, float* __restrict__ out0,
             f16* __restrict__ qg, f16* __restrict__ kgp,
             f16* __restrict__ vgp, int Ncols, int K)
{
    __shared__ f16 As[3][4][128][8];   // 8KB per buffer; byte = (ks*128+row)*16
    __shared__ f16 Bs[3][4][256][8];   // 16KB per buffer; byte = (ks*256+row)*16

    const int m0 = blockIdx.y * 128;
    const int n0 = blockIdx.x * 256;

    const int tid  = threadIdx.x;
    const int wid  = tid >> 6;
    const int lane = tid & 63;
    const int wr   = (wid >> 1) * 64;    // 0/64 (M)
    const int wc   = (wid & 1) * 128;    // 0/128 (N)
    const int l16  = lane & 15;
    const int kgf  = lane >> 4;

    // A staging: chunk c0 = tid -> (ks=tid>>7, row=tid&127); c1 = c0 + 256
    const int akg = tid >> 7, arow = tid & 127;
    const f16* aP = Ag + (size_t)(m0 + arow) * K + akg * 8;
    // B staging: row = tid, ks = j (0..3)
    const f16* bP = Bg + (size_t)(n0 + tid) * K;
    const int loff = wid << 10;          // lane-linear wave base within a chunk set

#define STAGE(buf, kt)                                               \
    do {                                                             \
        gl16(aP + (kt),      (char*)As[buf] + loff);                 \
        gl16(aP + (kt) + 16, (char*)As[buf] + loff + 4096);          \
        gl16(bP + (kt),      (char*)Bs[buf] + loff);                 \
        gl16(bP + (kt) + 8,  (char*)Bs[buf] + loff + 4096);         \
        gl16(bP + (kt) + 16, (char*)Bs[buf] + loff + 8192);         \
        gl16(bP + (kt) + 24, (char*)Bs[buf] + loff + 12288);        \
    } while (0)

#define COMPUTE(buf)                                                         \
    do {                                                                     \
        f16x8 fa[4], fb[8];                                                  \
        _Pragma("unroll")                                                    \
        for (int i = 0; i < 4; i++)                                          \
            fa[i] = *(const f16x8*)&As[buf][kgf][wr + i * 16 + l16][0];      \
        _Pragma("unroll")                                                    \
        for (int j = 0; j < 8; j++)                                          \
            fb[j] = *(const f16x8*)&Bs[buf][kgf][wc + j * 16 + l16][0];      \
        __builtin_amdgcn_s_setprio(1);                                       \
        _Pragma("unroll")                                                    \
        for (int i = 0; i < 4; i++)                                          \
            _Pragma("unroll")                                                \
            for (int j = 0; j < 8; j++)                                      \
                acc[i][j] = __builtin_amdgcn_mfma_f32_16x16x32_f16(          \
                    fa[i], fb[j], acc[i][j], 0, 0, 0);                       \
        __builtin_amdgcn_s_setprio(0);                                       \
    } while (0)

    f32x4 acc[4][8];
#pragma unroll
    for (int i = 0; i < 4; i++)
#pragma unroll
        for (int j = 0; j < 8; j++) acc[i][j] = (f32x4)0.f;

    const int T = K >> 5;   // 32 K-tiles

    STAGE(0, 0);
    STAGE(1, 32);

    int cur = 0;
    for (int t = 0; t < T - 2; t++) {
        const int nbuf = (cur == 0) ? 2 : (cur - 1);   // (t+2) % 3
        STAGE(nbuf, (t + 2) << 5);
        asm volatile("s_waitcnt vmcnt(12)" ::: "memory");  // tile t landed
        __builtin_amdgcn_sched_barrier(0);
        __builtin_amdgcn_s_barrier();
        __builtin_amdgcn_sched_barrier(0);
        COMPUTE(cur);
        __builtin_amdgcn_sched_barrier(0);
        __builtin_amdgcn_s_barrier();
        cur = (cur == 2) ? 0 : (cur + 1);
    }

    asm volatile("s_waitcnt vmcnt(6)" ::: "memory");       // tile T-2 landed
    __builtin_amdgcn_sched_barrier(0);
    __builtin_amdgcn_s_barrier();
    __builtin_amdgcn_sched_barrier(0);
    COMPUTE(cur);
    __builtin_amdgcn_sched_barrier(0);
    __builtin_amdgcn_s_barrier();
    cur = (cur == 2) ? 0 : (cur + 1);

    asm volatile("s_waitcnt vmcnt(0)" ::: "memory");
    __builtin_amdgcn_sched_barrier(0);
    __builtin_amdgcn_s_barrier();
    __builtin_amdgcn_sched_barrier(0);
    COMPUTE(cur);

#undef STAGE
#undef COMPUTE

    // epilogue. D layout (verified r4): col=lane&15, row=(lane>>4)*4+reg.
#pragma unroll
    for (int j = 0; j < 8; j++) {
        const int d  = n0 + wc + j * 16 + l16;
        const float bv = bias[d];
        int s = 0, hh = 0, dh = 0;
        if (MODE == 1) {
            s  = d >> 10;
            hh = (d >> 6) & 15;
            dh = d & 63;
        }
#pragma unroll
        for (int i = 0; i < 4; i++) {
            const int mbase = m0 + wr + i * 16 + (lane >> 4) * 4;
#pragma unroll
            for (int r = 0; r < 4; r++) {
                const float v = acc[i][j][r] + bv;
                const int m = mbase + r;
                if (MODE == 0) {
                    out0[(size_t)m * Ncols + d] = v;
                } else {
                    const int b = m >> 10, n = m & 1023;
                    const size_t bho = (size_t)((b << 4) + hh) << 16;
                    if (s == 0)
                        qg[bho + ((size_t)n << 6) + dh] = (f16)(v * 0.125f);
                    else if (s == 1)
                        kgp[bho + ((size_t)n << 6) + dh] = (f16)v;
                    else
                        vgp[bho + ((size_t)dh << 10) + n] = (f16)v;
                }
            }
        }
    }
}

// ===========================================================================
// MFMA flash attention (structure verified r6/r8). One block = 64 q-rows of
// one (b,h); 4 waves x 16 q-rows. fp16 MFMA QK^T/PV, fp32 online softmax.
// NEW (r17): s_setprio around MFMA clusters (independent blocks per CU at
// different phases -> scheduler role-split, m191 +4-7%).
// Output plain fp16 O to [B][N][C].
// ===========================================================================
__global__ __launch_bounds__(256, 4)
void attn_mfma(const f16* __restrict__ qf, const f16* __restrict__ kf,
               const f16* __restrict__ vtf, f16* __restrict__ og)
{
    __shared__ f16 Kl[8][64][8];    // [d/8][kcol][8]
    __shared__ f16 Vl[8][64][8];    // [k/8][drow][8]
    __shared__ f16 Pl[4][16][72];   // per-wave P: [wave][qrow][kcol], stride 72

    const int tid  = threadIdx.x;
    const int wid  = tid >> 6;
    const int lane = tid & 63;
    const int l16  = lane & 15;
    const int kg   = lane >> 4;      // 0..3
    const int bh   = blockIdx.y;
    const int q0   = blockIdx.x << 6;

    const size_t bhoff = (size_t)bh << 16;   // bh * 1024 * 64
    const f16* qb = qf  + bhoff;
    const f16* kb = kf  + bhoff;
    const f16* vb = vtf + bhoff;

    // Q fragments: row = q0+wid*16+l16, d = kg*8 + j (+32 for second half)
    f16x8 qfr[2];
    {
        const f16* qrow = qb + ((size_t)(q0 + wid * 16 + l16) << 6);
        qfr[0] = *(const f16x8*)(qrow + kg * 8);
        qfr[1] = *(const f16x8*)(qrow + 32 + kg * 8);
    }

    // staging assignment: 512 chunks of 16B per buffer, 2 per thread
    const int c0 = tid,        col0 = c0 & 63, slot0 = c0 >> 6;
    const int c1 = tid + 256,  col1 = c1 & 63, slot1 = c1 >> 6;

    float mrow[4], lrow[4];
    f32x4 accO[4];
#pragma unroll
    for (int r = 0; r < 4; r++) { mrow[r] = -INFINITY; lrow[r] = 0.f; }
#pragma unroll
    for (int t = 0; t < 4; t++) accO[t] = (f32x4)0.f;

    // prologue: k-tile 0 loads
    f16x8 rk0 = *(const f16x8*)(kb + ((size_t)col0 << 6) + slot0 * 8);
    f16x8 rk1 = *(const f16x8*)(kb + ((size_t)col1 << 6) + slot1 * 8);
    f16x8 rv0 = *(const f16x8*)(vb + ((size_t)col0 << 10) + slot0 * 8);
    f16x8 rv1 = *(const f16x8*)(vb + ((size_t)col1 << 10) + slot1 * 8);

    for (int kt = 0; kt < 16; kt++) {
        __syncthreads();   // previous iter's K/V fragment reads complete
        *(f16x8*)&Kl[slot0][col0][0] = rk0;
        *(f16x8*)&Kl[slot1][col1][0] = rk1;
        *(f16x8*)&Vl[slot0][col0][0] = rv0;
        *(f16x8*)&Vl[slot1][col1][0] = rv1;
        __syncthreads();

        // issue next tile's global loads; latency hides under compute
        if (kt < 15) {
            const int n1 = (kt + 1) << 6;
            rk0 = *(const f16x8*)(kb + ((size_t)(n1 + col0) << 6) + slot0 * 8);
            rk1 = *(const f16x8*)(kb + ((size_t)(n1 + col1) << 6) + slot1 * 8);
            rv0 = *(const f16x8*)(vb + ((size_t)col0 << 10) + n1 + slot0 * 8);
            rv1 = *(const f16x8*)(vb + ((size_t)col1 << 10) + n1 + slot1 * 8);
        }

        // ---- QK^T: wave's 16 rows x 64 cols, 4 col-tiles x 2 d-halves ----
        f32x4 accS[4];
#pragma unroll
        for (int t = 0; t < 4; t++) accS[t] = (f32x4)0.f;
        __builtin_amdgcn_s_setprio(1);
#pragma unroll
        for (int t = 0; t < 4; t++) {
            const f16x8 kf0 = *(const f16x8*)&Kl[kg][t * 16 + l16][0];
            const f16x8 kf1 = *(const f16x8*)&Kl[4 + kg][t * 16 + l16][0];
            accS[t] = __builtin_amdgcn_mfma_f32_16x16x32_f16(qfr[0], kf0, accS[t], 0, 0, 0);
            accS[t] = __builtin_amdgcn_mfma_f32_16x16x32_f16(qfr[1], kf1, accS[t], 0, 0, 0);
        }
        __builtin_amdgcn_s_setprio(0);

        // ---- online softmax; rows r -> q-row 4*kg + r, register-local ----
#pragma unroll
        for (int r = 0; r < 4; r++) {
            float sm = fmaxf(fmaxf(accS[0][r], accS[1][r]),
                             fmaxf(accS[2][r], accS[3][r]));
            sm = fmaxf(sm, __shfl_xor(sm, 1, 16));
            sm = fmaxf(sm, __shfl_xor(sm, 2, 16));
            sm = fmaxf(sm, __shfl_xor(sm, 4, 16));
            sm = fmaxf(sm, __shfl_xor(sm, 8, 16));
            const float mn = fmaxf(mrow[r], sm);
            const float al = __expf(mrow[r] - mn);
            float p0 = __expf(accS[0][r] - mn);
            float p1 = __expf(accS[1][r] - mn);
            float p2 = __expf(accS[2][r] - mn);
            float p3 = __expf(accS[3][r] - mn);
            float rs = (p0 + p1) + (p2 + p3);
            rs += __shfl_xor(rs, 1, 16);
            rs += __shfl_xor(rs, 2, 16);
            rs += __shfl_xor(rs, 4, 16);
            rs += __shfl_xor(rs, 8, 16);
            lrow[r] = lrow[r] * al + rs;
            mrow[r] = mn;
            accO[0][r] *= al;
            accO[1][r] *= al;
            accO[2][r] *= al;
            accO[3][r] *= al;
            const int prow = kg * 4 + r;
            Pl[wid][prow][l16]      = (f16)p0;
            Pl[wid][prow][16 + l16] = (f16)p1;
            Pl[wid][prow][32 + l16] = (f16)p2;
            Pl[wid][prow][48 + l16] = (f16)p3;
        }

        // ---- PV: O(16x64) += P(16x64) * V(64x64), via Vt fragments ----
        __builtin_amdgcn_s_setprio(1);
#pragma unroll
        for (int h = 0; h < 2; h++) {
            const f16x8 pa = *(const f16x8*)&Pl[wid][l16][h * 32 + kg * 8];
#pragma unroll
            for (int t = 0; t < 4; t++) {
                const f16x8 vf = *(const f16x8*)&Vl[h * 4 + kg][t * 16 + l16][0];
                accO[t] = __builtin_amdgcn_mfma_f32_16x16x32_f16(pa, vf, accO[t], 0, 0, 0);
            }
        }
        __builtin_amdgcn_s_setprio(0);
    }

    // ---- epilogue: normalize, fp16 store to [B][N][C] ----
    const int b = bh >> 4, hh = bh & 15;
#pragma unroll
    for (int r = 0; r < 4; r++) {
        const float inv = 1.0f / lrow[r];
        const int n = q0 + wid * 16 + kg * 4 + r;
        const size_t base = ((((size_t)b << 10) + n) << 10) + hh * 64;
#pragma unroll
        for (int t = 0; t < 4; t++)
            og[base + t * 16 + l16] = (f16)(accO[t][r] * inv);
    }
}

// ===========================================================================
// Fallback fp32 path (baseline, audited) — used only if ws_size < 96MB.
// ===========================================================================
#define TILE 128
#define KB   16
#define LSTR (TILE + 4)

template<int MODE>
__global__ __launch_bounds__(256, 2)
void gemm_bt(const float* __restrict__ A, const float* __restrict__ Bm,
             const float* __restrict__ bias, float* __restrict__ out0,
             float* __restrict__ qg, float* __restrict__ kg, float* __restrict__ vg,
             int M, int Ncols, int K)
{
    __shared__ float As[KB][LSTR];
    __shared__ float Bs[KB][LSTR];

    const int tid = threadIdx.x;
    const int tr  = tid >> 4;
    const int tc  = tid & 15;
    const int m0  = blockIdx.y * TILE;
    const int n0  = blockIdx.x * TILE;

    const int lrow = tid >> 2;
    const int lcol = (tid & 3) << 2;

    const float* Ap = A  + (size_t)(m0 + lrow) * K + lcol;
    const float* Bp = Bm + (size_t)(n0 + lrow) * K + lcol;
    const size_t rstep = (size_t)64 * K;

    float acc[8][8];
#pragma unroll
    for (int i = 0; i < 8; i++)
#pragma unroll
        for (int j = 0; j < 8; j++) acc[i][j] = 0.f;

    for (int kt = 0; kt < K; kt += KB) {
        float4 a0 = *(const float4*)(Ap + kt);
        float4 a1 = *(const float4*)(Ap + rstep + kt);
        float4 b0 = *(const float4*)(Bp + kt);
        float4 b1 = *(const float4*)(Bp + rstep + kt);
        __syncthreads();
        As[lcol + 0][lrow]      = a0.x;
        As[lcol + 1][lrow]      = a0.y;
        As[lcol + 2][lrow]      = a0.z;
        As[lcol + 3][lrow]      = a0.w;
        As[lcol + 0][lrow + 64] = a1.x;
        As[lcol + 1][lrow + 64] = a1.y;
        As[lcol + 2][lrow + 64] = a1.z;
        As[lcol + 3][lrow + 64] = a1.w;
        Bs[lcol + 0][lrow]      = b0.x;
        Bs[lcol + 1][lrow]      = b0.y;
        Bs[lcol + 2][lrow]      = b0.z;
        Bs[lcol + 3][lrow]      = b0.w;
        Bs[lcol + 0][lrow + 64] = b1.x;
        Bs[lcol + 1][lrow + 64] = b1.y;
        Bs[lcol + 2][lrow + 64] = b1.z;
        Bs[lcol + 3][lrow + 64] = b1.w;
        __syncthreads();
#pragma unroll
        for (int kk = 0; kk < KB; kk++) {
            float ar[8], br[8];
            *(float4*)&ar[0] = *(const float4*)&As[kk][tr << 2];
            *(float4*)&ar[4] = *(const float4*)&As[kk][64 + (tr << 2)];
            *(float4*)&br[0] = *(const float4*)&Bs[kk][tc << 2];
            *(float4*)&br[4] = *(const float4*)&Bs[kk][64 + (tc << 2)];
#pragma unroll
            for (int i = 0; i < 8; i++)
#pragma unroll
                for (int j = 0; j < 8; j++)
                    acc[i][j] = fmaf(ar[i], br[j], acc[i][j]);
        }
    }

#pragma unroll
    for (int rg = 0; rg < 2; rg++) {
#pragma unroll
        for (int ri = 0; ri < 4; ri++) {
            const int m = m0 + rg * 64 + (tr << 2) + ri;
#pragma unroll
            for (int cg = 0; cg < 2; cg++) {
                const int d = n0 + cg * 64 + (tc << 2);
                const float4 bb = *(const float4*)&bias[d];
                float v0 = acc[rg * 4 + ri][cg * 4 + 0] + bb.x;
                float v1 = acc[rg * 4 + ri][cg * 4 + 1] + bb.y;
                float v2 = acc[rg * 4 + ri][cg * 4 + 2] + bb.z;
                float v3 = acc[rg * 4 + ri][cg * 4 + 3] + bb.w;
                if (MODE == 0) {
                    *(float4*)&out0[(size_t)m * Ncols + d] = make_float4(v0, v1, v2, v3);
                } else {
                    const int s  = d >> 10;
                    const int h  = (d >> 6) & 15;
                    const int dh = d & 63;
                    const int b  = m >> 10;
                    const int n  = m & 1023;
                    float* dst = (s == 0) ? qg : ((s == 1) ? kg : vg);
                    if (s == 0) { v0 *= 0.125f; v1 *= 0.125f; v2 *= 0.125f; v3 *= 0.125f; }
                    const size_t idx = (((size_t)((b << 4) + h) << 10) + n) * 64 + dh;
                    *(float4*)&dst[idx] = make_float4(v0, v1, v2, v3);
                }
            }
        }
    }
}

__global__ __launch_bounds__(256, 2)
void attn_flash_f32(const float* __restrict__ qg, const float* __restrict__ kg,
                    const float* __restrict__ vg, float* __restrict__ og)
{
    __shared__ float Qs[64][68];
    __shared__ float KPs[64][68];
    __shared__ float Vs[64][68];

    const int tid = threadIdx.x;
    const int tr  = tid >> 4;
    const int tc  = tid & 15;
    const int bh  = blockIdx.y;
    const int q0  = blockIdx.x << 6;

    const float* qb = qg + ((size_t)bh * SEQ + q0) * DHEAD;
    const float* kb = kg + (size_t)bh * SEQ * DHEAD;
    const float* vb = vg + (size_t)bh * SEQ * DHEAD;

    const int lr = tid >> 4;
    const int lc = (tid & 15) << 2;

#pragma unroll
    for (int i = 0; i < 4; i++) {
        const int r = lr + (i << 4);
        float4 t = *(const float4*)(qb + r * 64 + lc);
        Qs[lc + 0][r] = t.x;
        Qs[lc + 1][r] = t.y;
        Qs[lc + 2][r] = t.z;
        Qs[lc + 3][r] = t.w;
    }

    float m[4], l[4], acc[4][4];
#pragma unroll
    for (int i = 0; i < 4; i++) {
        m[i] = -INFINITY; l[i] = 0.f;
#pragma unroll
        for (int j = 0; j < 4; j++) acc[i][j] = 0.f;
    }

    for (int kt = 0; kt < 16; kt++) {
        __syncthreads();
        const float* kbt = kb + (size_t)(kt << 6) * 64;
        const float* vbt = vb + (size_t)(kt << 6) * 64;
#pragma unroll
        for (int i = 0; i < 4; i++) {
            const int r = lr + (i << 4);
            float4 t = *(const float4*)(kbt + r * 64 + lc);
            KPs[lc + 0][r] = t.x;
            KPs[lc + 1][r] = t.y;
            KPs[lc + 2][r] = t.z;
            KPs[lc + 3][r] = t.w;
            float4 tv = *(const float4*)(vbt + r * 64 + lc);
            *(float4*)&Vs[r][lc] = tv;
        }
        __syncthreads();

        float s[4][4];
#pragma unroll
        for (int i = 0; i < 4; i++)
#pragma unroll
            for (int j = 0; j < 4; j++) s[i][j] = 0.f;
#pragma unroll 4
        for (int d = 0; d < 64; d++) {
            float qa[4], ka[4];
            *(float4*)qa = *(const float4*)&Qs[d][tr << 2];
            *(float4*)ka = *(const float4*)&KPs[d][tc << 2];
#pragma unroll
            for (int ri = 0; ri < 4; ri++)
#pragma unroll
                for (int ci = 0; ci < 4; ci++)
                    s[ri][ci] = fmaf(qa[ri], ka[ci], s[ri][ci]);
        }
        __syncthreads();

#pragma unroll
        for (int ri = 0; ri < 4; ri++) {
            float tm = fmaxf(fmaxf(s[ri][0], s[ri][1]), fmaxf(s[ri][2], s[ri][3]));
            tm = fmaxf(tm, __shfl_xor(tm, 1, 16));
            tm = fmaxf(tm, __shfl_xor(tm, 2, 16));
            tm = fmaxf(tm, __shfl_xor(tm, 4, 16));
            tm = fmaxf(tm, __shfl_xor(tm, 8, 16));
            const float mn = fmaxf(m[ri], tm);
            const float alpha = __expf(m[ri] - mn);
            const float p0 = __expf(s[ri][0] - mn);
            const float p1 = __expf(s[ri][1] - mn);
            const float p2 = __expf(s[ri][2] - mn);
            const float p3 = __expf(s[ri][3] - mn);
            float rs = (p0 + p1) + (p2 + p3);
            rs += __shfl_xor(rs, 1, 16);
            rs += __shfl_xor(rs, 2, 16);
            rs += __shfl_xor(rs, 4, 16);
            rs += __shfl_xor(rs, 8, 16);
            l[ri] = l[ri] * alpha + rs;
            m[ri] = mn;
            acc[ri][0] *= alpha; acc[ri][1] *= alpha;
            acc[ri][2] *= alpha; acc[ri][3] *= alpha;
            *(float4*)&KPs[(tr << 2) + ri][tc << 2] = make_float4(p0, p1, p2, p3);
        }
        __syncthreads();

#pragma unroll 4
        for (int c = 0; c < 64; c += 4) {
            float pr[4][4], vv[4][4];
            *(float4*)pr[0] = *(const float4*)&KPs[(tr << 2) + 0][c];
            *(float4*)pr[1] = *(const float4*)&KPs[(tr << 2) + 1][c];
            *(float4*)pr[2] = *(const float4*)&KPs[(tr << 2) + 2][c];
            *(float4*)pr[3] = *(const float4*)&KPs[(tr << 2) + 3][c];
            *(float4*)vv[0] = *(const float4*)&Vs[c + 0][tc << 2];
            *(float4*)vv[1] = *(const float4*)&Vs[c + 1][tc << 2];
            *(float4*)vv[2] = *(const float4*)&Vs[c + 2][tc << 2];
            *(float4*)vv[3] = *(const float4*)&Vs[c + 3][tc << 2];
#pragma unroll
            for (int ri = 0; ri < 4; ri++)
#pragma unroll
                for (int j = 0; j < 4; j++) {
                    float a = acc[ri][j];
                    a = fmaf(pr[ri][0], vv[0][j], a);
                    a = fmaf(pr[ri][1], vv[1][j], a);
                    a = fmaf(pr[ri][2], vv[2][j], a);
                    a = fmaf(pr[ri][3], vv[3][j], a);
                    acc[ri][j] = a;
                }
        }
    }

    const int b = bh >> 4, h = bh & 15;
#pragma unroll
    for (int ri = 0; ri < 4; ri++) {
        const float inv = 1.0f / l[ri];
        const int n = q0 + (tr << 2) + ri;
        const size_t idx = (((size_t)b * SEQ + n) << 10) + (h << 6) + (tc << 2);
        *(float4*)&og[idx] = make_float4(acc[ri][0] * inv, acc[ri][1] * inv,
                                         acc[ri][2] * inv, acc[ri][3] * inv);
    }
}

// ===========================================================================
extern "C" void kernel_launch(void* const* d_in, const int* in_sizes, int n_in,
                              void* d_out, int out_size, void* d_ws, size_t ws_size,
                              hipStream_t stream)
{
    const float* x     = (const float*)d_in[0];   // [8,1024,1024]
    const float* w_in  = (const float*)d_in[1];   // [3072,1024]
    const float* b_in  = (const float*)d_in[2];   // [3072]
    const float* w_out = (const float*)d_in[3];   // [1024,1024]
    const float* b_out = (const float*)d_in[4];   // [1024]
    float* out = (float*)d_out;                   // [8,1024,1024]
    (void)in_sizes; (void)n_in; (void)out_size;

    const size_t MB  = 1024 * 1024;
    const size_t per = (size_t)BATCH * HEADS * SEQ * DHEAD;  // 8M elements
    const int    M   = BATCH * SEQ;                          // 8192
    char* ws = (char*)d_ws;

    if (ws_size >= 96 * MB) {
        // --- fp16 MFMA path ---
        f16* qf16  = (f16*)(ws + 0 * MB);    // 16MB [BH][N][64]
        f16* kf16  = (f16*)(ws + 16 * MB);   // 16MB [BH][N][64]
        f16* vtf16 = (f16*)(ws + 32 * MB);   // 16MB [BH][64][N]
        f16* xf16  = (f16*)(ws + 48 * MB);   // 16MB (dead after QKV GEMM)
        f16* of16  = xf16;                   // aliased: born after attention
        f16* wif16 = (f16*)(ws + 64 * MB);   // 6MB
        f16* wof16 = (f16*)(ws + 70 * MB);   // 2MB -> 72MB total

        cvt_all<<<1536, 256, 0, stream>>>(x, w_in, w_out, xf16, wif16, wof16);

        // QKV: r13/r16-verified 3-buffer wide kernel (768 blocks) + T5
        gemm_w3<1><<<dim3(3 * CDIM / 256, M / 128), 256, 0, stream>>>(
            xf16, wif16, b_in, nullptr, qf16, kf16, vtf16, 3 * CDIM, CDIM);

        attn_mfma<<<dim3(SEQ / 64, BATCH * HEADS), 256, 0, stream>>>(
            qf16, kf16, vtf16, of16);

        // out-proj: same 3-buffer wide schedule, MODE 0 (256 blocks)
        gemm_w3<0><<<dim3(CDIM / 256, M / 128), 256, 0, stream>>>(
            of16, wof16, b_out, out, nullptr, nullptr, nullptr, CDIM, CDIM);
    } else {
        // --- fp32 fallback path (128MB) ---
        float* qws = (float*)d_ws;
        float* kws = qws + per;
        float* vws = kws + per;
        float* aws = vws + per;

        gemm_bt<1><<<dim3(3 * CDIM / TILE, M / TILE), 256, 0, stream>>>(
            x, w_in, b_in, nullptr, qws, kws, vws, M, 3 * CDIM, CDIM);

        attn_flash_f32<<<dim3(SEQ / 64, BATCH * HEADS), 256, 0, stream>>>(
            qws, kws, vws, aws);

        gemm_bt<0><<<dim3(CDIM / TILE, M / TILE), 256, 0, stream>>>(
            aws, w_out, b_out, out, nullptr, nullptr, nullptr, M, CDIM, CDIM);
    }
}

// Round 18
// 262.606 us; speedup vs baseline: 1.1838x; 1.0018x over previous
//
#include <hip/hip_runtime.h>
#include <math.h>
#include <stdint.h>

// Problem constants: B=8, N=1024, C=1024, H=16, Dh=64
#define SEQ   1024
#define BATCH 8
#define CDIM  1024
#define HEADS 16
#define DHEAD 64

typedef __bf16 bf16;
typedef _Float16 f16;
typedef __attribute__((ext_vector_type(8))) _Float16 f16x8;
typedef __attribute__((ext_vector_type(4))) float f32x4;

// async global->LDS, 16B per lane. LDS dest = wave-uniform base + lane*16.
static __device__ __forceinline__ void gl16(const void* g, void* l) {
    __builtin_amdgcn_global_load_lds(
        (const __attribute__((address_space(1))) void*)(uintptr_t)g,
        (__attribute__((address_space(3))) void*)(uintptr_t)l,
        16, 0, 0);
}

// ===========================================================================
// cvt_all: fused fp32 -> fp16 for x (1048576 vec8), w_in (393216), w_out
// (131072). One launch instead of three.
// ===========================================================================
__global__ __launch_bounds__(256)
void cvt_all(const float* __restrict__ x,  const float* __restrict__ wi,
             const float* __restrict__ wo, f16* __restrict__ xo,
             f16* __restrict__ wio, f16* __restrict__ woo)
{
    const int N1 = 1048576, N2 = 393216;   // vec8 counts for x, w_in
    const int NT = N1 + N2 + 131072;
    int i = blockIdx.x * blockDim.x + threadIdx.x;
    const int stride = gridDim.x * blockDim.x;
    for (; i < NT; i += stride) {
        const float* src; f16* dst; int off;
        if (i < N1)            { src = x;  dst = xo;  off = i; }
        else if (i < N1 + N2)  { src = wi; dst = wio; off = i - N1; }
        else                   { src = wo; dst = woo; off = i - N1 - N2; }
        const f32x4 v0 = *(const f32x4*)(src + (size_t)off * 8);
        const f32x4 v1 = *(const f32x4*)(src + (size_t)off * 8 + 4);
        f16x8 o;
#pragma unroll
        for (int j = 0; j < 4; j++) {
            o[j]     = (f16)v0[j];
            o[j + 4] = (f16)v1[j];
        }
        *(f16x8*)(dst + (size_t)off * 8) = o;
    }
}

// ===========================================================================
// Wide fp16 MFMA GEMM, 3-buffer counted-vmcnt depth-2 pipeline + setprio
// (r17 verified: QKV 125us, total-best path).  BM=128 x BN=256, BK=32,
// 4 waves (2x2), per-wave 64x128 (acc[4][8], 32 MFMA/K-step).
// LDS 3x(8KB A + 16KB B) = 72KB -> 2 blocks/CU.
// MODE 0: fp32 row-major store (+bias). MODE 1: QKV scatter as fp16.
// ===========================================================================
template<int MODE>
__global__ __launch_bounds__(256, 2)
void gemm_w3(const f16* __restrict__ Ag, const f16* __restrict__ Bg,
             const float* __restrict__ bias, float* __restrict__ out0,
             f16* __restrict__ qg, f16* __restrict__ kgp,
             f16* __restrict__ vgp, int Ncols, int K)
{
    __shared__ f16 As[3][4][128][8];   // 8KB per buffer; byte = (ks*128+row)*16
    __shared__ f16 Bs[3][4][256][8];   // 16KB per buffer; byte = (ks*256+row)*16

    const int m0 = blockIdx.y * 128;
    const int n0 = blockIdx.x * 256;

    const int tid  = threadIdx.x;
    const int wid  = tid >> 6;
    const int lane = tid & 63;
    const int wr   = (wid >> 1) * 64;    // 0/64 (M)
    const int wc   = (wid & 1) * 128;    // 0/128 (N)
    const int l16  = lane & 15;
    const int kgf  = lane >> 4;

    const int akg = tid >> 7, arow = tid & 127;
    const f16* aP = Ag + (size_t)(m0 + arow) * K + akg * 8;
    const f16* bP = Bg + (size_t)(n0 + tid) * K;
    const int loff = wid << 10;

#define STAGE(buf, kt)                                               \
    do {                                                             \
        gl16(aP + (kt),      (char*)As[buf] + loff);                 \
        gl16(aP + (kt) + 16, (char*)As[buf] + loff + 4096);          \
        gl16(bP + (kt),      (char*)Bs[buf] + loff);                 \
        gl16(bP + (kt) + 8,  (char*)Bs[buf] + loff + 4096);         \
        gl16(bP + (kt) + 16, (char*)Bs[buf] + loff + 8192);         \
        gl16(bP + (kt) + 24, (char*)Bs[buf] + loff + 12288);        \
    } while (0)

#define COMPUTE(buf)                                                         \
    do {                                                                     \
        f16x8 fa[4], fb[8];                                                  \
        _Pragma("unroll")                                                    \
        for (int i = 0; i < 4; i++)                                          \
            fa[i] = *(const f16x8*)&As[buf][kgf][wr + i * 16 + l16][0];      \
        _Pragma("unroll")                                                    \
        for (int j = 0; j < 8; j++)                                          \
            fb[j] = *(const f16x8*)&Bs[buf][kgf][wc + j * 16 + l16][0];      \
        __builtin_amdgcn_s_setprio(1);                                       \
        _Pragma("unroll")                                                    \
        for (int i = 0; i < 4; i++)                                          \
            _Pragma("unroll")                                                \
            for (int j = 0; j < 8; j++)                                      \
                acc[i][j] = __builtin_amdgcn_mfma_f32_16x16x32_f16(          \
                    fa[i], fb[j], acc[i][j], 0, 0, 0);                       \
        __builtin_amdgcn_s_setprio(0);                                       \
    } while (0)

    f32x4 acc[4][8];
#pragma unroll
    for (int i = 0; i < 4; i++)
#pragma unroll
        for (int j = 0; j < 8; j++) acc[i][j] = (f32x4)0.f;

    const int T = K >> 5;   // 32 K-tiles

    STAGE(0, 0);
    STAGE(1, 32);

    int cur = 0;
    for (int t = 0; t < T - 2; t++) {
        const int nbuf = (cur == 0) ? 2 : (cur - 1);   // (t+2) % 3
        STAGE(nbuf, (t + 2) << 5);
        asm volatile("s_waitcnt vmcnt(12)" ::: "memory");  // tile t landed
        __builtin_amdgcn_sched_barrier(0);
        __builtin_amdgcn_s_barrier();
        __builtin_amdgcn_sched_barrier(0);
        COMPUTE(cur);
        __builtin_amdgcn_sched_barrier(0);
        __builtin_amdgcn_s_barrier();
        cur = (cur == 2) ? 0 : (cur + 1);
    }

    asm volatile("s_waitcnt vmcnt(6)" ::: "memory");       // tile T-2 landed
    __builtin_amdgcn_sched_barrier(0);
    __builtin_amdgcn_s_barrier();
    __builtin_amdgcn_sched_barrier(0);
    COMPUTE(cur);
    __builtin_amdgcn_sched_barrier(0);
    __builtin_amdgcn_s_barrier();
    cur = (cur == 2) ? 0 : (cur + 1);

    asm volatile("s_waitcnt vmcnt(0)" ::: "memory");
    __builtin_amdgcn_sched_barrier(0);
    __builtin_amdgcn_s_barrier();
    __builtin_amdgcn_sched_barrier(0);
    COMPUTE(cur);

#undef STAGE
#undef COMPUTE

    // epilogue. D layout (verified r4): col=lane&15, row=(lane>>4)*4+reg.
#pragma unroll
    for (int j = 0; j < 8; j++) {
        const int d  = n0 + wc + j * 16 + l16;
        const float bv = bias[d];
        int s = 0, hh = 0, dh = 0;
        if (MODE == 1) {
            s  = d >> 10;
            hh = (d >> 6) & 15;
            dh = d & 63;
        }
#pragma unroll
        for (int i = 0; i < 4; i++) {
            const int mbase = m0 + wr + i * 16 + (lane >> 4) * 4;
#pragma unroll
            for (int r = 0; r < 4; r++) {
                const float v = acc[i][j][r] + bv;
                const int m = mbase + r;
                if (MODE == 0) {
                    out0[(size_t)m * Ncols + d] = v;
                } else {
                    const int b = m >> 10, n = m & 1023;
                    const size_t bho = (size_t)((b << 4) + hh) << 16;
                    if (s == 0)
                        qg[bho + ((size_t)n << 6) + dh] = (f16)(v * 0.125f);
                    else if (s == 1)
                        kgp[bho + ((size_t)n << 6) + dh] = (f16)v;
                    else
                        vgp[bho + ((size_t)dh << 10) + n] = (f16)v;
                }
            }
        }
    }
}

// ===========================================================================
// MFMA flash attention, KVBLK=128 (r18): halves K-loop iterations (16->8),
// barriers (32->16), and online-softmax reduce/rescale passes (16->8) at
// constant total MFMA.  One block = 64 q-rows of one (b,h); 4 waves x 16
// q-rows.  fp16 MFMA QK^T/PV, fp32 online softmax, setprio on MFMA clusters.
// LDS: Kl 16KB + Vl 16KB + Pl 17KB = 49KB -> 3 blocks/CU.
// Output plain fp16 O to [B][N][C].
// ===========================================================================
__global__ __launch_bounds__(256, 3)
void attn_mfma(const f16* __restrict__ qf, const f16* __restrict__ kf,
               const f16* __restrict__ vtf, f16* __restrict__ og)
{
    __shared__ f16 Kl[8][128][8];    // [d/8][kcol][8]
    __shared__ f16 Vl[16][64][8];    // [k/8][drow][8]
    __shared__ f16 Pl[4][16][136];   // per-wave P: [qrow][kcol], stride 136

    const int tid  = threadIdx.x;
    const int wid  = tid >> 6;
    const int lane = tid & 63;
    const int l16  = lane & 15;
    const int kg   = lane >> 4;      // 0..3
    const int bh   = blockIdx.y;
    const int q0   = blockIdx.x << 6;

    const size_t bhoff = (size_t)bh << 16;   // bh * 1024 * 64
    const f16* qb = qf  + bhoff;
    const f16* kb = kf  + bhoff;
    const f16* vb = vtf + bhoff;

    // Q fragments: row = q0+wid*16+l16, d = kg*8 + j (+32 for second half)
    f16x8 qfr[2];
    {
        const f16* qrow = qb + ((size_t)(q0 + wid * 16 + l16) << 6);
        qfr[0] = *(const f16x8*)(qrow + kg * 8);
        qfr[1] = *(const f16x8*)(qrow + 32 + kg * 8);
    }

    float mrow[4], lrow[4];
    f32x4 accO[4];
#pragma unroll
    for (int r = 0; r < 4; r++) { mrow[r] = -INFINITY; lrow[r] = 0.f; }
#pragma unroll
    for (int t = 0; t < 4; t++) accO[t] = (f32x4)0.f;

    // staging: 1024 chunks of 16B per buffer, 4 per thread (c = tid + 256j)
    // Kl chunk c: col = c & 127, slot = c >> 7   (K row-major [col][64])
    // Vl chunk c: drow = c & 63, ks = c >> 6     (Vt [drow][1024])
    f16x8 rk[4], rv[4];
#pragma unroll
    for (int j = 0; j < 4; j++) {
        const int ck = tid + 256 * j;
        rk[j] = *(const f16x8*)(kb + ((size_t)(ck & 127) << 6) + (ck >> 7) * 8);
        rv[j] = *(const f16x8*)(vb + ((size_t)(ck & 63) << 10) + (ck >> 6) * 8);
    }

    for (int kt = 0; kt < 8; kt++) {
        __syncthreads();   // previous iter's K/V fragment reads complete
#pragma unroll
        for (int j = 0; j < 4; j++) {
            const int ck = tid + 256 * j;
            *(f16x8*)&Kl[ck >> 7][ck & 127][0] = rk[j];
            *(f16x8*)&Vl[ck >> 6][ck & 63][0]  = rv[j];
        }
        __syncthreads();

        // issue next tile's global loads; latency hides under compute
        if (kt < 7) {
            const int n1 = (kt + 1) << 7;
#pragma unroll
            for (int j = 0; j < 4; j++) {
                const int ck = tid + 256 * j;
                rk[j] = *(const f16x8*)(kb + ((size_t)(n1 + (ck & 127)) << 6) + (ck >> 7) * 8);
                rv[j] = *(const f16x8*)(vb + ((size_t)(ck & 63) << 10) + n1 + (ck >> 6) * 8);
            }
        }

        // ---- QK^T: wave's 16 rows x 128 cols, 8 col-tiles x 2 d-halves ----
        f32x4 accS[8];
#pragma unroll
        for (int t = 0; t < 8; t++) accS[t] = (f32x4)0.f;
        __builtin_amdgcn_s_setprio(1);
#pragma unroll
        for (int t = 0; t < 8; t++) {
            const f16x8 kf0 = *(const f16x8*)&Kl[kg][t * 16 + l16][0];
            const f16x8 kf1 = *(const f16x8*)&Kl[4 + kg][t * 16 + l16][0];
            accS[t] = __builtin_amdgcn_mfma_f32_16x16x32_f16(qfr[0], kf0, accS[t], 0, 0, 0);
            accS[t] = __builtin_amdgcn_mfma_f32_16x16x32_f16(qfr[1], kf1, accS[t], 0, 0, 0);
        }
        __builtin_amdgcn_s_setprio(0);

        // ---- online softmax; rows r -> q-row 4*kg + r, register-local ----
#pragma unroll
        for (int r = 0; r < 4; r++) {
            float sm = fmaxf(fmaxf(fmaxf(accS[0][r], accS[1][r]),
                                   fmaxf(accS[2][r], accS[3][r])),
                             fmaxf(fmaxf(accS[4][r], accS[5][r]),
                                   fmaxf(accS[6][r], accS[7][r])));
            sm = fmaxf(sm, __shfl_xor(sm, 1, 16));
            sm = fmaxf(sm, __shfl_xor(sm, 2, 16));
            sm = fmaxf(sm, __shfl_xor(sm, 4, 16));
            sm = fmaxf(sm, __shfl_xor(sm, 8, 16));
            const float mn = fmaxf(mrow[r], sm);
            const float al = __expf(mrow[r] - mn);
            float p[8], rs = 0.f;
#pragma unroll
            for (int t = 0; t < 8; t++) {
                p[t] = __expf(accS[t][r] - mn);
                rs += p[t];
            }
            rs += __shfl_xor(rs, 1, 16);
            rs += __shfl_xor(rs, 2, 16);
            rs += __shfl_xor(rs, 4, 16);
            rs += __shfl_xor(rs, 8, 16);
            lrow[r] = lrow[r] * al + rs;
            mrow[r] = mn;
            accO[0][r] *= al;
            accO[1][r] *= al;
            accO[2][r] *= al;
            accO[3][r] *= al;
            const int prow = kg * 4 + r;
#pragma unroll
            for (int t = 0; t < 8; t++)
                Pl[wid][prow][t * 16 + l16] = (f16)p[t];
        }

        // ---- PV: O(16x64) += P(16x128) * V(128x64), via Vt fragments ----
        __builtin_amdgcn_s_setprio(1);
#pragma unroll
        for (int h = 0; h < 4; h++) {
            const f16x8 pa = *(const f16x8*)&Pl[wid][l16][h * 32 + kg * 8];
#pragma unroll
            for (int t = 0; t < 4; t++) {
                const f16x8 vf = *(const f16x8*)&Vl[h * 4 + kg][t * 16 + l16][0];
                accO[t] = __builtin_amdgcn_mfma_f32_16x16x32_f16(pa, vf, accO[t], 0, 0, 0);
            }
        }
        __builtin_amdgcn_s_setprio(0);
    }

    // ---- epilogue: normalize, fp16 store to [B][N][C] ----
    const int b = bh >> 4, hh = bh & 15;
#pragma unroll
    for (int r = 0; r < 4; r++) {
        const float inv = 1.0f / lrow[r];
        const int n = q0 + wid * 16 + kg * 4 + r;
        const size_t base = ((((size_t)b << 10) + n) << 10) + hh * 64;
#pragma unroll
        for (int t = 0; t < 4; t++)
            og[base + t * 16 + l16] = (f16)(accO[t][r] * inv);
    }
}

// ===========================================================================
// Fallback fp32 path (baseline, audited) — used only if ws_size < 96MB.
// ===========================================================================
#define TILE 128
#define KB   16
#define LSTR (TILE + 4)

template<int MODE>
__global__ __launch_bounds__(256, 2)
void gemm_bt(const float* __restrict__ A, const float* __restrict__ Bm,
             const float* __restrict__ bias, float* __restrict__ out0,
             float* __restrict__ qg, float* __restrict__ kg, float* __restrict__ vg,
             int M, int Ncols, int K)
{
    __shared__ float As[KB][LSTR];
    __shared__ float Bs[KB][LSTR];

    const int tid = threadIdx.x;
    const int tr  = tid >> 4;
    const int tc  = tid & 15;
    const int m0  = blockIdx.y * TILE;
    const int n0  = blockIdx.x * TILE;

    const int lrow = tid >> 2;
    const int lcol = (tid & 3) << 2;

    const float* Ap = A  + (size_t)(m0 + lrow) * K + lcol;
    const float* Bp = Bm + (size_t)(n0 + lrow) * K + lcol;
    const size_t rstep = (size_t)64 * K;

    float acc[8][8];
#pragma unroll
    for (int i = 0; i < 8; i++)
#pragma unroll
        for (int j = 0; j < 8; j++) acc[i][j] = 0.f;

    for (int kt = 0; kt < K; kt += KB) {
        float4 a0 = *(const float4*)(Ap + kt);
        float4 a1 = *(const float4*)(Ap + rstep + kt);
        float4 b0 = *(const float4*)(Bp + kt);
        float4 b1 = *(const float4*)(Bp + rstep + kt);
        __syncthreads();
        As[lcol + 0][lrow]      = a0.x;
        As[lcol + 1][lrow]      = a0.y;
        As[lcol + 2][lrow]      = a0.z;
        As[lcol + 3][lrow]      = a0.w;
        As[lcol + 0][lrow + 64] = a1.x;
        As[lcol + 1][lrow + 64] = a1.y;
        As[lcol + 2][lrow + 64] = a1.z;
        As[lcol + 3][lrow + 64] = a1.w;
        Bs[lcol + 0][lrow]      = b0.x;
        Bs[lcol + 1][lrow]      = b0.y;
        Bs[lcol + 2][lrow]      = b0.z;
        Bs[lcol + 3][lrow]      = b0.w;
        Bs[lcol + 0][lrow + 64] = b1.x;
        Bs[lcol + 1][lrow + 64] = b1.y;
        Bs[lcol + 2][lrow + 64] = b1.z;
        Bs[lcol + 3][lrow + 64] = b1.w;
        __syncthreads();
#pragma unroll
        for (int kk = 0; kk < KB; kk++) {
            float ar[8], br[8];
            *(float4*)&ar[0] = *(const float4*)&As[kk][tr << 2];
            *(float4*)&ar[4] = *(const float4*)&As[kk][64 + (tr << 2)];
            *(float4*)&br[0] = *(const float4*)&Bs[kk][tc << 2];
            *(float4*)&br[4] = *(const float4*)&Bs[kk][64 + (tc << 2)];
#pragma unroll
            for (int i = 0; i < 8; i++)
#pragma unroll
                for (int j = 0; j < 8; j++)
                    acc[i][j] = fmaf(ar[i], br[j], acc[i][j]);
        }
    }

#pragma unroll
    for (int rg = 0; rg < 2; rg++) {
#pragma unroll
        for (int ri = 0; ri < 4; ri++) {
            const int m = m0 + rg * 64 + (tr << 2) + ri;
#pragma unroll
            for (int cg = 0; cg < 2; cg++) {
                const int d = n0 + cg * 64 + (tc << 2);
                const float4 bb = *(const float4*)&bias[d];
                float v0 = acc[rg * 4 + ri][cg * 4 + 0] + bb.x;
                float v1 = acc[rg * 4 + ri][cg * 4 + 1] + bb.y;
                float v2 = acc[rg * 4 + ri][cg * 4 + 2] + bb.z;
                float v3 = acc[rg * 4 + ri][cg * 4 + 3] + bb.w;
                if (MODE == 0) {
                    *(float4*)&out0[(size_t)m * Ncols + d] = make_float4(v0, v1, v2, v3);
                } else {
                    const int s  = d >> 10;
                    const int h  = (d >> 6) & 15;
                    const int dh = d & 63;
                    const int b  = m >> 10;
                    const int n  = m & 1023;
                    float* dst = (s == 0) ? qg : ((s == 1) ? kg : vg);
                    if (s == 0) { v0 *= 0.125f; v1 *= 0.125f; v2 *= 0.125f; v3 *= 0.125f; }
                    const size_t idx = (((size_t)((b << 4) + h) << 10) + n) * 64 + dh;
                    *(float4*)&dst[idx] = make_float4(v0, v1, v2, v3);
                }
            }
        }
    }
}

__global__ __launch_bounds__(256, 2)
void attn_flash_f32(const float* __restrict__ qg, const float* __restrict__ kg,
                    const float* __restrict__ vg, float* __restrict__ og)
{
    __shared__ float Qs[64][68];
    __shared__ float KPs[64][68];
    __shared__ float Vs[64][68];

    const int tid = threadIdx.x;
    const int tr  = tid >> 4;
    const int tc  = tid & 15;
    const int bh  = blockIdx.y;
    const int q0  = blockIdx.x << 6;

    const float* qb = qg + ((size_t)bh * SEQ + q0) * DHEAD;
    const float* kb = kg + (size_t)bh * SEQ * DHEAD;
    const float* vb = vg + (size_t)bh * SEQ * DHEAD;

    const int lr = tid >> 4;
    const int lc = (tid & 15) << 2;

#pragma unroll
    for (int i = 0; i < 4; i++) {
        const int r = lr + (i << 4);
        float4 t = *(const float4*)(qb + r * 64 + lc);
        Qs[lc + 0][r] = t.x;
        Qs[lc + 1][r] = t.y;
        Qs[lc + 2][r] = t.z;
        Qs[lc + 3][r] = t.w;
    }

    float m[4], l[4], acc[4][4];
#pragma unroll
    for (int i = 0; i < 4; i++) {
        m[i] = -INFINITY; l[i] = 0.f;
#pragma unroll
        for (int j = 0; j < 4; j++) acc[i][j] = 0.f;
    }

    for (int kt = 0; kt < 16; kt++) {
        __syncthreads();
        const float* kbt = kb + (size_t)(kt << 6) * 64;
        const float* vbt = vb + (size_t)(kt << 6) * 64;
#pragma unroll
        for (int i = 0; i < 4; i++) {
            const int r = lr + (i << 4);
            float4 t = *(const float4*)(kbt + r * 64 + lc);
            KPs[lc + 0][r] = t.x;
            KPs[lc + 1][r] = t.y;
            KPs[lc + 2][r] = t.z;
            KPs[lc + 3][r] = t.w;
            float4 tv = *(const float4*)(vbt + r * 64 + lc);
            *(float4*)&Vs[r][lc] = tv;
        }
        __syncthreads();

        float s[4][4];
#pragma unroll
        for (int i = 0; i < 4; i++)
#pragma unroll
            for (int j = 0; j < 4; j++) s[i][j] = 0.f;
#pragma unroll 4
        for (int d = 0; d < 64; d++) {
            float qa[4], ka[4];
            *(float4*)qa = *(const float4*)&Qs[d][tr << 2];
            *(float4*)ka = *(const float4*)&KPs[d][tc << 2];
#pragma unroll
            for (int ri = 0; ri < 4; ri++)
#pragma unroll
                for (int ci = 0; ci < 4; ci++)
                    s[ri][ci] = fmaf(qa[ri], ka[ci], s[ri][ci]);
        }
        __syncthreads();

#pragma unroll
        for (int ri = 0; ri < 4; ri++) {
            float tm = fmaxf(fmaxf(s[ri][0], s[ri][1]), fmaxf(s[ri][2], s[ri][3]));
            tm = fmaxf(tm, __shfl_xor(tm, 1, 16));
            tm = fmaxf(tm, __shfl_xor(tm, 2, 16));
            tm = fmaxf(tm, __shfl_xor(tm, 4, 16));
            tm = fmaxf(tm, __shfl_xor(tm, 8, 16));
            const float mn = fmaxf(m[ri], tm);
            const float alpha = __expf(m[ri] - mn);
            const float p0 = __expf(s[ri][0] - mn);
            const float p1 = __expf(s[ri][1] - mn);
            const float p2 = __expf(s[ri][2] - mn);
            const float p3 = __expf(s[ri][3] - mn);
            float rs = (p0 + p1) + (p2 + p3);
            rs += __shfl_xor(rs, 1, 16);
            rs += __shfl_xor(rs, 2, 16);
            rs += __shfl_xor(rs, 4, 16);
            rs += __shfl_xor(rs, 8, 16);
            l[ri] = l[ri] * alpha + rs;
            m[ri] = mn;
            acc[ri][0] *= alpha; acc[ri][1] *= alpha;
            acc[ri][2] *= alpha; acc[ri][3] *= alpha;
            *(float4*)&KPs[(tr << 2) + ri][tc << 2] = make_float4(p0, p1, p2, p3);
        }
        __syncthreads();

#pragma unroll 4
        for (int c = 0; c < 64; c += 4) {
            float pr[4][4], vv[4][4];
            *(float4*)pr[0] = *(const float4*)&KPs[(tr << 2) + 0][c];
            *(float4*)pr[1] = *(const float4*)&KPs[(tr << 2) + 1][c];
            *(float4*)pr[2] = *(const float4*)&KPs[(tr << 2) + 2][c];
            *(float4*)pr[3] = *(const float4*)&KPs[(tr << 2) + 3][c];
            *(float4*)vv[0] = *(const float4*)&Vs[c + 0][tc << 2];
            *(float4*)vv[1] = *(const float4*)&Vs[c + 1][tc << 2];
            *(float4*)vv[2] = *(const float4*)&Vs[c + 2][tc << 2];
            *(float4*)vv[3] = *(const float4*)&Vs[c + 3][tc << 2];
#pragma unroll
            for (int ri = 0; ri < 4; ri++)
#pragma unroll
                for (int j = 0; j < 4; j++) {
                    float a = acc[ri][j];
                    a = fmaf(pr[ri][0], vv[0][j], a);
                    a = fmaf(pr[ri][1], vv[1][j], a);
                    a = fmaf(pr[ri][2], vv[2][j], a);
                    a = fmaf(pr[ri][3], vv[3][j], a);
                    acc[ri][j] = a;
                }
        }
    }

    const int b = bh >> 4, h = bh & 15;
#pragma unroll
    for (int ri = 0; ri < 4; ri++) {
        const float inv = 1.0f / l[ri];
        const int n = q0 + (tr << 2) + ri;
        const size_t idx = (((size_t)b * SEQ + n) << 10) + (h << 6) + (tc << 2);
        *(float4*)&og[idx] = make_float4(acc[ri][0] * inv, acc[ri][1] * inv,
                                         acc[ri][2] * inv, acc[ri][3] * inv);
    }
}

// ===========================================================================
extern "C" void kernel_launch(void* const* d_in, const int* in_sizes, int n_in,
                              void* d_out, int out_size, void* d_ws, size_t ws_size,
                              hipStream_t stream)
{
    const float* x     = (const float*)d_in[0];   // [8,1024,1024]
    const float* w_in  = (const float*)d_in[1];   // [3072,1024]
    const float* b_in  = (const float*)d_in[2];   // [3072]
    const float* w_out = (const float*)d_in[3];   // [1024,1024]
    const float* b_out = (const float*)d_in[4];   // [1024]
    float* out = (float*)d_out;                   // [8,1024,1024]
    (void)in_sizes; (void)n_in; (void)out_size;

    const size_t MB  = 1024 * 1024;
    const size_t per = (size_t)BATCH * HEADS * SEQ * DHEAD;  // 8M elements
    const int    M   = BATCH * SEQ;                          // 8192
    char* ws = (char*)d_ws;

    if (ws_size >= 96 * MB) {
        // --- fp16 MFMA path ---
        f16* qf16  = (f16*)(ws + 0 * MB);    // 16MB [BH][N][64]
        f16* kf16  = (f16*)(ws + 16 * MB);   // 16MB [BH][N][64]
        f16* vtf16 = (f16*)(ws + 32 * MB);   // 16MB [BH][64][N]
        f16* xf16  = (f16*)(ws + 48 * MB);   // 16MB (dead after QKV GEMM)
        f16* of16  = xf16;                   // aliased: born after attention
        f16* wif16 = (f16*)(ws + 64 * MB);   // 6MB
        f16* wof16 = (f16*)(ws + 70 * MB);   // 2MB -> 72MB total

        cvt_all<<<1536, 256, 0, stream>>>(x, w_in, w_out, xf16, wif16, wof16);

        // QKV: r13/r16/r17-verified 3-buffer wide kernel (768 blocks)
        gemm_w3<1><<<dim3(3 * CDIM / 256, M / 128), 256, 0, stream>>>(
            xf16, wif16, b_in, nullptr, qf16, kf16, vtf16, 3 * CDIM, CDIM);

        // attention: KVBLK=128 (8 iterations)
        attn_mfma<<<dim3(SEQ / 64, BATCH * HEADS), 256, 0, stream>>>(
            qf16, kf16, vtf16, of16);

        // out-proj: same 3-buffer wide schedule, MODE 0 (256 blocks)
        gemm_w3<0><<<dim3(CDIM / 256, M / 128), 256, 0, stream>>>(
            of16, wof16, b_out, out, nullptr, nullptr, nullptr, CDIM, CDIM);
    } else {
        // --- fp32 fallback path (128MB) ---
        float* qws = (float*)d_ws;
        float* kws = qws + per;
        float* vws = kws + per;
        float* aws = vws + per;

        gemm_bt<1><<<dim3(3 * CDIM / TILE, M / TILE), 256, 0, stream>>>(
            x, w_in, b_in, nullptr, qws, kws, vws, M, 3 * CDIM, CDIM);

        attn_flash_f32<<<dim3(SEQ / 64, BATCH * HEADS), 256, 0, stream>>>(
            qws, kws, vws, aws);

        gemm_bt<0><<<dim3(CDIM / TILE, M / TILE), 256, 0, stream>>>(
            aws, w_out, b_out, out, nullptr, nullptr, nullptr, M, CDIM, CDIM);
    }
}

// Round 19
// 256.892 us; speedup vs baseline: 1.2102x; 1.0222x over previous
//
#include <hip/hip_runtime.h>
#include <math.h>
#include <stdint.h>

// Problem constants: B=8, N=1024, C=1024, H=16, Dh=64
#define SEQ   1024
#define BATCH 8
#define CDIM  1024
#define HEADS 16
#define DHEAD 64

typedef __bf16 bf16;
typedef _Float16 f16;
typedef __attribute__((ext_vector_type(8))) _Float16 f16x8;
typedef __attribute__((ext_vector_type(4))) float f32x4;

// async global->LDS, 16B per lane. LDS dest = wave-uniform base + lane*16.
static __device__ __forceinline__ void gl16(const void* g, void* l) {
    __builtin_amdgcn_global_load_lds(
        (const __attribute__((address_space(1))) void*)(uintptr_t)g,
        (__attribute__((address_space(3))) void*)(uintptr_t)l,
        16, 0, 0);
}

// ===========================================================================
// cvt_all: fused fp32 -> fp16 for x (1048576 vec8), w_in (393216), w_out
// (131072). One launch instead of three.
// ===========================================================================
__global__ __launch_bounds__(256)
void cvt_all(const float* __restrict__ x,  const float* __restrict__ wi,
             const float* __restrict__ wo, f16* __restrict__ xo,
             f16* __restrict__ wio, f16* __restrict__ woo)
{
    const int N1 = 1048576, N2 = 393216;   // vec8 counts for x, w_in
    const int NT = N1 + N2 + 131072;
    int i = blockIdx.x * blockDim.x + threadIdx.x;
    const int stride = gridDim.x * blockDim.x;
    for (; i < NT; i += stride) {
        const float* src; f16* dst; int off;
        if (i < N1)            { src = x;  dst = xo;  off = i; }
        else if (i < N1 + N2)  { src = wi; dst = wio; off = i - N1; }
        else                   { src = wo; dst = woo; off = i - N1 - N2; }
        const f32x4 v0 = *(const f32x4*)(src + (size_t)off * 8);
        const f32x4 v1 = *(const f32x4*)(src + (size_t)off * 8 + 4);
        f16x8 o;
#pragma unroll
        for (int j = 0; j < 4; j++) {
            o[j]     = (f16)v0[j];
            o[j + 4] = (f16)v1[j];
        }
        *(f16x8*)(dst + (size_t)off * 8) = o;
    }
}

// ===========================================================================
// Wide fp16 MFMA GEMM, 3-buffer counted-vmcnt depth-2 pipeline + setprio
// (r17/r18 verified: QKV 125us).  BM=128 x BN=256, BK=32, 4 waves (2x2),
// per-wave 64x128 (acc[4][8], 32 MFMA/K-step).
// LDS 3x(8KB A + 16KB B) = 72KB -> 2 blocks/CU.
// MODE 0: fp32 row-major store (+bias). MODE 1: QKV scatter as fp16.
// ===========================================================================
template<int MODE>
__global__ __launch_bounds__(256, 2)
void gemm_w3(const f16* __restrict__ Ag, const f16* __restrict__ Bg,
             const float* __restrict__ bias, float* __restrict__ out0,
             f16* __restrict__ qg, f16* __restrict__ kgp,
             f16* __restrict__ vgp, int Ncols, int K)
{
    __shared__ f16 As[3][4][128][8];   // 8KB per buffer; byte = (ks*128+row)*16
    __shared__ f16 Bs[3][4][256][8];   // 16KB per buffer; byte = (ks*256+row)*16

    const int m0 = blockIdx.y * 128;
    const int n0 = blockIdx.x * 256;

    const int tid  = threadIdx.x;
    const int wid  = tid >> 6;
    const int lane = tid & 63;
    const int wr   = (wid >> 1) * 64;    // 0/64 (M)
    const int wc   = (wid & 1) * 128;    // 0/128 (N)
    const int l16  = lane & 15;
    const int kgf  = lane >> 4;

    const int akg = tid >> 7, arow = tid & 127;
    const f16* aP = Ag + (size_t)(m0 + arow) * K + akg * 8;
    const f16* bP = Bg + (size_t)(n0 + tid) * K;
    const int loff = wid << 10;

#define STAGE(buf, kt)                                               \
    do {                                                             \
        gl16(aP + (kt),      (char*)As[buf] + loff);                 \
        gl16(aP + (kt) + 16, (char*)As[buf] + loff + 4096);          \
        gl16(bP + (kt),      (char*)Bs[buf] + loff);                 \
        gl16(bP + (kt) + 8,  (char*)Bs[buf] + loff + 4096);         \
        gl16(bP + (kt) + 16, (char*)Bs[buf] + loff + 8192);         \
        gl16(bP + (kt) + 24, (char*)Bs[buf] + loff + 12288);        \
    } while (0)

#define COMPUTE(buf)                                                         \
    do {                                                                     \
        f16x8 fa[4], fb[8];                                                  \
        _Pragma("unroll")                                                    \
        for (int i = 0; i < 4; i++)                                          \
            fa[i] = *(const f16x8*)&As[buf][kgf][wr + i * 16 + l16][0];      \
        _Pragma("unroll")                                                    \
        for (int j = 0; j < 8; j++)                                          \
            fb[j] = *(const f16x8*)&Bs[buf][kgf][wc + j * 16 + l16][0];      \
        __builtin_amdgcn_s_setprio(1);                                       \
        _Pragma("unroll")                                                    \
        for (int i = 0; i < 4; i++)                                          \
            _Pragma("unroll")                                                \
            for (int j = 0; j < 8; j++)                                      \
                acc[i][j] = __builtin_amdgcn_mfma_f32_16x16x32_f16(          \
                    fa[i], fb[j], acc[i][j], 0, 0, 0);                       \
        __builtin_amdgcn_s_setprio(0);                                       \
    } while (0)

    f32x4 acc[4][8];
#pragma unroll
    for (int i = 0; i < 4; i++)
#pragma unroll
        for (int j = 0; j < 8; j++) acc[i][j] = (f32x4)0.f;

    const int T = K >> 5;   // 32 K-tiles

    STAGE(0, 0);
    STAGE(1, 32);

    int cur = 0;
    for (int t = 0; t < T - 2; t++) {
        const int nbuf = (cur == 0) ? 2 : (cur - 1);   // (t+2) % 3
        STAGE(nbuf, (t + 2) << 5);
        asm volatile("s_waitcnt vmcnt(12)" ::: "memory");  // tile t landed
        __builtin_amdgcn_sched_barrier(0);
        __builtin_amdgcn_s_barrier();
        __builtin_amdgcn_sched_barrier(0);
        COMPUTE(cur);
        __builtin_amdgcn_sched_barrier(0);
        __builtin_amdgcn_s_barrier();
        cur = (cur == 2) ? 0 : (cur + 1);
    }

    asm volatile("s_waitcnt vmcnt(6)" ::: "memory");       // tile T-2 landed
    __builtin_amdgcn_sched_barrier(0);
    __builtin_amdgcn_s_barrier();
    __builtin_amdgcn_sched_barrier(0);
    COMPUTE(cur);
    __builtin_amdgcn_sched_barrier(0);
    __builtin_amdgcn_s_barrier();
    cur = (cur == 2) ? 0 : (cur + 1);

    asm volatile("s_waitcnt vmcnt(0)" ::: "memory");
    __builtin_amdgcn_sched_barrier(0);
    __builtin_amdgcn_s_barrier();
    __builtin_amdgcn_sched_barrier(0);
    COMPUTE(cur);

#undef STAGE
#undef COMPUTE

    // epilogue. D layout (verified r4): col=lane&15, row=(lane>>4)*4+reg.
#pragma unroll
    for (int j = 0; j < 8; j++) {
        const int d  = n0 + wc + j * 16 + l16;
        const float bv = bias[d];
        int s = 0, hh = 0, dh = 0;
        if (MODE == 1) {
            s  = d >> 10;
            hh = (d >> 6) & 15;
            dh = d & 63;
        }
#pragma unroll
        for (int i = 0; i < 4; i++) {
            const int mbase = m0 + wr + i * 16 + (lane >> 4) * 4;
#pragma unroll
            for (int r = 0; r < 4; r++) {
                const float v = acc[i][j][r] + bv;
                const int m = mbase + r;
                if (MODE == 0) {
                    out0[(size_t)m * Ncols + d] = v;
                } else {
                    const int b = m >> 10, n = m & 1023;
                    const size_t bho = (size_t)((b << 4) + hh) << 16;
                    if (s == 0)
                        qg[bho + ((size_t)n << 6) + dh] = (f16)(v * 0.125f);
                    else if (s == 1)
                        kgp[bho + ((size_t)n << 6) + dh] = (f16)v;
                    else
                        vgp[bho + ((size_t)dh << 10) + n] = (f16)v;
                }
            }
        }
    }
}

// ===========================================================================
// MFMA flash attention, QBLK=128 x KVBLK=128 (r19): each block covers 128
// q-rows (halves grid to 1024 -> K/V staging traffic halves to 512MB;
// 1024 blocks at 2/CU = exactly 2 full residency rounds, no tail).
// 4 waves; each wave owns 2 groups of 16 q-rows, processed sequentially per
// K-tile (static unroll -> no scratch).  fp16 MFMA QK^T/PV, fp32 online
// softmax, setprio on MFMA clusters.  LDS 49KB.
// Output plain fp16 O to [B][N][C].
// ===========================================================================
__global__ __launch_bounds__(256, 2)
void attn_mfma(const f16* __restrict__ qf, const f16* __restrict__ kf,
               const f16* __restrict__ vtf, f16* __restrict__ og)
{
    __shared__ f16 Kl[8][128][8];    // [d/8][kcol][8]
    __shared__ f16 Vl[16][64][8];    // [k/8][drow][8]
    __shared__ f16 Pl[4][16][136];   // per-wave P: [qrow][kcol], stride 136

    const int tid  = threadIdx.x;
    const int wid  = tid >> 6;
    const int lane = tid & 63;
    const int l16  = lane & 15;
    const int kg   = lane >> 4;      // 0..3
    const int bh   = blockIdx.y;
    const int q0   = blockIdx.x << 7;   // 128 q-rows per block

    const size_t bhoff = (size_t)bh << 16;   // bh * 1024 * 64
    const f16* qb = qf  + bhoff;
    const f16* kb = kf  + bhoff;
    const f16* vb = vtf + bhoff;

    // Q fragments: group g row = q0 + wid*32 + g*16 + l16
    f16x8 qfr[2][2];
#pragma unroll
    for (int g = 0; g < 2; g++) {
        const f16* qrow = qb + ((size_t)(q0 + wid * 32 + g * 16 + l16) << 6);
        qfr[g][0] = *(const f16x8*)(qrow + kg * 8);
        qfr[g][1] = *(const f16x8*)(qrow + 32 + kg * 8);
    }

    float mrow[2][4], lrow[2][4];
    f32x4 accO[2][4];
#pragma unroll
    for (int g = 0; g < 2; g++)
#pragma unroll
        for (int r = 0; r < 4; r++) {
            mrow[g][r] = -INFINITY; lrow[g][r] = 0.f;
            accO[g][r] = (f32x4)0.f;
        }

    // staging: 1024 chunks of 16B per buffer, 4 per thread (c = tid + 256j)
    // Kl chunk c: col = c & 127, slot = c >> 7   (K row-major [col][64])
    // Vl chunk c: drow = c & 63, ks = c >> 6     (Vt [drow][1024])
    f16x8 rk[4], rv[4];
#pragma unroll
    for (int j = 0; j < 4; j++) {
        const int ck = tid + 256 * j;
        rk[j] = *(const f16x8*)(kb + ((size_t)(ck & 127) << 6) + (ck >> 7) * 8);
        rv[j] = *(const f16x8*)(vb + ((size_t)(ck & 63) << 10) + (ck >> 6) * 8);
    }

    for (int kt = 0; kt < 8; kt++) {
        __syncthreads();   // previous iter's K/V fragment reads complete
#pragma unroll
        for (int j = 0; j < 4; j++) {
            const int ck = tid + 256 * j;
            *(f16x8*)&Kl[ck >> 7][ck & 127][0] = rk[j];
            *(f16x8*)&Vl[ck >> 6][ck & 63][0]  = rv[j];
        }
        __syncthreads();

        // issue next tile's global loads; latency hides under compute
        if (kt < 7) {
            const int n1 = (kt + 1) << 7;
#pragma unroll
            for (int j = 0; j < 4; j++) {
                const int ck = tid + 256 * j;
                rk[j] = *(const f16x8*)(kb + ((size_t)(n1 + (ck & 127)) << 6) + (ck >> 7) * 8);
                rv[j] = *(const f16x8*)(vb + ((size_t)(ck & 63) << 10) + n1 + (ck >> 6) * 8);
            }
        }

#pragma unroll
        for (int g = 0; g < 2; g++) {
            // ---- QK^T: group's 16 rows x 128 cols ----
            f32x4 accS[8];
#pragma unroll
            for (int t = 0; t < 8; t++) accS[t] = (f32x4)0.f;
            __builtin_amdgcn_s_setprio(1);
#pragma unroll
            for (int t = 0; t < 8; t++) {
                const f16x8 kf0 = *(const f16x8*)&Kl[kg][t * 16 + l16][0];
                const f16x8 kf1 = *(const f16x8*)&Kl[4 + kg][t * 16 + l16][0];
                accS[t] = __builtin_amdgcn_mfma_f32_16x16x32_f16(qfr[g][0], kf0, accS[t], 0, 0, 0);
                accS[t] = __builtin_amdgcn_mfma_f32_16x16x32_f16(qfr[g][1], kf1, accS[t], 0, 0, 0);
            }
            __builtin_amdgcn_s_setprio(0);

            // ---- online softmax; rows r -> q-row 4*kg + r ----
#pragma unroll
            for (int r = 0; r < 4; r++) {
                float sm = fmaxf(fmaxf(fmaxf(accS[0][r], accS[1][r]),
                                       fmaxf(accS[2][r], accS[3][r])),
                                 fmaxf(fmaxf(accS[4][r], accS[5][r]),
                                       fmaxf(accS[6][r], accS[7][r])));
                sm = fmaxf(sm, __shfl_xor(sm, 1, 16));
                sm = fmaxf(sm, __shfl_xor(sm, 2, 16));
                sm = fmaxf(sm, __shfl_xor(sm, 4, 16));
                sm = fmaxf(sm, __shfl_xor(sm, 8, 16));
                const float mn = fmaxf(mrow[g][r], sm);
                const float al = __expf(mrow[g][r] - mn);
                float p[8], rs = 0.f;
#pragma unroll
                for (int t = 0; t < 8; t++) {
                    p[t] = __expf(accS[t][r] - mn);
                    rs += p[t];
                }
                rs += __shfl_xor(rs, 1, 16);
                rs += __shfl_xor(rs, 2, 16);
                rs += __shfl_xor(rs, 4, 16);
                rs += __shfl_xor(rs, 8, 16);
                lrow[g][r] = lrow[g][r] * al + rs;
                mrow[g][r] = mn;
                accO[g][0][r] *= al;
                accO[g][1][r] *= al;
                accO[g][2][r] *= al;
                accO[g][3][r] *= al;
                const int prow = kg * 4 + r;
#pragma unroll
                for (int t = 0; t < 8; t++)
                    Pl[wid][prow][t * 16 + l16] = (f16)p[t];
            }

            // ---- PV: O(16x64) += P(16x128) * V(128x64) ----
            __builtin_amdgcn_s_setprio(1);
#pragma unroll
            for (int h = 0; h < 4; h++) {
                const f16x8 pa = *(const f16x8*)&Pl[wid][l16][h * 32 + kg * 8];
#pragma unroll
                for (int t = 0; t < 4; t++) {
                    const f16x8 vf = *(const f16x8*)&Vl[h * 4 + kg][t * 16 + l16][0];
                    accO[g][t] = __builtin_amdgcn_mfma_f32_16x16x32_f16(pa, vf, accO[g][t], 0, 0, 0);
                }
            }
            __builtin_amdgcn_s_setprio(0);
        }
    }

    // ---- epilogue: normalize, fp16 store to [B][N][C] ----
    const int b = bh >> 4, hh = bh & 15;
#pragma unroll
    for (int g = 0; g < 2; g++)
#pragma unroll
        for (int r = 0; r < 4; r++) {
            const float inv = 1.0f / lrow[g][r];
            const int n = q0 + wid * 32 + g * 16 + kg * 4 + r;
            const size_t base = ((((size_t)b << 10) + n) << 10) + hh * 64;
#pragma unroll
            for (int t = 0; t < 4; t++)
                og[base + t * 16 + l16] = (f16)(accO[g][t][r] * inv);
        }
}

// ===========================================================================
// Fallback fp32 path (baseline, audited) — used only if ws_size < 96MB.
// ===========================================================================
#define TILE 128
#define KB   16
#define LSTR (TILE + 4)

template<int MODE>
__global__ __launch_bounds__(256, 2)
void gemm_bt(const float* __restrict__ A, const float* __restrict__ Bm,
             const float* __restrict__ bias, float* __restrict__ out0,
             float* __restrict__ qg, float* __restrict__ kg, float* __restrict__ vg,
             int M, int Ncols, int K)
{
    __shared__ float As[KB][LSTR];
    __shared__ float Bs[KB][LSTR];

    const int tid = threadIdx.x;
    const int tr  = tid >> 4;
    const int tc  = tid & 15;
    const int m0  = blockIdx.y * TILE;
    const int n0  = blockIdx.x * TILE;

    const int lrow = tid >> 2;
    const int lcol = (tid & 3) << 2;

    const float* Ap = A  + (size_t)(m0 + lrow) * K + lcol;
    const float* Bp = Bm + (size_t)(n0 + lrow) * K + lcol;
    const size_t rstep = (size_t)64 * K;

    float acc[8][8];
#pragma unroll
    for (int i = 0; i < 8; i++)
#pragma unroll
        for (int j = 0; j < 8; j++) acc[i][j] = 0.f;

    for (int kt = 0; kt < K; kt += KB) {
        float4 a0 = *(const float4*)(Ap + kt);
        float4 a1 = *(const float4*)(Ap + rstep + kt);
        float4 b0 = *(const float4*)(Bp + kt);
        float4 b1 = *(const float4*)(Bp + rstep + kt);
        __syncthreads();
        As[lcol + 0][lrow]      = a0.x;
        As[lcol + 1][lrow]      = a0.y;
        As[lcol + 2][lrow]      = a0.z;
        As[lcol + 3][lrow]      = a0.w;
        As[lcol + 0][lrow + 64] = a1.x;
        As[lcol + 1][lrow + 64] = a1.y;
        As[lcol + 2][lrow + 64] = a1.z;
        As[lcol + 3][lrow + 64] = a1.w;
        Bs[lcol + 0][lrow]      = b0.x;
        Bs[lcol + 1][lrow]      = b0.y;
        Bs[lcol + 2][lrow]      = b0.z;
        Bs[lcol + 3][lrow]      = b0.w;
        Bs[lcol + 0][lrow + 64] = b1.x;
        Bs[lcol + 1][lrow + 64] = b1.y;
        Bs[lcol + 2][lrow + 64] = b1.z;
        Bs[lcol + 3][lrow + 64] = b1.w;
        __syncthreads();
#pragma unroll
        for (int kk = 0; kk < KB; kk++) {
            float ar[8], br[8];
            *(float4*)&ar[0] = *(const float4*)&As[kk][tr << 2];
            *(float4*)&ar[4] = *(const float4*)&As[kk][64 + (tr << 2)];
            *(float4*)&br[0] = *(const float4*)&Bs[kk][tc << 2];
            *(float4*)&br[4] = *(const float4*)&Bs[kk][64 + (tc << 2)];
#pragma unroll
            for (int i = 0; i < 8; i++)
#pragma unroll
                for (int j = 0; j < 8; j++)
                    acc[i][j] = fmaf(ar[i], br[j], acc[i][j]);
        }
    }

#pragma unroll
    for (int rg = 0; rg < 2; rg++) {
#pragma unroll
        for (int ri = 0; ri < 4; ri++) {
            const int m = m0 + rg * 64 + (tr << 2) + ri;
#pragma unroll
            for (int cg = 0; cg < 2; cg++) {
                const int d = n0 + cg * 64 + (tc << 2);
                const float4 bb = *(const float4*)&bias[d];
                float v0 = acc[rg * 4 + ri][cg * 4 + 0] + bb.x;
                float v1 = acc[rg * 4 + ri][cg * 4 + 1] + bb.y;
                float v2 = acc[rg * 4 + ri][cg * 4 + 2] + bb.z;
                float v3 = acc[rg * 4 + ri][cg * 4 + 3] + bb.w;
                if (MODE == 0) {
                    *(float4*)&out0[(size_t)m * Ncols + d] = make_float4(v0, v1, v2, v3);
                } else {
                    const int s  = d >> 10;
                    const int h  = (d >> 6) & 15;
                    const int dh = d & 63;
                    const int b  = m >> 10;
                    const int n  = m & 1023;
                    float* dst = (s == 0) ? qg : ((s == 1) ? kg : vg);
                    if (s == 0) { v0 *= 0.125f; v1 *= 0.125f; v2 *= 0.125f; v3 *= 0.125f; }
                    const size_t idx = (((size_t)((b << 4) + h) << 10) + n) * 64 + dh;
                    *(float4*)&dst[idx] = make_float4(v0, v1, v2, v3);
                }
            }
        }
    }
}

__global__ __launch_bounds__(256, 2)
void attn_flash_f32(const float* __restrict__ qg, const float* __restrict__ kg,
                    const float* __restrict__ vg, float* __restrict__ og)
{
    __shared__ float Qs[64][68];
    __shared__ float KPs[64][68];
    __shared__ float Vs[64][68];

    const int tid = threadIdx.x;
    const int tr  = tid >> 4;
    const int tc  = tid & 15;
    const int bh  = blockIdx.y;
    const int q0  = blockIdx.x << 6;

    const float* qb = qg + ((size_t)bh * SEQ + q0) * DHEAD;
    const float* kb = kg + (size_t)bh * SEQ * DHEAD;
    const float* vb = vg + (size_t)bh * SEQ * DHEAD;

    const int lr = tid >> 4;
    const int lc = (tid & 15) << 2;

#pragma unroll
    for (int i = 0; i < 4; i++) {
        const int r = lr + (i << 4);
        float4 t = *(const float4*)(qb + r * 64 + lc);
        Qs[lc + 0][r] = t.x;
        Qs[lc + 1][r] = t.y;
        Qs[lc + 2][r] = t.z;
        Qs[lc + 3][r] = t.w;
    }

    float m[4], l[4], acc[4][4];
#pragma unroll
    for (int i = 0; i < 4; i++) {
        m[i] = -INFINITY; l[i] = 0.f;
#pragma unroll
        for (int j = 0; j < 4; j++) acc[i][j] = 0.f;
    }

    for (int kt = 0; kt < 16; kt++) {
        __syncthreads();
        const float* kbt = kb + (size_t)(kt << 6) * 64;
        const float* vbt = vb + (size_t)(kt << 6) * 64;
#pragma unroll
        for (int i = 0; i < 4; i++) {
            const int r = lr + (i << 4);
            float4 t = *(const float4*)(kbt + r * 64 + lc);
            KPs[lc + 0][r] = t.x;
            KPs[lc + 1][r] = t.y;
            KPs[lc + 2][r] = t.z;
            KPs[lc + 3][r] = t.w;
            float4 tv = *(const float4*)(vbt + r * 64 + lc);
            *(float4*)&Vs[r][lc] = tv;
        }
        __syncthreads();

        float s[4][4];
#pragma unroll
        for (int i = 0; i < 4; i++)
#pragma unroll
            for (int j = 0; j < 4; j++) s[i][j] = 0.f;
#pragma unroll 4
        for (int d = 0; d < 64; d++) {
            float qa[4], ka[4];
            *(float4*)qa = *(const float4*)&Qs[d][tr << 2];
            *(float4*)ka = *(const float4*)&KPs[d][tc << 2];
#pragma unroll
            for (int ri = 0; ri < 4; ri++)
#pragma unroll
                for (int ci = 0; ci < 4; ci++)
                    s[ri][ci] = fmaf(qa[ri], ka[ci], s[ri][ci]);
        }
        __syncthreads();

#pragma unroll
        for (int ri = 0; ri < 4; ri++) {
            float tm = fmaxf(fmaxf(s[ri][0], s[ri][1]), fmaxf(s[ri][2], s[ri][3]));
            tm = fmaxf(tm, __shfl_xor(tm, 1, 16));
            tm = fmaxf(tm, __shfl_xor(tm, 2, 16));
            tm = fmaxf(tm, __shfl_xor(tm, 4, 16));
            tm = fmaxf(tm, __shfl_xor(tm, 8, 16));
            const float mn = fmaxf(m[ri], tm);
            const float alpha = __expf(m[ri] - mn);
            const float p0 = __expf(s[ri][0] - mn);
            const float p1 = __expf(s[ri][1] - mn);
            const float p2 = __expf(s[ri][2] - mn);
            const float p3 = __expf(s[ri][3] - mn);
            float rs = (p0 + p1) + (p2 + p3);
            rs += __shfl_xor(rs, 1, 16);
            rs += __shfl_xor(rs, 2, 16);
            rs += __shfl_xor(rs, 4, 16);
            rs += __shfl_xor(rs, 8, 16);
            l[ri] = l[ri] * alpha + rs;
            m[ri] = mn;
            acc[ri][0] *= alpha; acc[ri][1] *= alpha;
            acc[ri][2] *= alpha; acc[ri][3] *= alpha;
            *(float4*)&KPs[(tr << 2) + ri][tc << 2] = make_float4(p0, p1, p2, p3);
        }
        __syncthreads();

#pragma unroll 4
        for (int c = 0; c < 64; c += 4) {
            float pr[4][4], vv[4][4];
            *(float4*)pr[0] = *(const float4*)&KPs[(tr << 2) + 0][c];
            *(float4*)pr[1] = *(const float4*)&KPs[(tr << 2) + 1][c];
            *(float4*)pr[2] = *(const float4*)&KPs[(tr << 2) + 2][c];
            *(float4*)pr[3] = *(const float4*)&KPs[(tr << 2) + 3][c];
            *(float4*)vv[0] = *(const float4*)&Vs[c + 0][tc << 2];
            *(float4*)vv[1] = *(const float4*)&Vs[c + 1][tc << 2];
            *(float4*)vv[2] = *(const float4*)&Vs[c + 2][tc << 2];
            *(float4*)vv[3] = *(const float4*)&Vs[c + 3][tc << 2];
#pragma unroll
            for (int ri = 0; ri < 4; ri++)
#pragma unroll
                for (int j = 0; j < 4; j++) {
                    float a = acc[ri][j];
                    a = fmaf(pr[ri][0], vv[0][j], a);
                    a = fmaf(pr[ri][1], vv[1][j], a);
                    a = fmaf(pr[ri][2], vv[2][j], a);
                    a = fmaf(pr[ri][3], vv[3][j], a);
                    acc[ri][j] = a;
                }
        }
    }

    const int b = bh >> 4, h = bh & 15;
#pragma unroll
    for (int ri = 0; ri < 4; ri++) {
        const float inv = 1.0f / l[ri];
        const int n = q0 + (tr << 2) + ri;
        const size_t idx = (((size_t)b * SEQ + n) << 10) + (h << 6) + (tc << 2);
        *(float4*)&og[idx] = make_float4(acc[ri][0] * inv, acc[ri][1] * inv,
                                         acc[ri][2] * inv, acc[ri][3] * inv);
    }
}

// ===========================================================================
extern "C" void kernel_launch(void* const* d_in, const int* in_sizes, int n_in,
                              void* d_out, int out_size, void* d_ws, size_t ws_size,
                              hipStream_t stream)
{
    const float* x     = (const float*)d_in[0];   // [8,1024,1024]
    const float* w_in  = (const float*)d_in[1];   // [3072,1024]
    const float* b_in  = (const float*)d_in[2];   // [3072]
    const float* w_out = (const float*)d_in[3];   // [1024,1024]
    const float* b_out = (const float*)d_in[4];   // [1024]
    float* out = (float*)d_out;                   // [8,1024,1024]
    (void)in_sizes; (void)n_in; (void)out_size;

    const size_t MB  = 1024 * 1024;
    const size_t per = (size_t)BATCH * HEADS * SEQ * DHEAD;  // 8M elements
    const int    M   = BATCH * SEQ;                          // 8192
    char* ws = (char*)d_ws;

    if (ws_size >= 96 * MB) {
        // --- fp16 MFMA path ---
        f16* qf16  = (f16*)(ws + 0 * MB);    // 16MB [BH][N][64]
        f16* kf16  = (f16*)(ws + 16 * MB);   // 16MB [BH][N][64]
        f16* vtf16 = (f16*)(ws + 32 * MB);   // 16MB [BH][64][N]
        f16* xf16  = (f16*)(ws + 48 * MB);   // 16MB (dead after QKV GEMM)
        f16* of16  = xf16;                   // aliased: born after attention
        f16* wif16 = (f16*)(ws + 64 * MB);   // 6MB
        f16* wof16 = (f16*)(ws + 70 * MB);   // 2MB -> 72MB total

        cvt_all<<<1536, 256, 0, stream>>>(x, w_in, w_out, xf16, wif16, wof16);

        // QKV: r13/r16/r17-verified 3-buffer wide kernel (768 blocks)
        gemm_w3<1><<<dim3(3 * CDIM / 256, M / 128), 256, 0, stream>>>(
            xf16, wif16, b_in, nullptr, qf16, kf16, vtf16, 3 * CDIM, CDIM);

        // attention: QBLK=128 x KVBLK=128 (1024 blocks, 2 residency rounds)
        attn_mfma<<<dim3(SEQ / 128, BATCH * HEADS), 256, 0, stream>>>(
            qf16, kf16, vtf16, of16);

        // out-proj: same 3-buffer wide schedule, MODE 0 (256 blocks)
        gemm_w3<0><<<dim3(CDIM / 256, M / 128), 256, 0, stream>>>(
            of16, wof16, b_out, out, nullptr, nullptr, nullptr, CDIM, CDIM);
    } else {
        // --- fp32 fallback path (128MB) ---
        float* qws = (float*)d_ws;
        float* kws = qws + per;
        float* vws = kws + per;
        float* aws = vws + per;

        gemm_bt<1><<<dim3(3 * CDIM / TILE, M / TILE), 256, 0, stream>>>(
            x, w_in, b_in, nullptr, qws, kws, vws, M, 3 * CDIM, CDIM);

        attn_flash_f32<<<dim3(SEQ / 64, BATCH * HEADS), 256, 0, stream>>>(
            qws, kws, vws, aws);

        gemm_bt<0><<<dim3(CDIM / TILE, M / TILE), 256, 0, stream>>>(
            aws, w_out, b_out, out, nullptr, nullptr, nullptr, M, CDIM, CDIM);
    }
}

// Round 20
// 251.719 us; speedup vs baseline: 1.2350x; 1.0206x over previous
//
#include <hip/hip_runtime.h>
#include <math.h>
#include <stdint.h>

// Problem constants: B=8, N=1024, C=1024, H=16, Dh=64
#define SEQ   1024
#define BATCH 8
#define CDIM  1024
#define HEADS 16
#define DHEAD 64

typedef __bf16 bf16;
typedef _Float16 f16;
typedef __attribute__((ext_vector_type(8))) _Float16 f16x8;
typedef __attribute__((ext_vector_type(4))) float f32x4;

// async global->LDS, 16B per lane. LDS dest = wave-uniform base + lane*16.
static __device__ __forceinline__ void gl16(const void* g, void* l) {
    __builtin_amdgcn_global_load_lds(
        (const __attribute__((address_space(1))) void*)(uintptr_t)g,
        (__attribute__((address_space(3))) void*)(uintptr_t)l,
        16, 0, 0);
}

// ===========================================================================
// cvt_all: fused fp32 -> fp16 for x (1048576 vec8), w_in (393216), w_out
// (131072). One launch instead of three.
// ===========================================================================
__global__ __launch_bounds__(256)
void cvt_all(const float* __restrict__ x,  const float* __restrict__ wi,
             const float* __restrict__ wo, f16* __restrict__ xo,
             f16* __restrict__ wio, f16* __restrict__ woo)
{
    const int N1 = 1048576, N2 = 393216;   // vec8 counts for x, w_in
    const int NT = N1 + N2 + 131072;
    int i = blockIdx.x * blockDim.x + threadIdx.x;
    const int stride = gridDim.x * blockDim.x;
    for (; i < NT; i += stride) {
        const float* src; f16* dst; int off;
        if (i < N1)            { src = x;  dst = xo;  off = i; }
        else if (i < N1 + N2)  { src = wi; dst = wio; off = i - N1; }
        else                   { src = wo; dst = woo; off = i - N1 - N2; }
        const f32x4 v0 = *(const f32x4*)(src + (size_t)off * 8);
        const f32x4 v1 = *(const f32x4*)(src + (size_t)off * 8 + 4);
        f16x8 o;
#pragma unroll
        for (int j = 0; j < 4; j++) {
            o[j]     = (f16)v0[j];
            o[j + 4] = (f16)v1[j];
        }
        *(f16x8*)(dst + (size_t)off * 8) = o;
    }
}

// ===========================================================================
// Wide fp16 MFMA GEMM, 3-buffer counted-vmcnt depth-2 pipeline + setprio
// (r17/r18/r19 verified: QKV 125us).  BM=128 x BN=256, BK=32, 4 waves (2x2),
// per-wave 64x128 (acc[4][8], 32 MFMA/K-step).
// LDS 3x(8KB A + 16KB B) = 72KB -> 2 blocks/CU.
// MODE 0: fp32 row-major store (+bias). MODE 1: QKV scatter as fp16.
// ===========================================================================
template<int MODE>
__global__ __launch_bounds__(256, 2)
void gemm_w3(const f16* __restrict__ Ag, const f16* __restrict__ Bg,
             const float* __restrict__ bias, float* __restrict__ out0,
             f16* __restrict__ qg, f16* __restrict__ kgp,
             f16* __restrict__ vgp, int Ncols, int K)
{
    __shared__ f16 As[3][4][128][8];   // 8KB per buffer; byte = (ks*128+row)*16
    __shared__ f16 Bs[3][4][256][8];   // 16KB per buffer; byte = (ks*256+row)*16

    const int m0 = blockIdx.y * 128;
    const int n0 = blockIdx.x * 256;

    const int tid  = threadIdx.x;
    const int wid  = tid >> 6;
    const int lane = tid & 63;
    const int wr   = (wid >> 1) * 64;    // 0/64 (M)
    const int wc   = (wid & 1) * 128;    // 0/128 (N)
    const int l16  = lane & 15;
    const int kgf  = lane >> 4;

    const int akg = tid >> 7, arow = tid & 127;
    const f16* aP = Ag + (size_t)(m0 + arow) * K + akg * 8;
    const f16* bP = Bg + (size_t)(n0 + tid) * K;
    const int loff = wid << 10;

#define STAGE(buf, kt)                                               \
    do {                                                             \
        gl16(aP + (kt),      (char*)As[buf] + loff);                 \
        gl16(aP + (kt) + 16, (char*)As[buf] + loff + 4096);          \
        gl16(bP + (kt),      (char*)Bs[buf] + loff);                 \
        gl16(bP + (kt) + 8,  (char*)Bs[buf] + loff + 4096);         \
        gl16(bP + (kt) + 16, (char*)Bs[buf] + loff + 8192);         \
        gl16(bP + (kt) + 24, (char*)Bs[buf] + loff + 12288);        \
    } while (0)

#define COMPUTE(buf)                                                         \
    do {                                                                     \
        f16x8 fa[4], fb[8];                                                  \
        _Pragma("unroll")                                                    \
        for (int i = 0; i < 4; i++)                                          \
            fa[i] = *(const f16x8*)&As[buf][kgf][wr + i * 16 + l16][0];      \
        _Pragma("unroll")                                                    \
        for (int j = 0; j < 8; j++)                                          \
            fb[j] = *(const f16x8*)&Bs[buf][kgf][wc + j * 16 + l16][0];      \
        __builtin_amdgcn_s_setprio(1);                                       \
        _Pragma("unroll")                                                    \
        for (int i = 0; i < 4; i++)                                          \
            _Pragma("unroll")                                                \
            for (int j = 0; j < 8; j++)                                      \
                acc[i][j] = __builtin_amdgcn_mfma_f32_16x16x32_f16(          \
                    fa[i], fb[j], acc[i][j], 0, 0, 0);                       \
        __builtin_amdgcn_s_setprio(0);                                       \
    } while (0)

    f32x4 acc[4][8];
#pragma unroll
    for (int i = 0; i < 4; i++)
#pragma unroll
        for (int j = 0; j < 8; j++) acc[i][j] = (f32x4)0.f;

    const int T = K >> 5;   // 32 K-tiles

    STAGE(0, 0);
    STAGE(1, 32);

    int cur = 0;
    for (int t = 0; t < T - 2; t++) {
        const int nbuf = (cur == 0) ? 2 : (cur - 1);   // (t+2) % 3
        STAGE(nbuf, (t + 2) << 5);
        asm volatile("s_waitcnt vmcnt(12)" ::: "memory");  // tile t landed
        __builtin_amdgcn_sched_barrier(0);
        __builtin_amdgcn_s_barrier();
        __builtin_amdgcn_sched_barrier(0);
        COMPUTE(cur);
        __builtin_amdgcn_sched_barrier(0);
        __builtin_amdgcn_s_barrier();
        cur = (cur == 2) ? 0 : (cur + 1);
    }

    asm volatile("s_waitcnt vmcnt(6)" ::: "memory");       // tile T-2 landed
    __builtin_amdgcn_sched_barrier(0);
    __builtin_amdgcn_s_barrier();
    __builtin_amdgcn_sched_barrier(0);
    COMPUTE(cur);
    __builtin_amdgcn_sched_barrier(0);
    __builtin_amdgcn_s_barrier();
    cur = (cur == 2) ? 0 : (cur + 1);

    asm volatile("s_waitcnt vmcnt(0)" ::: "memory");
    __builtin_amdgcn_sched_barrier(0);
    __builtin_amdgcn_s_barrier();
    __builtin_amdgcn_sched_barrier(0);
    COMPUTE(cur);

#undef STAGE
#undef COMPUTE

    // epilogue. D layout (verified r4): col=lane&15, row=(lane>>4)*4+reg.
#pragma unroll
    for (int j = 0; j < 8; j++) {
        const int d  = n0 + wc + j * 16 + l16;
        const float bv = bias[d];
        int s = 0, hh = 0, dh = 0;
        if (MODE == 1) {
            s  = d >> 10;
            hh = (d >> 6) & 15;
            dh = d & 63;
        }
#pragma unroll
        for (int i = 0; i < 4; i++) {
            const int mbase = m0 + wr + i * 16 + (lane >> 4) * 4;
#pragma unroll
            for (int r = 0; r < 4; r++) {
                const float v = acc[i][j][r] + bv;
                const int m = mbase + r;
                if (MODE == 0) {
                    out0[(size_t)m * Ncols + d] = v;
                } else {
                    const int b = m >> 10, n = m & 1023;
                    const size_t bho = (size_t)((b << 4) + hh) << 16;
                    if (s == 0)
                        qg[bho + ((size_t)n << 6) + dh] = (f16)(v * 0.125f);
                    else if (s == 1)
                        kgp[bho + ((size_t)n << 6) + dh] = (f16)v;
                    else
                        vgp[bho + ((size_t)dh << 10) + n] = (f16)v;
                }
            }
        }
    }
}

// ===========================================================================
// MFMA flash attention, QBLK=256 x KVBLK=128 (r20): each block covers 256
// q-rows (grid 512 = exactly one residency round at 2/CU; K/V staging
// traffic halves again to 128MB).  4 waves; each wave owns 4 groups of 16
// q-rows, processed sequentially per K-tile (static unroll).  fp16 MFMA
// QK^T/PV, fp32 online softmax, setprio on MFMA clusters.  LDS 49KB.
// Output plain fp16 O to [B][N][C].
// ===========================================================================
__global__ __launch_bounds__(256, 2)
void attn_mfma(const f16* __restrict__ qf, const f16* __restrict__ kf,
               const f16* __restrict__ vtf, f16* __restrict__ og)
{
    __shared__ f16 Kl[8][128][8];    // [d/8][kcol][8]
    __shared__ f16 Vl[16][64][8];    // [k/8][drow][8]
    __shared__ f16 Pl[4][16][136];   // per-wave P: [qrow][kcol], stride 136

    const int tid  = threadIdx.x;
    const int wid  = tid >> 6;
    const int lane = tid & 63;
    const int l16  = lane & 15;
    const int kg   = lane >> 4;      // 0..3
    const int bh   = blockIdx.y;
    const int q0   = blockIdx.x << 8;   // 256 q-rows per block

    const size_t bhoff = (size_t)bh << 16;   // bh * 1024 * 64
    const f16* qb = qf  + bhoff;
    const f16* kb = kf  + bhoff;
    const f16* vb = vtf + bhoff;

    // Q fragments: group g row = q0 + wid*64 + g*16 + l16
    f16x8 qfr[4][2];
#pragma unroll
    for (int g = 0; g < 4; g++) {
        const f16* qrow = qb + ((size_t)(q0 + wid * 64 + g * 16 + l16) << 6);
        qfr[g][0] = *(const f16x8*)(qrow + kg * 8);
        qfr[g][1] = *(const f16x8*)(qrow + 32 + kg * 8);
    }

    float mrow[4][4], lrow[4][4];
    f32x4 accO[4][4];
#pragma unroll
    for (int g = 0; g < 4; g++)
#pragma unroll
        for (int r = 0; r < 4; r++) {
            mrow[g][r] = -INFINITY; lrow[g][r] = 0.f;
            accO[g][r] = (f32x4)0.f;
        }

    // staging: 1024 chunks of 16B per buffer, 4 per thread (c = tid + 256j)
    // Kl chunk c: col = c & 127, slot = c >> 7   (K row-major [col][64])
    // Vl chunk c: drow = c & 63, ks = c >> 6     (Vt [drow][1024])
    f16x8 rk[4], rv[4];
#pragma unroll
    for (int j = 0; j < 4; j++) {
        const int ck = tid + 256 * j;
        rk[j] = *(const f16x8*)(kb + ((size_t)(ck & 127) << 6) + (ck >> 7) * 8);
        rv[j] = *(const f16x8*)(vb + ((size_t)(ck & 63) << 10) + (ck >> 6) * 8);
    }

    for (int kt = 0; kt < 8; kt++) {
        __syncthreads();   // previous iter's K/V fragment reads complete
#pragma unroll
        for (int j = 0; j < 4; j++) {
            const int ck = tid + 256 * j;
            *(f16x8*)&Kl[ck >> 7][ck & 127][0] = rk[j];
            *(f16x8*)&Vl[ck >> 6][ck & 63][0]  = rv[j];
        }
        __syncthreads();

        // issue next tile's global loads; latency hides under compute
        if (kt < 7) {
            const int n1 = (kt + 1) << 7;
#pragma unroll
            for (int j = 0; j < 4; j++) {
                const int ck = tid + 256 * j;
                rk[j] = *(const f16x8*)(kb + ((size_t)(n1 + (ck & 127)) << 6) + (ck >> 7) * 8);
                rv[j] = *(const f16x8*)(vb + ((size_t)(ck & 63) << 10) + n1 + (ck >> 6) * 8);
            }
        }

#pragma unroll
        for (int g = 0; g < 4; g++) {
            // ---- QK^T: group's 16 rows x 128 cols ----
            f32x4 accS[8];
#pragma unroll
            for (int t = 0; t < 8; t++) accS[t] = (f32x4)0.f;
            __builtin_amdgcn_s_setprio(1);
#pragma unroll
            for (int t = 0; t < 8; t++) {
                const f16x8 kf0 = *(const f16x8*)&Kl[kg][t * 16 + l16][0];
                const f16x8 kf1 = *(const f16x8*)&Kl[4 + kg][t * 16 + l16][0];
                accS[t] = __builtin_amdgcn_mfma_f32_16x16x32_f16(qfr[g][0], kf0, accS[t], 0, 0, 0);
                accS[t] = __builtin_amdgcn_mfma_f32_16x16x32_f16(qfr[g][1], kf1, accS[t], 0, 0, 0);
            }
            __builtin_amdgcn_s_setprio(0);

            // ---- online softmax; rows r -> q-row 4*kg + r ----
#pragma unroll
            for (int r = 0; r < 4; r++) {
                float sm = fmaxf(fmaxf(fmaxf(accS[0][r], accS[1][r]),
                                       fmaxf(accS[2][r], accS[3][r])),
                                 fmaxf(fmaxf(accS[4][r], accS[5][r]),
                                       fmaxf(accS[6][r], accS[7][r])));
                sm = fmaxf(sm, __shfl_xor(sm, 1, 16));
                sm = fmaxf(sm, __shfl_xor(sm, 2, 16));
                sm = fmaxf(sm, __shfl_xor(sm, 4, 16));
                sm = fmaxf(sm, __shfl_xor(sm, 8, 16));
                const float mn = fmaxf(mrow[g][r], sm);
                const float al = __expf(mrow[g][r] - mn);
                float p[8], rs = 0.f;
#pragma unroll
                for (int t = 0; t < 8; t++) {
                    p[t] = __expf(accS[t][r] - mn);
                    rs += p[t];
                }
                rs += __shfl_xor(rs, 1, 16);
                rs += __shfl_xor(rs, 2, 16);
                rs += __shfl_xor(rs, 4, 16);
                rs += __shfl_xor(rs, 8, 16);
                lrow[g][r] = lrow[g][r] * al + rs;
                mrow[g][r] = mn;
                accO[g][0][r] *= al;
                accO[g][1][r] *= al;
                accO[g][2][r] *= al;
                accO[g][3][r] *= al;
                const int prow = kg * 4 + r;
#pragma unroll
                for (int t = 0; t < 8; t++)
                    Pl[wid][prow][t * 16 + l16] = (f16)p[t];
            }

            // ---- PV: O(16x64) += P(16x128) * V(128x64) ----
            __builtin_amdgcn_s_setprio(1);
#pragma unroll
            for (int h = 0; h < 4; h++) {
                const f16x8 pa = *(const f16x8*)&Pl[wid][l16][h * 32 + kg * 8];
#pragma unroll
                for (int t = 0; t < 4; t++) {
                    const f16x8 vf = *(const f16x8*)&Vl[h * 4 + kg][t * 16 + l16][0];
                    accO[g][t] = __builtin_amdgcn_mfma_f32_16x16x32_f16(pa, vf, accO[g][t], 0, 0, 0);
                }
            }
            __builtin_amdgcn_s_setprio(0);
        }
    }

    // ---- epilogue: normalize, fp16 store to [B][N][C] ----
    const int b = bh >> 4, hh = bh & 15;
#pragma unroll
    for (int g = 0; g < 4; g++)
#pragma unroll
        for (int r = 0; r < 4; r++) {
            const float inv = 1.0f / lrow[g][r];
            const int n = q0 + wid * 64 + g * 16 + kg * 4 + r;
            const size_t base = ((((size_t)b << 10) + n) << 10) + hh * 64;
#pragma unroll
            for (int t = 0; t < 4; t++)
                og[base + t * 16 + l16] = (f16)(accO[g][t][r] * inv);
        }
}

// ===========================================================================
// Fallback fp32 path (baseline, audited) — used only if ws_size < 96MB.
// ===========================================================================
#define TILE 128
#define KB   16
#define LSTR (TILE + 4)

template<int MODE>
__global__ __launch_bounds__(256, 2)
void gemm_bt(const float* __restrict__ A, const float* __restrict__ Bm,
             const float* __restrict__ bias, float* __restrict__ out0,
             float* __restrict__ qg, float* __restrict__ kg, float* __restrict__ vg,
             int M, int Ncols, int K)
{
    __shared__ float As[KB][LSTR];
    __shared__ float Bs[KB][LSTR];

    const int tid = threadIdx.x;
    const int tr  = tid >> 4;
    const int tc  = tid & 15;
    const int m0  = blockIdx.y * TILE;
    const int n0  = blockIdx.x * TILE;

    const int lrow = tid >> 2;
    const int lcol = (tid & 3) << 2;

    const float* Ap = A  + (size_t)(m0 + lrow) * K + lcol;
    const float* Bp = Bm + (size_t)(n0 + lrow) * K + lcol;
    const size_t rstep = (size_t)64 * K;

    float acc[8][8];
#pragma unroll
    for (int i = 0; i < 8; i++)
#pragma unroll
        for (int j = 0; j < 8; j++) acc[i][j] = 0.f;

    for (int kt = 0; kt < K; kt += KB) {
        float4 a0 = *(const float4*)(Ap + kt);
        float4 a1 = *(const float4*)(Ap + rstep + kt);
        float4 b0 = *(const float4*)(Bp + kt);
        float4 b1 = *(const float4*)(Bp + rstep + kt);
        __syncthreads();
        As[lcol + 0][lrow]      = a0.x;
        As[lcol + 1][lrow]      = a0.y;
        As[lcol + 2][lrow]      = a0.z;
        As[lcol + 3][lrow]      = a0.w;
        As[lcol + 0][lrow + 64] = a1.x;
        As[lcol + 1][lrow + 64] = a1.y;
        As[lcol + 2][lrow + 64] = a1.z;
        As[lcol + 3][lrow + 64] = a1.w;
        Bs[lcol + 0][lrow]      = b0.x;
        Bs[lcol + 1][lrow]      = b0.y;
        Bs[lcol + 2][lrow]      = b0.z;
        Bs[lcol + 3][lrow]      = b0.w;
        Bs[lcol + 0][lrow + 64] = b1.x;
        Bs[lcol + 1][lrow + 64] = b1.y;
        Bs[lcol + 2][lrow + 64] = b1.z;
        Bs[lcol + 3][lrow + 64] = b1.w;
        __syncthreads();
#pragma unroll
        for (int kk = 0; kk < KB; kk++) {
            float ar[8], br[8];
            *(float4*)&ar[0] = *(const float4*)&As[kk][tr << 2];
            *(float4*)&ar[4] = *(const float4*)&As[kk][64 + (tr << 2)];
            *(float4*)&br[0] = *(const float4*)&Bs[kk][tc << 2];
            *(float4*)&br[4] = *(const float4*)&Bs[kk][64 + (tc << 2)];
#pragma unroll
            for (int i = 0; i < 8; i++)
#pragma unroll
                for (int j = 0; j < 8; j++)
                    acc[i][j] = fmaf(ar[i], br[j], acc[i][j]);
        }
    }

#pragma unroll
    for (int rg = 0; rg < 2; rg++) {
#pragma unroll
        for (int ri = 0; ri < 4; ri++) {
            const int m = m0 + rg * 64 + (tr << 2) + ri;
#pragma unroll
            for (int cg = 0; cg < 2; cg++) {
                const int d = n0 + cg * 64 + (tc << 2);
                const float4 bb = *(const float4*)&bias[d];
                float v0 = acc[rg * 4 + ri][cg * 4 + 0] + bb.x;
                float v1 = acc[rg * 4 + ri][cg * 4 + 1] + bb.y;
                float v2 = acc[rg * 4 + ri][cg * 4 + 2] + bb.z;
                float v3 = acc[rg * 4 + ri][cg * 4 + 3] + bb.w;
                if (MODE == 0) {
                    *(float4*)&out0[(size_t)m * Ncols + d] = make_float4(v0, v1, v2, v3);
                } else {
                    const int s  = d >> 10;
                    const int h  = (d >> 6) & 15;
                    const int dh = d & 63;
                    const int b  = m >> 10;
                    const int n  = m & 1023;
                    float* dst = (s == 0) ? qg : ((s == 1) ? kg : vg);
                    if (s == 0) { v0 *= 0.125f; v1 *= 0.125f; v2 *= 0.125f; v3 *= 0.125f; }
                    const size_t idx = (((size_t)((b << 4) + h) << 10) + n) * 64 + dh;
                    *(float4*)&dst[idx] = make_float4(v0, v1, v2, v3);
                }
            }
        }
    }
}

__global__ __launch_bounds__(256, 2)
void attn_flash_f32(const float* __restrict__ qg, const float* __restrict__ kg,
                    const float* __restrict__ vg, float* __restrict__ og)
{
    __shared__ float Qs[64][68];
    __shared__ float KPs[64][68];
    __shared__ float Vs[64][68];

    const int tid = threadIdx.x;
    const int tr  = tid >> 4;
    const int tc  = tid & 15;
    const int bh  = blockIdx.y;
    const int q0  = blockIdx.x << 6;

    const float* qb = qg + ((size_t)bh * SEQ + q0) * DHEAD;
    const float* kb = kg + (size_t)bh * SEQ * DHEAD;
    const float* vb = vg + (size_t)bh * SEQ * DHEAD;

    const int lr = tid >> 4;
    const int lc = (tid & 15) << 2;

#pragma unroll
    for (int i = 0; i < 4; i++) {
        const int r = lr + (i << 4);
        float4 t = *(const float4*)(qb + r * 64 + lc);
        Qs[lc + 0][r] = t.x;
        Qs[lc + 1][r] = t.y;
        Qs[lc + 2][r] = t.z;
        Qs[lc + 3][r] = t.w;
    }

    float m[4], l[4], acc[4][4];
#pragma unroll
    for (int i = 0; i < 4; i++) {
        m[i] = -INFINITY; l[i] = 0.f;
#pragma unroll
        for (int j = 0; j < 4; j++) acc[i][j] = 0.f;
    }

    for (int kt = 0; kt < 16; kt++) {
        __syncthreads();
        const float* kbt = kb + (size_t)(kt << 6) * 64;
        const float* vbt = vb + (size_t)(kt << 6) * 64;
#pragma unroll
        for (int i = 0; i < 4; i++) {
            const int r = lr + (i << 4);
            float4 t = *(const float4*)(kbt + r * 64 + lc);
            KPs[lc + 0][r] = t.x;
            KPs[lc + 1][r] = t.y;
            KPs[lc + 2][r] = t.z;
            KPs[lc + 3][r] = t.w;
            float4 tv = *(const float4*)(vbt + r * 64 + lc);
            *(float4*)&Vs[r][lc] = tv;
        }
        __syncthreads();

        float s[4][4];
#pragma unroll
        for (int i = 0; i < 4; i++)
#pragma unroll
            for (int j = 0; j < 4; j++) s[i][j] = 0.f;
#pragma unroll 4
        for (int d = 0; d < 64; d++) {
            float qa[4], ka[4];
            *(float4*)qa = *(const float4*)&Qs[d][tr << 2];
            *(float4*)ka = *(const float4*)&KPs[d][tc << 2];
#pragma unroll
            for (int ri = 0; ri < 4; ri++)
#pragma unroll
                for (int ci = 0; ci < 4; ci++)
                    s[ri][ci] = fmaf(qa[ri], ka[ci], s[ri][ci]);
        }
        __syncthreads();

#pragma unroll
        for (int ri = 0; ri < 4; ri++) {
            float tm = fmaxf(fmaxf(s[ri][0], s[ri][1]), fmaxf(s[ri][2], s[ri][3]));
            tm = fmaxf(tm, __shfl_xor(tm, 1, 16));
            tm = fmaxf(tm, __shfl_xor(tm, 2, 16));
            tm = fmaxf(tm, __shfl_xor(tm, 4, 16));
            tm = fmaxf(tm, __shfl_xor(tm, 8, 16));
            const float mn = fmaxf(m[ri], tm);
            const float alpha = __expf(m[ri] - mn);
            const float p0 = __expf(s[ri][0] - mn);
            const float p1 = __expf(s[ri][1] - mn);
            const float p2 = __expf(s[ri][2] - mn);
            const float p3 = __expf(s[ri][3] - mn);
            float rs = (p0 + p1) + (p2 + p3);
            rs += __shfl_xor(rs, 1, 16);
            rs += __shfl_xor(rs, 2, 16);
            rs += __shfl_xor(rs, 4, 16);
            rs += __shfl_xor(rs, 8, 16);
            l[ri] = l[ri] * alpha + rs;
            m[ri] = mn;
            acc[ri][0] *= alpha; acc[ri][1] *= alpha;
            acc[ri][2] *= alpha; acc[ri][3] *= alpha;
            *(float4*)&KPs[(tr << 2) + ri][tc << 2] = make_float4(p0, p1, p2, p3);
        }
        __syncthreads();

#pragma unroll 4
        for (int c = 0; c < 64; c += 4) {
            float pr[4][4], vv[4][4];
            *(float4*)pr[0] = *(const float4*)&KPs[(tr << 2) + 0][c];
            *(float4*)pr[1] = *(const float4*)&KPs[(tr << 2) + 1][c];
            *(float4*)pr[2] = *(const float4*)&KPs[(tr << 2) + 2][c];
            *(float4*)pr[3] = *(const float4*)&KPs[(tr << 2) + 3][c];
            *(float4*)vv[0] = *(const float4*)&Vs[c + 0][tc << 2];
            *(float4*)vv[1] = *(const float4*)&Vs[c + 1][tc << 2];
            *(float4*)vv[2] = *(const float4*)&Vs[c + 2][tc << 2];
            *(float4*)vv[3] = *(const float4*)&Vs[c + 3][tc << 2];
#pragma unroll
            for (int ri = 0; ri < 4; ri++)
#pragma unroll
                for (int j = 0; j < 4; j++) {
                    float a = acc[ri][j];
                    a = fmaf(pr[ri][0], vv[0][j], a);
                    a = fmaf(pr[ri][1], vv[1][j], a);
                    a = fmaf(pr[ri][2], vv[2][j], a);
                    a = fmaf(pr[ri][3], vv[3][j], a);
                    acc[ri][j] = a;
                }
        }
    }

    const int b = bh >> 4, h = bh & 15;
#pragma unroll
    for (int ri = 0; ri < 4; ri++) {
        const float inv = 1.0f / l[ri];
        const int n = q0 + (tr << 2) + ri;
        const size_t idx = (((size_t)b * SEQ + n) << 10) + (h << 6) + (tc << 2);
        *(float4*)&og[idx] = make_float4(acc[ri][0] * inv, acc[ri][1] * inv,
                                         acc[ri][2] * inv, acc[ri][3] * inv);
    }
}

// ===========================================================================
extern "C" void kernel_launch(void* const* d_in, const int* in_sizes, int n_in,
                              void* d_out, int out_size, void* d_ws, size_t ws_size,
                              hipStream_t stream)
{
    const float* x     = (const float*)d_in[0];   // [8,1024,1024]
    const float* w_in  = (const float*)d_in[1];   // [3072,1024]
    const float* b_in  = (const float*)d_in[2];   // [3072]
    const float* w_out = (const float*)d_in[3];   // [1024,1024]
    const float* b_out = (const float*)d_in[4];   // [1024]
    float* out = (float*)d_out;                   // [8,1024,1024]
    (void)in_sizes; (void)n_in; (void)out_size;

    const size_t MB  = 1024 * 1024;
    const size_t per = (size_t)BATCH * HEADS * SEQ * DHEAD;  // 8M elements
    const int    M   = BATCH * SEQ;                          // 8192
    char* ws = (char*)d_ws;

    if (ws_size >= 96 * MB) {
        // --- fp16 MFMA path ---
        f16* qf16  = (f16*)(ws + 0 * MB);    // 16MB [BH][N][64]
        f16* kf16  = (f16*)(ws + 16 * MB);   // 16MB [BH][N][64]
        f16* vtf16 = (f16*)(ws + 32 * MB);   // 16MB [BH][64][N]
        f16* xf16  = (f16*)(ws + 48 * MB);   // 16MB (dead after QKV GEMM)
        f16* of16  = xf16;                   // aliased: born after attention
        f16* wif16 = (f16*)(ws + 64 * MB);   // 6MB
        f16* wof16 = (f16*)(ws + 70 * MB);   // 2MB -> 72MB total

        cvt_all<<<1536, 256, 0, stream>>>(x, w_in, w_out, xf16, wif16, wof16);

        // QKV: r13/r16/r17-verified 3-buffer wide kernel (768 blocks)
        gemm_w3<1><<<dim3(3 * CDIM / 256, M / 128), 256, 0, stream>>>(
            xf16, wif16, b_in, nullptr, qf16, kf16, vtf16, 3 * CDIM, CDIM);

        // attention: QBLK=256 x KVBLK=128 (512 blocks, 1 residency round)
        attn_mfma<<<dim3(SEQ / 256, BATCH * HEADS), 256, 0, stream>>>(
            qf16, kf16, vtf16, of16);

        // out-proj: same 3-buffer wide schedule, MODE 0 (256 blocks)
        gemm_w3<0><<<dim3(CDIM / 256, M / 128), 256, 0, stream>>>(
            of16, wof16, b_out, out, nullptr, nullptr, nullptr, CDIM, CDIM);
    } else {
        // --- fp32 fallback path (128MB) ---
        float* qws = (float*)d_ws;
        float* kws = qws + per;
        float* vws = kws + per;
        float* aws = vws + per;

        gemm_bt<1><<<dim3(3 * CDIM / TILE, M / TILE), 256, 0, stream>>>(
            x, w_in, b_in, nullptr, qws, kws, vws, M, 3 * CDIM, CDIM);

        attn_flash_f32<<<dim3(SEQ / 64, BATCH * HEADS), 256, 0, stream>>>(
            qws, kws, vws, aws);

        gemm_bt<0><<<dim3(CDIM / TILE, M / TILE), 256, 0, stream>>>(
            aws, w_out, b_out, out, nullptr, nullptr, nullptr, M, CDIM, CDIM);
    }
}

// Round 21
// 249.250 us; speedup vs baseline: 1.2473x; 1.0099x over previous
//
#include <hip/hip_runtime.h>
#include <math.h>
#include <stdint.h>

// Problem constants: B=8, N=1024, C=1024, H=16, Dh=64
#define SEQ   1024
#define BATCH 8
#define CDIM  1024
#define HEADS 16
#define DHEAD 64

typedef __bf16 bf16;
typedef _Float16 f16;
typedef __attribute__((ext_vector_type(8))) _Float16 f16x8;
typedef __attribute__((ext_vector_type(4))) float f32x4;

// async global->LDS, 16B per lane. LDS dest = wave-uniform base + lane*16.
static __device__ __forceinline__ void gl16(const void* g, void* l) {
    __builtin_amdgcn_global_load_lds(
        (const __attribute__((address_space(1))) void*)(uintptr_t)g,
        (__attribute__((address_space(3))) void*)(uintptr_t)l,
        16, 0, 0);
}

// ===========================================================================
// cvt_all: fused fp32 -> fp16 for x (1048576 vec8), w_in (393216), w_out
// (131072). One launch instead of three.
// ===========================================================================
__global__ __launch_bounds__(256)
void cvt_all(const float* __restrict__ x,  const float* __restrict__ wi,
             const float* __restrict__ wo, f16* __restrict__ xo,
             f16* __restrict__ wio, f16* __restrict__ woo)
{
    const int N1 = 1048576, N2 = 393216;   // vec8 counts for x, w_in
    const int NT = N1 + N2 + 131072;
    int i = blockIdx.x * blockDim.x + threadIdx.x;
    const int stride = gridDim.x * blockDim.x;
    for (; i < NT; i += stride) {
        const float* src; f16* dst; int off;
        if (i < N1)            { src = x;  dst = xo;  off = i; }
        else if (i < N1 + N2)  { src = wi; dst = wio; off = i - N1; }
        else                   { src = wo; dst = woo; off = i - N1 - N2; }
        const f32x4 v0 = *(const f32x4*)(src + (size_t)off * 8);
        const f32x4 v1 = *(const f32x4*)(src + (size_t)off * 8 + 4);
        f16x8 o;
#pragma unroll
        for (int j = 0; j < 4; j++) {
            o[j]     = (f16)v0[j];
            o[j + 4] = (f16)v1[j];
        }
        *(f16x8*)(dst + (size_t)off * 8) = o;
    }
}

// ===========================================================================
// Wide fp16 MFMA GEMM, 3-buffer counted-vmcnt depth-2 pipeline + setprio
// (r17-r20 verified: QKV 125us).  BM=128 x BN=256, BK=32, 4 waves (2x2),
// per-wave 64x128 (acc[4][8], 32 MFMA/K-step).
// LDS 3x(8KB A + 16KB B) = 72KB -> 2 blocks/CU.
// MODE 0: fp32 row-major store (+bias). MODE 1: QKV scatter as fp16.
// ===========================================================================
template<int MODE>
__global__ __launch_bounds__(256, 2)
void gemm_w3(const f16* __restrict__ Ag, const f16* __restrict__ Bg,
             const float* __restrict__ bias, float* __restrict__ out0,
             f16* __restrict__ qg, f16* __restrict__ kgp,
             f16* __restrict__ vgp, int Ncols, int K)
{
    __shared__ f16 As[3][4][128][8];   // 8KB per buffer; byte = (ks*128+row)*16
    __shared__ f16 Bs[3][4][256][8];   // 16KB per buffer; byte = (ks*256+row)*16

    const int m0 = blockIdx.y * 128;
    const int n0 = blockIdx.x * 256;

    const int tid  = threadIdx.x;
    const int wid  = tid >> 6;
    const int lane = tid & 63;
    const int wr   = (wid >> 1) * 64;    // 0/64 (M)
    const int wc   = (wid & 1) * 128;    // 0/128 (N)
    const int l16  = lane & 15;
    const int kgf  = lane >> 4;

    const int akg = tid >> 7, arow = tid & 127;
    const f16* aP = Ag + (size_t)(m0 + arow) * K + akg * 8;
    const f16* bP = Bg + (size_t)(n0 + tid) * K;
    const int loff = wid << 10;

#define STAGE(buf, kt)                                               \
    do {                                                             \
        gl16(aP + (kt),      (char*)As[buf] + loff);                 \
        gl16(aP + (kt) + 16, (char*)As[buf] + loff + 4096);          \
        gl16(bP + (kt),      (char*)Bs[buf] + loff);                 \
        gl16(bP + (kt) + 8,  (char*)Bs[buf] + loff + 4096);         \
        gl16(bP + (kt) + 16, (char*)Bs[buf] + loff + 8192);         \
        gl16(bP + (kt) + 24, (char*)Bs[buf] + loff + 12288);        \
    } while (0)

#define COMPUTE(buf)                                                         \
    do {                                                                     \
        f16x8 fa[4], fb[8];                                                  \
        _Pragma("unroll")                                                    \
        for (int i = 0; i < 4; i++)                                          \
            fa[i] = *(const f16x8*)&As[buf][kgf][wr + i * 16 + l16][0];      \
        _Pragma("unroll")                                                    \
        for (int j = 0; j < 8; j++)                                          \
            fb[j] = *(const f16x8*)&Bs[buf][kgf][wc + j * 16 + l16][0];      \
        __builtin_amdgcn_s_setprio(1);                                       \
        _Pragma("unroll")                                                    \
        for (int i = 0; i < 4; i++)                                          \
            _Pragma("unroll")                                                \
            for (int j = 0; j < 8; j++)                                      \
                acc[i][j] = __builtin_amdgcn_mfma_f32_16x16x32_f16(          \
                    fa[i], fb[j], acc[i][j], 0, 0, 0);                       \
        __builtin_amdgcn_s_setprio(0);                                       \
    } while (0)

    f32x4 acc[4][8];
#pragma unroll
    for (int i = 0; i < 4; i++)
#pragma unroll
        for (int j = 0; j < 8; j++) acc[i][j] = (f32x4)0.f;

    const int T = K >> 5;   // 32 K-tiles

    STAGE(0, 0);
    STAGE(1, 32);

    int cur = 0;
    for (int t = 0; t < T - 2; t++) {
        const int nbuf = (cur == 0) ? 2 : (cur - 1);   // (t+2) % 3
        STAGE(nbuf, (t + 2) << 5);
        asm volatile("s_waitcnt vmcnt(12)" ::: "memory");  // tile t landed
        __builtin_amdgcn_sched_barrier(0);
        __builtin_amdgcn_s_barrier();
        __builtin_amdgcn_sched_barrier(0);
        COMPUTE(cur);
        __builtin_amdgcn_sched_barrier(0);
        __builtin_amdgcn_s_barrier();
        cur = (cur == 2) ? 0 : (cur + 1);
    }

    asm volatile("s_waitcnt vmcnt(6)" ::: "memory");       // tile T-2 landed
    __builtin_amdgcn_sched_barrier(0);
    __builtin_amdgcn_s_barrier();
    __builtin_amdgcn_sched_barrier(0);
    COMPUTE(cur);
    __builtin_amdgcn_sched_barrier(0);
    __builtin_amdgcn_s_barrier();
    cur = (cur == 2) ? 0 : (cur + 1);

    asm volatile("s_waitcnt vmcnt(0)" ::: "memory");
    __builtin_amdgcn_sched_barrier(0);
    __builtin_amdgcn_s_barrier();
    __builtin_amdgcn_sched_barrier(0);
    COMPUTE(cur);

#undef STAGE
#undef COMPUTE

    // epilogue. D layout (verified r4): col=lane&15, row=(lane>>4)*4+reg.
#pragma unroll
    for (int j = 0; j < 8; j++) {
        const int d  = n0 + wc + j * 16 + l16;
        const float bv = bias[d];
        int s = 0, hh = 0, dh = 0;
        if (MODE == 1) {
            s  = d >> 10;
            hh = (d >> 6) & 15;
            dh = d & 63;
        }
#pragma unroll
        for (int i = 0; i < 4; i++) {
            const int mbase = m0 + wr + i * 16 + (lane >> 4) * 4;
#pragma unroll
            for (int r = 0; r < 4; r++) {
                const float v = acc[i][j][r] + bv;
                const int m = mbase + r;
                if (MODE == 0) {
                    out0[(size_t)m * Ncols + d] = v;
                } else {
                    const int b = m >> 10, n = m & 1023;
                    const size_t bho = (size_t)((b << 4) + hh) << 16;
                    if (s == 0)
                        qg[bho + ((size_t)n << 6) + dh] = (f16)(v * 0.125f);
                    else if (s == 1)
                        kgp[bho + ((size_t)n << 6) + dh] = (f16)v;
                    else
                        vgp[bho + ((size_t)dh << 10) + n] = (f16)v;
                }
            }
        }
    }
}

// ===========================================================================
// MFMA flash attention, QBLK=512 x KVBLK=128, 8 waves (r21): one block per
// half-sequence per (b,h) -> grid 256 = one residency round at 1 block/CU;
// K/V staging traffic halves again to 64MB.  Each wave owns 4 groups of 16
// q-rows (static unroll).  fp16 MFMA QK^T/PV, fp32 online softmax, setprio.
// LDS: Kl 16KB + Vl 16KB + Pl[8][16][136] 34.8KB = 67KB -> 1 block/CU
// (8 waves = 2/SIMD, VGPR budget 256 -- same as r20's passing config).
// Output plain fp16 O to [B][N][C].
// ===========================================================================
__global__ __launch_bounds__(512, 1)
void attn_mfma(const f16* __restrict__ qf, const f16* __restrict__ kf,
               const f16* __restrict__ vtf, f16* __restrict__ og)
{
    __shared__ f16 Kl[8][128][8];    // [d/8][kcol][8]
    __shared__ f16 Vl[16][64][8];    // [k/8][drow][8]
    __shared__ f16 Pl[8][16][136];   // per-wave P: [qrow][kcol], stride 136

    const int tid  = threadIdx.x;
    const int wid  = tid >> 6;       // 0..7
    const int lane = tid & 63;
    const int l16  = lane & 15;
    const int kg   = lane >> 4;      // 0..3
    const int bh   = blockIdx.y;
    const int q0   = blockIdx.x << 9;   // 512 q-rows per block

    const size_t bhoff = (size_t)bh << 16;   // bh * 1024 * 64
    const f16* qb = qf  + bhoff;
    const f16* kb = kf  + bhoff;
    const f16* vb = vtf + bhoff;

    // Q fragments: group g row = q0 + wid*64 + g*16 + l16
    f16x8 qfr[4][2];
#pragma unroll
    for (int g = 0; g < 4; g++) {
        const f16* qrow = qb + ((size_t)(q0 + wid * 64 + g * 16 + l16) << 6);
        qfr[g][0] = *(const f16x8*)(qrow + kg * 8);
        qfr[g][1] = *(const f16x8*)(qrow + 32 + kg * 8);
    }

    float mrow[4][4], lrow[4][4];
    f32x4 accO[4][4];
#pragma unroll
    for (int g = 0; g < 4; g++)
#pragma unroll
        for (int r = 0; r < 4; r++) {
            mrow[g][r] = -INFINITY; lrow[g][r] = 0.f;
            accO[g][r] = (f32x4)0.f;
        }

    // staging: 1024 chunks of 16B per buffer, 2 per thread (c = tid + 512j)
    // Kl chunk c: col = c & 127, slot = c >> 7   (K row-major [col][64])
    // Vl chunk c: drow = c & 63, ks = c >> 6     (Vt [drow][1024])
    f16x8 rk[2], rv[2];
#pragma unroll
    for (int j = 0; j < 2; j++) {
        const int ck = tid + 512 * j;
        rk[j] = *(const f16x8*)(kb + ((size_t)(ck & 127) << 6) + (ck >> 7) * 8);
        rv[j] = *(const f16x8*)(vb + ((size_t)(ck & 63) << 10) + (ck >> 6) * 8);
    }

    for (int kt = 0; kt < 8; kt++) {
        __syncthreads();   // previous iter's K/V fragment reads complete
#pragma unroll
        for (int j = 0; j < 2; j++) {
            const int ck = tid + 512 * j;
            *(f16x8*)&Kl[ck >> 7][ck & 127][0] = rk[j];
            *(f16x8*)&Vl[ck >> 6][ck & 63][0]  = rv[j];
        }
        __syncthreads();

        // issue next tile's global loads; latency hides under compute
        if (kt < 7) {
            const int n1 = (kt + 1) << 7;
#pragma unroll
            for (int j = 0; j < 2; j++) {
                const int ck = tid + 512 * j;
                rk[j] = *(const f16x8*)(kb + ((size_t)(n1 + (ck & 127)) << 6) + (ck >> 7) * 8);
                rv[j] = *(const f16x8*)(vb + ((size_t)(ck & 63) << 10) + n1 + (ck >> 6) * 8);
            }
        }

#pragma unroll
        for (int g = 0; g < 4; g++) {
            // ---- QK^T: group's 16 rows x 128 cols ----
            f32x4 accS[8];
#pragma unroll
            for (int t = 0; t < 8; t++) accS[t] = (f32x4)0.f;
            __builtin_amdgcn_s_setprio(1);
#pragma unroll
            for (int t = 0; t < 8; t++) {
                const f16x8 kf0 = *(const f16x8*)&Kl[kg][t * 16 + l16][0];
                const f16x8 kf1 = *(const f16x8*)&Kl[4 + kg][t * 16 + l16][0];
                accS[t] = __builtin_amdgcn_mfma_f32_16x16x32_f16(qfr[g][0], kf0, accS[t], 0, 0, 0);
                accS[t] = __builtin_amdgcn_mfma_f32_16x16x32_f16(qfr[g][1], kf1, accS[t], 0, 0, 0);
            }
            __builtin_amdgcn_s_setprio(0);

            // ---- online softmax; rows r -> q-row 4*kg + r ----
#pragma unroll
            for (int r = 0; r < 4; r++) {
                float sm = fmaxf(fmaxf(fmaxf(accS[0][r], accS[1][r]),
                                       fmaxf(accS[2][r], accS[3][r])),
                                 fmaxf(fmaxf(accS[4][r], accS[5][r]),
                                       fmaxf(accS[6][r], accS[7][r])));
                sm = fmaxf(sm, __shfl_xor(sm, 1, 16));
                sm = fmaxf(sm, __shfl_xor(sm, 2, 16));
                sm = fmaxf(sm, __shfl_xor(sm, 4, 16));
                sm = fmaxf(sm, __shfl_xor(sm, 8, 16));
                const float mn = fmaxf(mrow[g][r], sm);
                const float al = __expf(mrow[g][r] - mn);
                float p[8], rs = 0.f;
#pragma unroll
                for (int t = 0; t < 8; t++) {
                    p[t] = __expf(accS[t][r] - mn);
                    rs += p[t];
                }
                rs += __shfl_xor(rs, 1, 16);
                rs += __shfl_xor(rs, 2, 16);
                rs += __shfl_xor(rs, 4, 16);
                rs += __shfl_xor(rs, 8, 16);
                lrow[g][r] = lrow[g][r] * al + rs;
                mrow[g][r] = mn;
                accO[g][0][r] *= al;
                accO[g][1][r] *= al;
                accO[g][2][r] *= al;
                accO[g][3][r] *= al;
                const int prow = kg * 4 + r;
#pragma unroll
                for (int t = 0; t < 8; t++)
                    Pl[wid][prow][t * 16 + l16] = (f16)p[t];
            }

            // ---- PV: O(16x64) += P(16x128) * V(128x64) ----
            __builtin_amdgcn_s_setprio(1);
#pragma unroll
            for (int h = 0; h < 4; h++) {
                const f16x8 pa = *(const f16x8*)&Pl[wid][l16][h * 32 + kg * 8];
#pragma unroll
                for (int t = 0; t < 4; t++) {
                    const f16x8 vf = *(const f16x8*)&Vl[h * 4 + kg][t * 16 + l16][0];
                    accO[g][t] = __builtin_amdgcn_mfma_f32_16x16x32_f16(pa, vf, accO[g][t], 0, 0, 0);
                }
            }
            __builtin_amdgcn_s_setprio(0);
        }
    }

    // ---- epilogue: normalize, fp16 store to [B][N][C] ----
    const int b = bh >> 4, hh = bh & 15;
#pragma unroll
    for (int g = 0; g < 4; g++)
#pragma unroll
        for (int r = 0; r < 4; r++) {
            const float inv = 1.0f / lrow[g][r];
            const int n = q0 + wid * 64 + g * 16 + kg * 4 + r;
            const size_t base = ((((size_t)b << 10) + n) << 10) + hh * 64;
#pragma unroll
            for (int t = 0; t < 4; t++)
                og[base + t * 16 + l16] = (f16)(accO[g][t][r] * inv);
        }
}

// ===========================================================================
// Fallback fp32 path (baseline, audited) — used only if ws_size < 96MB.
// ===========================================================================
#define TILE 128
#define KB   16
#define LSTR (TILE + 4)

template<int MODE>
__global__ __launch_bounds__(256, 2)
void gemm_bt(const float* __restrict__ A, const float* __restrict__ Bm,
             const float* __restrict__ bias, float* __restrict__ out0,
             float* __restrict__ qg, float* __restrict__ kg, float* __restrict__ vg,
             int M, int Ncols, int K)
{
    __shared__ float As[KB][LSTR];
    __shared__ float Bs[KB][LSTR];

    const int tid = threadIdx.x;
    const int tr  = tid >> 4;
    const int tc  = tid & 15;
    const int m0  = blockIdx.y * TILE;
    const int n0  = blockIdx.x * TILE;

    const int lrow = tid >> 2;
    const int lcol = (tid & 3) << 2;

    const float* Ap = A  + (size_t)(m0 + lrow) * K + lcol;
    const float* Bp = Bm + (size_t)(n0 + lrow) * K + lcol;
    const size_t rstep = (size_t)64 * K;

    float acc[8][8];
#pragma unroll
    for (int i = 0; i < 8; i++)
#pragma unroll
        for (int j = 0; j < 8; j++) acc[i][j] = 0.f;

    for (int kt = 0; kt < K; kt += KB) {
        float4 a0 = *(const float4*)(Ap + kt);
        float4 a1 = *(const float4*)(Ap + rstep + kt);
        float4 b0 = *(const float4*)(Bp + kt);
        float4 b1 = *(const float4*)(Bp + rstep + kt);
        __syncthreads();
        As[lcol + 0][lrow]      = a0.x;
        As[lcol + 1][lrow]      = a0.y;
        As[lcol + 2][lrow]      = a0.z;
        As[lcol + 3][lrow]      = a0.w;
        As[lcol + 0][lrow + 64] = a1.x;
        As[lcol + 1][lrow + 64] = a1.y;
        As[lcol + 2][lrow + 64] = a1.z;
        As[lcol + 3][lrow + 64] = a1.w;
        Bs[lcol + 0][lrow]      = b0.x;
        Bs[lcol + 1][lrow]      = b0.y;
        Bs[lcol + 2][lrow]      = b0.z;
        Bs[lcol + 3][lrow]      = b0.w;
        Bs[lcol + 0][lrow + 64] = b1.x;
        Bs[lcol + 1][lrow + 64] = b1.y;
        Bs[lcol + 2][lrow + 64] = b1.z;
        Bs[lcol + 3][lrow + 64] = b1.w;
        __syncthreads();
#pragma unroll
        for (int kk = 0; kk < KB; kk++) {
            float ar[8], br[8];
            *(float4*)&ar[0] = *(const float4*)&As[kk][tr << 2];
            *(float4*)&ar[4] = *(const float4*)&As[kk][64 + (tr << 2)];
            *(float4*)&br[0] = *(const float4*)&Bs[kk][tc << 2];
            *(float4*)&br[4] = *(const float4*)&Bs[kk][64 + (tc << 2)];
#pragma unroll
            for (int i = 0; i < 8; i++)
#pragma unroll
                for (int j = 0; j < 8; j++)
                    acc[i][j] = fmaf(ar[i], br[j], acc[i][j]);
        }
    }

#pragma unroll
    for (int rg = 0; rg < 2; rg++) {
#pragma unroll
        for (int ri = 0; ri < 4; ri++) {
            const int m = m0 + rg * 64 + (tr << 2) + ri;
#pragma unroll
            for (int cg = 0; cg < 2; cg++) {
                const int d = n0 + cg * 64 + (tc << 2);
                const float4 bb = *(const float4*)&bias[d];
                float v0 = acc[rg * 4 + ri][cg * 4 + 0] + bb.x;
                float v1 = acc[rg * 4 + ri][cg * 4 + 1] + bb.y;
                float v2 = acc[rg * 4 + ri][cg * 4 + 2] + bb.z;
                float v3 = acc[rg * 4 + ri][cg * 4 + 3] + bb.w;
                if (MODE == 0) {
                    *(float4*)&out0[(size_t)m * Ncols + d] = make_float4(v0, v1, v2, v3);
                } else {
                    const int s  = d >> 10;
                    const int h  = (d >> 6) & 15;
                    const int dh = d & 63;
                    const int b  = m >> 10;
                    const int n  = m & 1023;
                    float* dst = (s == 0) ? qg : ((s == 1) ? kg : vg);
                    if (s == 0) { v0 *= 0.125f; v1 *= 0.125f; v2 *= 0.125f; v3 *= 0.125f; }
                    const size_t idx = (((size_t)((b << 4) + h) << 10) + n) * 64 + dh;
                    *(float4*)&dst[idx] = make_float4(v0, v1, v2, v3);
                }
            }
        }
    }
}

__global__ __launch_bounds__(256, 2)
void attn_flash_f32(const float* __restrict__ qg, const float* __restrict__ kg,
                    const float* __restrict__ vg, float* __restrict__ og)
{
    __shared__ float Qs[64][68];
    __shared__ float KPs[64][68];
    __shared__ float Vs[64][68];

    const int tid = threadIdx.x;
    const int tr  = tid >> 4;
    const int tc  = tid & 15;
    const int bh  = blockIdx.y;
    const int q0  = blockIdx.x << 6;

    const float* qb = qg + ((size_t)bh * SEQ + q0) * DHEAD;
    const float* kb = kg + (size_t)bh * SEQ * DHEAD;
    const float* vb = vg + (size_t)bh * SEQ * DHEAD;

    const int lr = tid >> 4;
    const int lc = (tid & 15) << 2;

#pragma unroll
    for (int i = 0; i < 4; i++) {
        const int r = lr + (i << 4);
        float4 t = *(const float4*)(qb + r * 64 + lc);
        Qs[lc + 0][r] = t.x;
        Qs[lc + 1][r] = t.y;
        Qs[lc + 2][r] = t.z;
        Qs[lc + 3][r] = t.w;
    }

    float m[4], l[4], acc[4][4];
#pragma unroll
    for (int i = 0; i < 4; i++) {
        m[i] = -INFINITY; l[i] = 0.f;
#pragma unroll
        for (int j = 0; j < 4; j++) acc[i][j] = 0.f;
    }

    for (int kt = 0; kt < 16; kt++) {
        __syncthreads();
        const float* kbt = kb + (size_t)(kt << 6) * 64;
        const float* vbt = vb + (size_t)(kt << 6) * 64;
#pragma unroll
        for (int i = 0; i < 4; i++) {
            const int r = lr + (i << 4);
            float4 t = *(const float4*)(kbt + r * 64 + lc);
            KPs[lc + 0][r] = t.x;
            KPs[lc + 1][r] = t.y;
            KPs[lc + 2][r] = t.z;
            KPs[lc + 3][r] = t.w;
            float4 tv = *(const float4*)(vbt + r * 64 + lc);
            *(float4*)&Vs[r][lc] = tv;
        }
        __syncthreads();

        float s[4][4];
#pragma unroll
        for (int i = 0; i < 4; i++)
#pragma unroll
            for (int j = 0; j < 4; j++) s[i][j] = 0.f;
#pragma unroll 4
        for (int d = 0; d < 64; d++) {
            float qa[4], ka[4];
            *(float4*)qa = *(const float4*)&Qs[d][tr << 2];
            *(float4*)ka = *(const float4*)&KPs[d][tc << 2];
#pragma unroll
            for (int ri = 0; ri < 4; ri++)
#pragma unroll
                for (int ci = 0; ci < 4; ci++)
                    s[ri][ci] = fmaf(qa[ri], ka[ci], s[ri][ci]);
        }
        __syncthreads();

#pragma unroll
        for (int ri = 0; ri < 4; ri++) {
            float tm = fmaxf(fmaxf(s[ri][0], s[ri][1]), fmaxf(s[ri][2], s[ri][3]));
            tm = fmaxf(tm, __shfl_xor(tm, 1, 16));
            tm = fmaxf(tm, __shfl_xor(tm, 2, 16));
            tm = fmaxf(tm, __shfl_xor(tm, 4, 16));
            tm = fmaxf(tm, __shfl_xor(tm, 8, 16));
            const float mn = fmaxf(m[ri], tm);
            const float alpha = __expf(m[ri] - mn);
            const float p0 = __expf(s[ri][0] - mn);
            const float p1 = __expf(s[ri][1] - mn);
            const float p2 = __expf(s[ri][2] - mn);
            const float p3 = __expf(s[ri][3] - mn);
            float rs = (p0 + p1) + (p2 + p3);
            rs += __shfl_xor(rs, 1, 16);
            rs += __shfl_xor(rs, 2, 16);
            rs += __shfl_xor(rs, 4, 16);
            rs += __shfl_xor(rs, 8, 16);
            l[ri] = l[ri] * alpha + rs;
            m[ri] = mn;
            acc[ri][0] *= alpha; acc[ri][1] *= alpha;
            acc[ri][2] *= alpha; acc[ri][3] *= alpha;
            *(float4*)&KPs[(tr << 2) + ri][tc << 2] = make_float4(p0, p1, p2, p3);
        }
        __syncthreads();

#pragma unroll 4
        for (int c = 0; c < 64; c += 4) {
            float pr[4][4], vv[4][4];
            *(float4*)pr[0] = *(const float4*)&KPs[(tr << 2) + 0][c];
            *(float4*)pr[1] = *(const float4*)&KPs[(tr << 2) + 1][c];
            *(float4*)pr[2] = *(const float4*)&KPs[(tr << 2) + 2][c];
            *(float4*)pr[3] = *(const float4*)&KPs[(tr << 2) + 3][c];
            *(float4*)vv[0] = *(const float4*)&Vs[c + 0][tc << 2];
            *(float4*)vv[1] = *(const float4*)&Vs[c + 1][tc << 2];
            *(float4*)vv[2] = *(const float4*)&Vs[c + 2][tc << 2];
            *(float4*)vv[3] = *(const float4*)&Vs[c + 3][tc << 2];
#pragma unroll
            for (int ri = 0; ri < 4; ri++)
#pragma unroll
                for (int j = 0; j < 4; j++) {
                    float a = acc[ri][j];
                    a = fmaf(pr[ri][0], vv[0][j], a);
                    a = fmaf(pr[ri][1], vv[1][j], a);
                    a = fmaf(pr[ri][2], vv[2][j], a);
                    a = fmaf(pr[ri][3], vv[3][j], a);
                    acc[ri][j] = a;
                }
        }
    }

    const int b = bh >> 4, h = bh & 15;
#pragma unroll
    for (int ri = 0; ri < 4; ri++) {
        const float inv = 1.0f / l[ri];
        const int n = q0 + (tr << 2) + ri;
        const size_t idx = (((size_t)b * SEQ + n) << 10) + (h << 6) + (tc << 2);
        *(float4*)&og[idx] = make_float4(acc[ri][0] * inv, acc[ri][1] * inv,
                                         acc[ri][2] * inv, acc[ri][3] * inv);
    }
}

// ===========================================================================
extern "C" void kernel_launch(void* const* d_in, const int* in_sizes, int n_in,
                              void* d_out, int out_size, void* d_ws, size_t ws_size,
                              hipStream_t stream)
{
    const float* x     = (const float*)d_in[0];   // [8,1024,1024]
    const float* w_in  = (const float*)d_in[1];   // [3072,1024]
    const float* b_in  = (const float*)d_in[2];   // [3072]
    const float* w_out = (const float*)d_in[3];   // [1024,1024]
    const float* b_out = (const float*)d_in[4];   // [1024]
    float* out = (float*)d_out;                   // [8,1024,1024]
    (void)in_sizes; (void)n_in; (void)out_size;

    const size_t MB  = 1024 * 1024;
    const size_t per = (size_t)BATCH * HEADS * SEQ * DHEAD;  // 8M elements
    const int    M   = BATCH * SEQ;                          // 8192
    char* ws = (char*)d_ws;

    if (ws_size >= 96 * MB) {
        // --- fp16 MFMA path ---
        f16* qf16  = (f16*)(ws + 0 * MB);    // 16MB [BH][N][64]
        f16* kf16  = (f16*)(ws + 16 * MB);   // 16MB [BH][N][64]
        f16* vtf16 = (f16*)(ws + 32 * MB);   // 16MB [BH][64][N]
        f16* xf16  = (f16*)(ws + 48 * MB);   // 16MB (dead after QKV GEMM)
        f16* of16  = xf16;                   // aliased: born after attention
        f16* wif16 = (f16*)(ws + 64 * MB);   // 6MB
        f16* wof16 = (f16*)(ws + 70 * MB);   // 2MB -> 72MB total

        cvt_all<<<1536, 256, 0, stream>>>(x, w_in, w_out, xf16, wif16, wof16);

        // QKV: r13/r16/r17-verified 3-buffer wide kernel (768 blocks)
        gemm_w3<1><<<dim3(3 * CDIM / 256, M / 128), 256, 0, stream>>>(
            xf16, wif16, b_in, nullptr, qf16, kf16, vtf16, 3 * CDIM, CDIM);

        // attention: QBLK=512 x KVBLK=128, 8 waves (256 blocks, 1 round)
        attn_mfma<<<dim3(SEQ / 512, BATCH * HEADS), 512, 0, stream>>>(
            qf16, kf16, vtf16, of16);

        // out-proj: same 3-buffer wide schedule, MODE 0 (256 blocks)
        gemm_w3<0><<<dim3(CDIM / 256, M / 128), 256, 0, stream>>>(
            of16, wof16, b_out, out, nullptr, nullptr, nullptr, CDIM, CDIM);
    } else {
        // --- fp32 fallback path (128MB) ---
        float* qws = (float*)d_ws;
        float* kws = qws + per;
        float* vws = kws + per;
        float* aws = vws + per;

        gemm_bt<1><<<dim3(3 * CDIM / TILE, M / TILE), 256, 0, stream>>>(
            x, w_in, b_in, nullptr, qws, kws, vws, M, 3 * CDIM, CDIM);

        attn_flash_f32<<<dim3(SEQ / 64, BATCH * HEADS), 256, 0, stream>>>(
            qws, kws, vws, aws);

        gemm_bt<0><<<dim3(CDIM / TILE, M / TILE), 256, 0, stream>>>(
            aws, w_out, b_out, out, nullptr, nullptr, nullptr, M, CDIM, CDIM);
    }
}

// Round 22
// 248.549 us; speedup vs baseline: 1.2508x; 1.0028x over previous
//
#include <hip/hip_runtime.h>
#include <math.h>
#include <stdint.h>

// Problem constants: B=8, N=1024, C=1024, H=16, Dh=64
#define SEQ   1024
#define BATCH 8
#define CDIM  1024
#define HEADS 16
#define DHEAD 64

typedef __bf16 bf16;
typedef _Float16 f16;
typedef __attribute__((ext_vector_type(8))) _Float16 f16x8;
typedef __attribute__((ext_vector_type(4))) float f32x4;

// async global->LDS, 16B per lane. LDS dest = wave-uniform base + lane*16.
static __device__ __forceinline__ void gl16(const void* g, void* l) {
    __builtin_amdgcn_global_load_lds(
        (const __attribute__((address_space(1))) void*)(uintptr_t)g,
        (__attribute__((address_space(3))) void*)(uintptr_t)l,
        16, 0, 0);
}

// ===========================================================================
// cvt_all: fused fp32 -> fp16 for x (1048576 vec8), w_in (393216), w_out
// (131072). One launch instead of three.
// ===========================================================================
__global__ __launch_bounds__(256)
void cvt_all(const float* __restrict__ x,  const float* __restrict__ wi,
             const float* __restrict__ wo, f16* __restrict__ xo,
             f16* __restrict__ wio, f16* __restrict__ woo)
{
    const int N1 = 1048576, N2 = 393216;   // vec8 counts for x, w_in
    const int NT = N1 + N2 + 131072;
    int i = blockIdx.x * blockDim.x + threadIdx.x;
    const int stride = gridDim.x * blockDim.x;
    for (; i < NT; i += stride) {
        const float* src; f16* dst; int off;
        if (i < N1)            { src = x;  dst = xo;  off = i; }
        else if (i < N1 + N2)  { src = wi; dst = wio; off = i - N1; }
        else                   { src = wo; dst = woo; off = i - N1 - N2; }
        const f32x4 v0 = *(const f32x4*)(src + (size_t)off * 8);
        const f32x4 v1 = *(const f32x4*)(src + (size_t)off * 8 + 4);
        f16x8 o;
#pragma unroll
        for (int j = 0; j < 4; j++) {
            o[j]     = (f16)v0[j];
            o[j + 4] = (f16)v1[j];
        }
        *(f16x8*)(dst + (size_t)off * 8) = o;
    }
}

// ===========================================================================
// Wide fp16 MFMA GEMM, 3-buffer counted-vmcnt depth-2 pipeline + setprio
// (r17-r21 verified: QKV 125us).  BM=128 x BN=256, BK=32, 4 waves (2x2),
// per-wave 64x128 (acc[4][8], 32 MFMA/K-step).
// LDS 3x(8KB A + 16KB B) = 72KB -> 2 blocks/CU.
// MODE 0: fp32 row-major store (+bias). MODE 1: QKV scatter as fp16.
// ===========================================================================
template<int MODE>
__global__ __launch_bounds__(256, 2)
void gemm_w3(const f16* __restrict__ Ag, const f16* __restrict__ Bg,
             const float* __restrict__ bias, float* __restrict__ out0,
             f16* __restrict__ qg, f16* __restrict__ kgp,
             f16* __restrict__ vgp, int Ncols, int K)
{
    __shared__ f16 As[3][4][128][8];   // 8KB per buffer; byte = (ks*128+row)*16
    __shared__ f16 Bs[3][4][256][8];   // 16KB per buffer; byte = (ks*256+row)*16

    const int m0 = blockIdx.y * 128;
    const int n0 = blockIdx.x * 256;

    const int tid  = threadIdx.x;
    const int wid  = tid >> 6;
    const int lane = tid & 63;
    const int wr   = (wid >> 1) * 64;    // 0/64 (M)
    const int wc   = (wid & 1) * 128;    // 0/128 (N)
    const int l16  = lane & 15;
    const int kgf  = lane >> 4;

    const int akg = tid >> 7, arow = tid & 127;
    const f16* aP = Ag + (size_t)(m0 + arow) * K + akg * 8;
    const f16* bP = Bg + (size_t)(n0 + tid) * K;
    const int loff = wid << 10;

#define STAGE(buf, kt)                                               \
    do {                                                             \
        gl16(aP + (kt),      (char*)As[buf] + loff);                 \
        gl16(aP + (kt) + 16, (char*)As[buf] + loff + 4096);          \
        gl16(bP + (kt),      (char*)Bs[buf] + loff);                 \
        gl16(bP + (kt) + 8,  (char*)Bs[buf] + loff + 4096);         \
        gl16(bP + (kt) + 16, (char*)Bs[buf] + loff + 8192);         \
        gl16(bP + (kt) + 24, (char*)Bs[buf] + loff + 12288);        \
    } while (0)

#define COMPUTE(buf)                                                         \
    do {                                                                     \
        f16x8 fa[4], fb[8];                                                  \
        _Pragma("unroll")                                                    \
        for (int i = 0; i < 4; i++)                                          \
            fa[i] = *(const f16x8*)&As[buf][kgf][wr + i * 16 + l16][0];      \
        _Pragma("unroll")                                                    \
        for (int j = 0; j < 8; j++)                                          \
            fb[j] = *(const f16x8*)&Bs[buf][kgf][wc + j * 16 + l16][0];      \
        __builtin_amdgcn_s_setprio(1);                                       \
        _Pragma("unroll")                                                    \
        for (int i = 0; i < 4; i++)                                          \
            _Pragma("unroll")                                                \
            for (int j = 0; j < 8; j++)                                      \
                acc[i][j] = __builtin_amdgcn_mfma_f32_16x16x32_f16(          \
                    fa[i], fb[j], acc[i][j], 0, 0, 0);                       \
        __builtin_amdgcn_s_setprio(0);                                       \
    } while (0)

    f32x4 acc[4][8];
#pragma unroll
    for (int i = 0; i < 4; i++)
#pragma unroll
        for (int j = 0; j < 8; j++) acc[i][j] = (f32x4)0.f;

    const int T = K >> 5;   // 32 K-tiles

    STAGE(0, 0);
    STAGE(1, 32);

    int cur = 0;
    for (int t = 0; t < T - 2; t++) {
        const int nbuf = (cur == 0) ? 2 : (cur - 1);   // (t+2) % 3
        STAGE(nbuf, (t + 2) << 5);
        asm volatile("s_waitcnt vmcnt(12)" ::: "memory");  // tile t landed
        __builtin_amdgcn_sched_barrier(0);
        __builtin_amdgcn_s_barrier();
        __builtin_amdgcn_sched_barrier(0);
        COMPUTE(cur);
        __builtin_amdgcn_sched_barrier(0);
        __builtin_amdgcn_s_barrier();
        cur = (cur == 2) ? 0 : (cur + 1);
    }

    asm volatile("s_waitcnt vmcnt(6)" ::: "memory");       // tile T-2 landed
    __builtin_amdgcn_sched_barrier(0);
    __builtin_amdgcn_s_barrier();
    __builtin_amdgcn_sched_barrier(0);
    COMPUTE(cur);
    __builtin_amdgcn_sched_barrier(0);
    __builtin_amdgcn_s_barrier();
    cur = (cur == 2) ? 0 : (cur + 1);

    asm volatile("s_waitcnt vmcnt(0)" ::: "memory");
    __builtin_amdgcn_sched_barrier(0);
    __builtin_amdgcn_s_barrier();
    __builtin_amdgcn_sched_barrier(0);
    COMPUTE(cur);

#undef STAGE
#undef COMPUTE

    // epilogue. D layout (verified r4): col=lane&15, row=(lane>>4)*4+reg.
#pragma unroll
    for (int j = 0; j < 8; j++) {
        const int d  = n0 + wc + j * 16 + l16;
        const float bv = bias[d];
        int s = 0, hh = 0, dh = 0;
        if (MODE == 1) {
            s  = d >> 10;
            hh = (d >> 6) & 15;
            dh = d & 63;
        }
#pragma unroll
        for (int i = 0; i < 4; i++) {
            const int mbase = m0 + wr + i * 16 + (lane >> 4) * 4;
#pragma unroll
            for (int r = 0; r < 4; r++) {
                const float v = acc[i][j][r] + bv;
                const int m = mbase + r;
                if (MODE == 0) {
                    out0[(size_t)m * Ncols + d] = v;
                } else {
                    const int b = m >> 10, n = m & 1023;
                    const size_t bho = (size_t)((b << 4) + hh) << 16;
                    if (s == 0)
                        qg[bho + ((size_t)n << 6) + dh] = (f16)(v * 0.125f);
                    else if (s == 1)
                        kgp[bho + ((size_t)n << 6) + dh] = (f16)v;
                    else
                        vgp[bho + ((size_t)dh << 10) + n] = (f16)v;
                }
            }
        }
    }
}

// ===========================================================================
// MFMA flash attention, QBLK=512 x KVBLK=128, 8 waves (r21 verified) +
// XCD co-location (r22): 1-D grid of 256; decode (bh, half) so the 2 blocks
// sharing one (b,h)'s K/V land on the SAME XCD (lin%8 = XCD under
// round-robin dispatch) -> second block L2-hits the 256KB K/V.
// Bijection: xcd=lin&7, slot=lin>>3; bh=xcd*16+(slot>>1), half=slot&1.
// LDS: Kl 16KB + Vl 16KB + Pl[8][16][136] 34.8KB = 67KB -> 1 block/CU.
// Output plain fp16 O to [B][N][C].
// ===========================================================================
__global__ __launch_bounds__(512, 1)
void attn_mfma(const f16* __restrict__ qf, const f16* __restrict__ kf,
               const f16* __restrict__ vtf, f16* __restrict__ og)
{
    __shared__ f16 Kl[8][128][8];    // [d/8][kcol][8]
    __shared__ f16 Vl[16][64][8];    // [k/8][drow][8]
    __shared__ f16 Pl[8][16][136];   // per-wave P: [qrow][kcol], stride 136

    const int tid  = threadIdx.x;
    const int wid  = tid >> 6;       // 0..7
    const int lane = tid & 63;
    const int l16  = lane & 15;
    const int kg   = lane >> 4;      // 0..3
    // XCD co-location decode: pair (bh, half=0/1) shares lin%8 (same XCD)
    const int lin  = blockIdx.x;
    const int xcd  = lin & 7;
    const int slot = lin >> 3;
    const int bh   = xcd * 16 + (slot >> 1);
    const int q0   = (slot & 1) << 9;   // 512 q-rows per block

    const size_t bhoff = (size_t)bh << 16;   // bh * 1024 * 64
    const f16* qb = qf  + bhoff;
    const f16* kb = kf  + bhoff;
    const f16* vb = vtf + bhoff;

    // Q fragments: group g row = q0 + wid*64 + g*16 + l16
    f16x8 qfr[4][2];
#pragma unroll
    for (int g = 0; g < 4; g++) {
        const f16* qrow = qb + ((size_t)(q0 + wid * 64 + g * 16 + l16) << 6);
        qfr[g][0] = *(const f16x8*)(qrow + kg * 8);
        qfr[g][1] = *(const f16x8*)(qrow + 32 + kg * 8);
    }

    float mrow[4][4], lrow[4][4];
    f32x4 accO[4][4];
#pragma unroll
    for (int g = 0; g < 4; g++)
#pragma unroll
        for (int r = 0; r < 4; r++) {
            mrow[g][r] = -INFINITY; lrow[g][r] = 0.f;
            accO[g][r] = (f32x4)0.f;
        }

    // staging: 1024 chunks of 16B per buffer, 2 per thread (c = tid + 512j)
    f16x8 rk[2], rv[2];
#pragma unroll
    for (int j = 0; j < 2; j++) {
        const int ck = tid + 512 * j;
        rk[j] = *(const f16x8*)(kb + ((size_t)(ck & 127) << 6) + (ck >> 7) * 8);
        rv[j] = *(const f16x8*)(vb + ((size_t)(ck & 63) << 10) + (ck >> 6) * 8);
    }

    for (int kt = 0; kt < 8; kt++) {
        __syncthreads();   // previous iter's K/V fragment reads complete
#pragma unroll
        for (int j = 0; j < 2; j++) {
            const int ck = tid + 512 * j;
            *(f16x8*)&Kl[ck >> 7][ck & 127][0] = rk[j];
            *(f16x8*)&Vl[ck >> 6][ck & 63][0]  = rv[j];
        }
        __syncthreads();

        // issue next tile's global loads; latency hides under compute
        if (kt < 7) {
            const int n1 = (kt + 1) << 7;
#pragma unroll
            for (int j = 0; j < 2; j++) {
                const int ck = tid + 512 * j;
                rk[j] = *(const f16x8*)(kb + ((size_t)(n1 + (ck & 127)) << 6) + (ck >> 7) * 8);
                rv[j] = *(const f16x8*)(vb + ((size_t)(ck & 63) << 10) + n1 + (ck >> 6) * 8);
            }
        }

#pragma unroll
        for (int g = 0; g < 4; g++) {
            // ---- QK^T: group's 16 rows x 128 cols ----
            f32x4 accS[8];
#pragma unroll
            for (int t = 0; t < 8; t++) accS[t] = (f32x4)0.f;
            __builtin_amdgcn_s_setprio(1);
#pragma unroll
            for (int t = 0; t < 8; t++) {
                const f16x8 kf0 = *(const f16x8*)&Kl[kg][t * 16 + l16][0];
                const f16x8 kf1 = *(const f16x8*)&Kl[4 + kg][t * 16 + l16][0];
                accS[t] = __builtin_amdgcn_mfma_f32_16x16x32_f16(qfr[g][0], kf0, accS[t], 0, 0, 0);
                accS[t] = __builtin_amdgcn_mfma_f32_16x16x32_f16(qfr[g][1], kf1, accS[t], 0, 0, 0);
            }
            __builtin_amdgcn_s_setprio(0);

            // ---- online softmax; rows r -> q-row 4*kg + r ----
#pragma unroll
            for (int r = 0; r < 4; r++) {
                float sm = fmaxf(fmaxf(fmaxf(accS[0][r], accS[1][r]),
                                       fmaxf(accS[2][r], accS[3][r])),
                                 fmaxf(fmaxf(accS[4][r], accS[5][r]),
                                       fmaxf(accS[6][r], accS[7][r])));
                sm = fmaxf(sm, __shfl_xor(sm, 1, 16));
                sm = fmaxf(sm, __shfl_xor(sm, 2, 16));
                sm = fmaxf(sm, __shfl_xor(sm, 4, 16));
                sm = fmaxf(sm, __shfl_xor(sm, 8, 16));
                const float mn = fmaxf(mrow[g][r], sm);
                const float al = __expf(mrow[g][r] - mn);
                float p[8], rs = 0.f;
#pragma unroll
                for (int t = 0; t < 8; t++) {
                    p[t] = __expf(accS[t][r] - mn);
                    rs += p[t];
                }
                rs += __shfl_xor(rs, 1, 16);
                rs += __shfl_xor(rs, 2, 16);
                rs += __shfl_xor(rs, 4, 16);
                rs += __shfl_xor(rs, 8, 16);
                lrow[g][r] = lrow[g][r] * al + rs;
                mrow[g][r] = mn;
                accO[g][0][r] *= al;
                accO[g][1][r] *= al;
                accO[g][2][r] *= al;
                accO[g][3][r] *= al;
                const int prow = kg * 4 + r;
#pragma unroll
                for (int t = 0; t < 8; t++)
                    Pl[wid][prow][t * 16 + l16] = (f16)p[t];
            }

            // ---- PV: O(16x64) += P(16x128) * V(128x64) ----
            __builtin_amdgcn_s_setprio(1);
#pragma unroll
            for (int h = 0; h < 4; h++) {
                const f16x8 pa = *(const f16x8*)&Pl[wid][l16][h * 32 + kg * 8];
#pragma unroll
                for (int t = 0; t < 4; t++) {
                    const f16x8 vf = *(const f16x8*)&Vl[h * 4 + kg][t * 16 + l16][0];
                    accO[g][t] = __builtin_amdgcn_mfma_f32_16x16x32_f16(pa, vf, accO[g][t], 0, 0, 0);
                }
            }
            __builtin_amdgcn_s_setprio(0);
        }
    }

    // ---- epilogue: normalize, fp16 store to [B][N][C] ----
    const int b = bh >> 4, hh = bh & 15;
#pragma unroll
    for (int g = 0; g < 4; g++)
#pragma unroll
        for (int r = 0; r < 4; r++) {
            const float inv = 1.0f / lrow[g][r];
            const int n = q0 + wid * 64 + g * 16 + kg * 4 + r;
            const size_t base = ((((size_t)b << 10) + n) << 10) + hh * 64;
#pragma unroll
            for (int t = 0; t < 4; t++)
                og[base + t * 16 + l16] = (f16)(accO[g][t][r] * inv);
        }
}

// ===========================================================================
// Fallback fp32 path (baseline, audited) — used only if ws_size < 96MB.
// ===========================================================================
#define TILE 128
#define KB   16
#define LSTR (TILE + 4)

template<int MODE>
__global__ __launch_bounds__(256, 2)
void gemm_bt(const float* __restrict__ A, const float* __restrict__ Bm,
             const float* __restrict__ bias, float* __restrict__ out0,
             float* __restrict__ qg, float* __restrict__ kg, float* __restrict__ vg,
             int M, int Ncols, int K)
{
    __shared__ float As[KB][LSTR];
    __shared__ float Bs[KB][LSTR];

    const int tid = threadIdx.x;
    const int tr  = tid >> 4;
    const int tc  = tid & 15;
    const int m0  = blockIdx.y * TILE;
    const int n0  = blockIdx.x * TILE;

    const int lrow = tid >> 2;
    const int lcol = (tid & 3) << 2;

    const float* Ap = A  + (size_t)(m0 + lrow) * K + lcol;
    const float* Bp = Bm + (size_t)(n0 + lrow) * K + lcol;
    const size_t rstep = (size_t)64 * K;

    float acc[8][8];
#pragma unroll
    for (int i = 0; i < 8; i++)
#pragma unroll
        for (int j = 0; j < 8; j++) acc[i][j] = 0.f;

    for (int kt = 0; kt < K; kt += KB) {
        float4 a0 = *(const float4*)(Ap + kt);
        float4 a1 = *(const float4*)(Ap + rstep + kt);
        float4 b0 = *(const float4*)(Bp + kt);
        float4 b1 = *(const float4*)(Bp + rstep + kt);
        __syncthreads();
        As[lcol + 0][lrow]      = a0.x;
        As[lcol + 1][lrow]      = a0.y;
        As[lcol + 2][lrow]      = a0.z;
        As[lcol + 3][lrow]      = a0.w;
        As[lcol + 0][lrow + 64] = a1.x;
        As[lcol + 1][lrow + 64] = a1.y;
        As[lcol + 2][lrow + 64] = a1.z;
        As[lcol + 3][lrow + 64] = a1.w;
        Bs[lcol + 0][lrow]      = b0.x;
        Bs[lcol + 1][lrow]      = b0.y;
        Bs[lcol + 2][lrow]      = b0.z;
        Bs[lcol + 3][lrow]      = b0.w;
        Bs[lcol + 0][lrow + 64] = b1.x;
        Bs[lcol + 1][lrow + 64] = b1.y;
        Bs[lcol + 2][lrow + 64] = b1.z;
        Bs[lcol + 3][lrow + 64] = b1.w;
        __syncthreads();
#pragma unroll
        for (int kk = 0; kk < KB; kk++) {
            float ar[8], br[8];
            *(float4*)&ar[0] = *(const float4*)&As[kk][tr << 2];
            *(float4*)&ar[4] = *(const float4*)&As[kk][64 + (tr << 2)];
            *(float4*)&br[0] = *(const float4*)&Bs[kk][tc << 2];
            *(float4*)&br[4] = *(const float4*)&Bs[kk][64 + (tc << 2)];
#pragma unroll
            for (int i = 0; i < 8; i++)
#pragma unroll
                for (int j = 0; j < 8; j++)
                    acc[i][j] = fmaf(ar[i], br[j], acc[i][j]);
        }
    }

#pragma unroll
    for (int rg = 0; rg < 2; rg++) {
#pragma unroll
        for (int ri = 0; ri < 4; ri++) {
            const int m = m0 + rg * 64 + (tr << 2) + ri;
#pragma unroll
            for (int cg = 0; cg < 2; cg++) {
                const int d = n0 + cg * 64 + (tc << 2);
                const float4 bb = *(const float4*)&bias[d];
                float v0 = acc[rg * 4 + ri][cg * 4 + 0] + bb.x;
                float v1 = acc[rg * 4 + ri][cg * 4 + 1] + bb.y;
                float v2 = acc[rg * 4 + ri][cg * 4 + 2] + bb.z;
                float v3 = acc[rg * 4 + ri][cg * 4 + 3] + bb.w;
                if (MODE == 0) {
                    *(float4*)&out0[(size_t)m * Ncols + d] = make_float4(v0, v1, v2, v3);
                } else {
                    const int s  = d >> 10;
                    const int h  = (d >> 6) & 15;
                    const int dh = d & 63;
                    const int b  = m >> 10;
                    const int n  = m & 1023;
                    float* dst = (s == 0) ? qg : ((s == 1) ? kg : vg);
                    if (s == 0) { v0 *= 0.125f; v1 *= 0.125f; v2 *= 0.125f; v3 *= 0.125f; }
                    const size_t idx = (((size_t)((b << 4) + h) << 10) + n) * 64 + dh;
                    *(float4*)&dst[idx] = make_float4(v0, v1, v2, v3);
                }
            }
        }
    }
}

__global__ __launch_bounds__(256, 2)
void attn_flash_f32(const float* __restrict__ qg, const float* __restrict__ kg,
                    const float* __restrict__ vg, float* __restrict__ og)
{
    __shared__ float Qs[64][68];
    __shared__ float KPs[64][68];
    __shared__ float Vs[64][68];

    const int tid = threadIdx.x;
    const int tr  = tid >> 4;
    const int tc  = tid & 15;
    const int bh  = blockIdx.y;
    const int q0  = blockIdx.x << 6;

    const float* qb = qg + ((size_t)bh * SEQ + q0) * DHEAD;
    const float* kb = kg + (size_t)bh * SEQ * DHEAD;
    const float* vb = vg + (size_t)bh * SEQ * DHEAD;

    const int lr = tid >> 4;
    const int lc = (tid & 15) << 2;

#pragma unroll
    for (int i = 0; i < 4; i++) {
        const int r = lr + (i << 4);
        float4 t = *(const float4*)(qb + r * 64 + lc);
        Qs[lc + 0][r] = t.x;
        Qs[lc + 1][r] = t.y;
        Qs[lc + 2][r] = t.z;
        Qs[lc + 3][r] = t.w;
    }

    float m[4], l[4], acc[4][4];
#pragma unroll
    for (int i = 0; i < 4; i++) {
        m[i] = -INFINITY; l[i] = 0.f;
#pragma unroll
        for (int j = 0; j < 4; j++) acc[i][j] = 0.f;
    }

    for (int kt = 0; kt < 16; kt++) {
        __syncthreads();
        const float* kbt = kb + (size_t)(kt << 6) * 64;
        const float* vbt = vb + (size_t)(kt << 6) * 64;
#pragma unroll
        for (int i = 0; i < 4; i++) {
            const int r = lr + (i << 4);
            float4 t = *(const float4*)(kbt + r * 64 + lc);
            KPs[lc + 0][r] = t.x;
            KPs[lc + 1][r] = t.y;
            KPs[lc + 2][r] = t.z;
            KPs[lc + 3][r] = t.w;
            float4 tv = *(const float4*)(vbt + r * 64 + lc);
            *(float4*)&Vs[r][lc] = tv;
        }
        __syncthreads();

        float s[4][4];
#pragma unroll
        for (int i = 0; i < 4; i++)
#pragma unroll
            for (int j = 0; j < 4; j++) s[i][j] = 0.f;
#pragma unroll 4
        for (int d = 0; d < 64; d++) {
            float qa[4], ka[4];
            *(float4*)qa = *(const float4*)&Qs[d][tr << 2];
            *(float4*)ka = *(const float4*)&KPs[d][tc << 2];
#pragma unroll
            for (int ri = 0; ri < 4; ri++)
#pragma unroll
                for (int ci = 0; ci < 4; ci++)
                    s[ri][ci] = fmaf(qa[ri], ka[ci], s[ri][ci]);
        }
        __syncthreads();

#pragma unroll
        for (int ri = 0; ri < 4; ri++) {
            float tm = fmaxf(fmaxf(s[ri][0], s[ri][1]), fmaxf(s[ri][2], s[ri][3]));
            tm = fmaxf(tm, __shfl_xor(tm, 1, 16));
            tm = fmaxf(tm, __shfl_xor(tm, 2, 16));
            tm = fmaxf(tm, __shfl_xor(tm, 4, 16));
            tm = fmaxf(tm, __shfl_xor(tm, 8, 16));
            const float mn = fmaxf(m[ri], tm);
            const float alpha = __expf(m[ri] - mn);
            const float p0 = __expf(s[ri][0] - mn);
            const float p1 = __expf(s[ri][1] - mn);
            const float p2 = __expf(s[ri][2] - mn);
            const float p3 = __expf(s[ri][3] - mn);
            float rs = (p0 + p1) + (p2 + p3);
            rs += __shfl_xor(rs, 1, 16);
            rs += __shfl_xor(rs, 2, 16);
            rs += __shfl_xor(rs, 4, 16);
            rs += __shfl_xor(rs, 8, 16);
            l[ri] = l[ri] * alpha + rs;
            m[ri] = mn;
            acc[ri][0] *= alpha; acc[ri][1] *= alpha;
            acc[ri][2] *= alpha; acc[ri][3] *= alpha;
            *(float4*)&KPs[(tr << 2) + ri][tc << 2] = make_float4(p0, p1, p2, p3);
        }
        __syncthreads();

#pragma unroll 4
        for (int c = 0; c < 64; c += 4) {
            float pr[4][4], vv[4][4];
            *(float4*)pr[0] = *(const float4*)&KPs[(tr << 2) + 0][c];
            *(float4*)pr[1] = *(const float4*)&KPs[(tr << 2) + 1][c];
            *(float4*)pr[2] = *(const float4*)&KPs[(tr << 2) + 2][c];
            *(float4*)pr[3] = *(const float4*)&KPs[(tr << 2) + 3][c];
            *(float4*)vv[0] = *(const float4*)&Vs[c + 0][tc << 2];
            *(float4*)vv[1] = *(const float4*)&Vs[c + 1][tc << 2];
            *(float4*)vv[2] = *(const float4*)&Vs[c + 2][tc << 2];
            *(float4*)vv[3] = *(const float4*)&Vs[c + 3][tc << 2];
#pragma unroll
            for (int ri = 0; ri < 4; ri++)
#pragma unroll
                for (int j = 0; j < 4; j++) {
                    float a = acc[ri][j];
                    a = fmaf(pr[ri][0], vv[0][j], a);
                    a = fmaf(pr[ri][1], vv[1][j], a);
                    a = fmaf(pr[ri][2], vv[2][j], a);
                    a = fmaf(pr[ri][3], vv[3][j], a);
                    acc[ri][j] = a;
                }
        }
    }

    const int b = bh >> 4, h = bh & 15;
#pragma unroll
    for (int ri = 0; ri < 4; ri++) {
        const float inv = 1.0f / l[ri];
        const int n = q0 + (tr << 2) + ri;
        const size_t idx = (((size_t)b * SEQ + n) << 10) + (h << 6) + (tc << 2);
        *(float4*)&og[idx] = make_float4(acc[ri][0] * inv, acc[ri][1] * inv,
                                         acc[ri][2] * inv, acc[ri][3] * inv);
    }
}

// ===========================================================================
extern "C" void kernel_launch(void* const* d_in, const int* in_sizes, int n_in,
                              void* d_out, int out_size, void* d_ws, size_t ws_size,
                              hipStream_t stream)
{
    const float* x     = (const float*)d_in[0];   // [8,1024,1024]
    const float* w_in  = (const float*)d_in[1];   // [3072,1024]
    const float* b_in  = (const float*)d_in[2];   // [3072]
    const float* w_out = (const float*)d_in[3];   // [1024,1024]
    const float* b_out = (const float*)d_in[4];   // [1024]
    float* out = (float*)d_out;                   // [8,1024,1024]
    (void)in_sizes; (void)n_in; (void)out_size;

    const size_t MB  = 1024 * 1024;
    const size_t per = (size_t)BATCH * HEADS * SEQ * DHEAD;  // 8M elements
    const int    M   = BATCH * SEQ;                          // 8192
    char* ws = (char*)d_ws;

    if (ws_size >= 96 * MB) {
        // --- fp16 MFMA path ---
        f16* qf16  = (f16*)(ws + 0 * MB);    // 16MB [BH][N][64]
        f16* kf16  = (f16*)(ws + 16 * MB);   // 16MB [BH][N][64]
        f16* vtf16 = (f16*)(ws + 32 * MB);   // 16MB [BH][64][N]
        f16* xf16  = (f16*)(ws + 48 * MB);   // 16MB (dead after QKV GEMM)
        f16* of16  = xf16;                   // aliased: born after attention
        f16* wif16 = (f16*)(ws + 64 * MB);   // 6MB
        f16* wof16 = (f16*)(ws + 70 * MB);   // 2MB -> 72MB total

        cvt_all<<<1536, 256, 0, stream>>>(x, w_in, w_out, xf16, wif16, wof16);

        // QKV: r13/r16/r17-verified 3-buffer wide kernel (768 blocks)
        gemm_w3<1><<<dim3(3 * CDIM / 256, M / 128), 256, 0, stream>>>(
            xf16, wif16, b_in, nullptr, qf16, kf16, vtf16, 3 * CDIM, CDIM);

        // attention: QBLK=512, 1-D grid 256 with XCD co-location decode
        attn_mfma<<<dim3(256), 512, 0, stream>>>(
            qf16, kf16, vtf16, of16);

        // out-proj: same 3-buffer wide schedule, MODE 0 (256 blocks)
        gemm_w3<0><<<dim3(CDIM / 256, M / 128), 256, 0, stream>>>(
            of16, wof16, b_out, out, nullptr, nullptr, nullptr, CDIM, CDIM);
    } else {
        // --- fp32 fallback path (128MB) ---
        float* qws = (float*)d_ws;
        float* kws = qws + per;
        float* vws = kws + per;
        float* aws = vws + per;

        gemm_bt<1><<<dim3(3 * CDIM / TILE, M / TILE), 256, 0, stream>>>(
            x, w_in, b_in, nullptr, qws, kws, vws, M, 3 * CDIM, CDIM);

        attn_flash_f32<<<dim3(SEQ / 64, BATCH * HEADS), 256, 0, stream>>>(
            qws, kws, vws, aws);

        gemm_bt<0><<<dim3(CDIM / TILE, M / TILE), 256, 0, stream>>>(
            aws, w_out, b_out, out, nullptr, nullptr, nullptr, M, CDIM, CDIM);
    }
}

// Round 23
// 247.241 us; speedup vs baseline: 1.2574x; 1.0053x over previous
//
#include <hip/hip_runtime.h>
#include <math.h>
#include <stdint.h>

// Problem constants: B=8, N=1024, C=1024, H=16, Dh=64
#define SEQ   1024
#define BATCH 8
#define CDIM  1024
#define HEADS 16
#define DHEAD 64

typedef __bf16 bf16;
typedef _Float16 f16;
typedef __attribute__((ext_vector_type(8))) _Float16 f16x8;
typedef __attribute__((ext_vector_type(4))) float f32x4;

// async global->LDS, 16B per lane. LDS dest = wave-uniform base + lane*16.
static __device__ __forceinline__ void gl16(const void* g, void* l) {
    __builtin_amdgcn_global_load_lds(
        (const __attribute__((address_space(1))) void*)(uintptr_t)g,
        (__attribute__((address_space(3))) void*)(uintptr_t)l,
        16, 0, 0);
}

// ===========================================================================
// cvt_all: fused fp32 -> fp16 for x (1048576 vec8), w_in (393216), w_out
// (131072). One launch instead of three.
// ===========================================================================
__global__ __launch_bounds__(256)
void cvt_all(const float* __restrict__ x,  const float* __restrict__ wi,
             const float* __restrict__ wo, f16* __restrict__ xo,
             f16* __restrict__ wio, f16* __restrict__ woo)
{
    const int N1 = 1048576, N2 = 393216;   // vec8 counts for x, w_in
    const int NT = N1 + N2 + 131072;
    int i = blockIdx.x * blockDim.x + threadIdx.x;
    const int stride = gridDim.x * blockDim.x;
    for (; i < NT; i += stride) {
        const float* src; f16* dst; int off;
        if (i < N1)            { src = x;  dst = xo;  off = i; }
        else if (i < N1 + N2)  { src = wi; dst = wio; off = i - N1; }
        else                   { src = wo; dst = woo; off = i - N1 - N2; }
        const f32x4 v0 = *(const f32x4*)(src + (size_t)off * 8);
        const f32x4 v1 = *(const f32x4*)(src + (size_t)off * 8 + 4);
        f16x8 o;
#pragma unroll
        for (int j = 0; j < 4; j++) {
            o[j]     = (f16)v0[j];
            o[j + 4] = (f16)v1[j];
        }
        *(f16x8*)(dst + (size_t)off * 8) = o;
    }
}

// ===========================================================================
// Wide fp16 MFMA GEMM, 3-buffer counted-vmcnt depth-2 pipeline + setprio
// (r13/r16-r22 verified: QKV 125us).  BM=128 x BN=256, BK=32, 4 waves (2x2),
// per-wave 64x128 (acc[4][8], 32 MFMA/K-step).
// LDS 3x(8KB A + 16KB B) = 72KB -> 2 blocks/CU.
// MODE 0: fp32 row-major store (+bias). MODE 1: QKV scatter as fp16.
// ===========================================================================
template<int MODE>
__global__ __launch_bounds__(256, 2)
void gemm_w3(const f16* __restrict__ Ag, const f16* __restrict__ Bg,
             const float* __restrict__ bias, float* __restrict__ out0,
             f16* __restrict__ qg, f16* __restrict__ kgp,
             f16* __restrict__ vgp, int Ncols, int K)
{
    __shared__ f16 As[3][4][128][8];   // 8KB per buffer; byte = (ks*128+row)*16
    __shared__ f16 Bs[3][4][256][8];   // 16KB per buffer; byte = (ks*256+row)*16

    const int m0 = blockIdx.y * 128;
    const int n0 = blockIdx.x * 256;

    const int tid  = threadIdx.x;
    const int wid  = tid >> 6;
    const int lane = tid & 63;
    const int wr   = (wid >> 1) * 64;    // 0/64 (M)
    const int wc   = (wid & 1) * 128;    // 0/128 (N)
    const int l16  = lane & 15;
    const int kgf  = lane >> 4;

    const int akg = tid >> 7, arow = tid & 127;
    const f16* aP = Ag + (size_t)(m0 + arow) * K + akg * 8;
    const f16* bP = Bg + (size_t)(n0 + tid) * K;
    const int loff = wid << 10;

#define STAGE(buf, kt)                                               \
    do {                                                             \
        gl16(aP + (kt),      (char*)As[buf] + loff);                 \
        gl16(aP + (kt) + 16, (char*)As[buf] + loff + 4096);          \
        gl16(bP + (kt),      (char*)Bs[buf] + loff);                 \
        gl16(bP + (kt) + 8,  (char*)Bs[buf] + loff + 4096);         \
        gl16(bP + (kt) + 16, (char*)Bs[buf] + loff + 8192);         \
        gl16(bP + (kt) + 24, (char*)Bs[buf] + loff + 12288);        \
    } while (0)

#define COMPUTE(buf)                                                         \
    do {                                                                     \
        f16x8 fa[4], fb[8];                                                  \
        _Pragma("unroll")                                                    \
        for (int i = 0; i < 4; i++)                                          \
            fa[i] = *(const f16x8*)&As[buf][kgf][wr + i * 16 + l16][0];      \
        _Pragma("unroll")                                                    \
        for (int j = 0; j < 8; j++)                                          \
            fb[j] = *(const f16x8*)&Bs[buf][kgf][wc + j * 16 + l16][0];      \
        __builtin_amdgcn_s_setprio(1);                                       \
        _Pragma("unroll")                                                    \
        for (int i = 0; i < 4; i++)                                          \
            _Pragma("unroll")                                                \
            for (int j = 0; j < 8; j++)                                      \
                acc[i][j] = __builtin_amdgcn_mfma_f32_16x16x32_f16(          \
                    fa[i], fb[j], acc[i][j], 0, 0, 0);                       \
        __builtin_amdgcn_s_setprio(0);                                       \
    } while (0)

    f32x4 acc[4][8];
#pragma unroll
    for (int i = 0; i < 4; i++)
#pragma unroll
        for (int j = 0; j < 8; j++) acc[i][j] = (f32x4)0.f;

    const int T = K >> 5;   // 32 K-tiles

    STAGE(0, 0);
    STAGE(1, 32);

    int cur = 0;
    for (int t = 0; t < T - 2; t++) {
        const int nbuf = (cur == 0) ? 2 : (cur - 1);   // (t+2) % 3
        STAGE(nbuf, (t + 2) << 5);
        asm volatile("s_waitcnt vmcnt(12)" ::: "memory");  // tile t landed
        __builtin_amdgcn_sched_barrier(0);
        __builtin_amdgcn_s_barrier();
        __builtin_amdgcn_sched_barrier(0);
        COMPUTE(cur);
        __builtin_amdgcn_sched_barrier(0);
        __builtin_amdgcn_s_barrier();
        cur = (cur == 2) ? 0 : (cur + 1);
    }

    asm volatile("s_waitcnt vmcnt(6)" ::: "memory");       // tile T-2 landed
    __builtin_amdgcn_sched_barrier(0);
    __builtin_amdgcn_s_barrier();
    __builtin_amdgcn_sched_barrier(0);
    COMPUTE(cur);
    __builtin_amdgcn_sched_barrier(0);
    __builtin_amdgcn_s_barrier();
    cur = (cur == 2) ? 0 : (cur + 1);

    asm volatile("s_waitcnt vmcnt(0)" ::: "memory");
    __builtin_amdgcn_sched_barrier(0);
    __builtin_amdgcn_s_barrier();
    __builtin_amdgcn_sched_barrier(0);
    COMPUTE(cur);

#undef STAGE
#undef COMPUTE

    // epilogue. D layout (verified r4): col=lane&15, row=(lane>>4)*4+reg.
#pragma unroll
    for (int j = 0; j < 8; j++) {
        const int d  = n0 + wc + j * 16 + l16;
        const float bv = bias[d];
        int s = 0, hh = 0, dh = 0;
        if (MODE == 1) {
            s  = d >> 10;
            hh = (d >> 6) & 15;
            dh = d & 63;
        }
#pragma unroll
        for (int i = 0; i < 4; i++) {
            const int mbase = m0 + wr + i * 16 + (lane >> 4) * 4;
#pragma unroll
            for (int r = 0; r < 4; r++) {
                const float v = acc[i][j][r] + bv;
                const int m = mbase + r;
                if (MODE == 0) {
                    out0[(size_t)m * Ncols + d] = v;
                } else {
                    const int b = m >> 10, n = m & 1023;
                    const size_t bho = (size_t)((b << 4) + hh) << 16;
                    if (s == 0)
                        qg[bho + ((size_t)n << 6) + dh] = (f16)(v * 0.125f);
                    else if (s == 1)
                        kgp[bho + ((size_t)n << 6) + dh] = (f16)v;
                    else
                        vgp[bho + ((size_t)dh << 10) + n] = (f16)v;
                }
            }
        }
    }
}

// ===========================================================================
// MFMA flash attention, QBLK=512 x KVBLK=128, 8 waves + XCD co-location
// (r21/r22 verified).  1-D grid of 256; decode (bh, half) so the 2 blocks
// sharing one (b,h)'s K/V land on the SAME XCD (lin%8 = XCD under
// round-robin dispatch).  Each wave owns 4 groups of 16 q-rows (static
// unroll).  fp16 MFMA QK^T/PV, fp32 online softmax, setprio.
// LDS: Kl 16KB + Vl 16KB + Pl[8][16][136] 34.8KB = 67KB -> 1 block/CU.
// Output plain fp16 O to [B][N][C].
// ===========================================================================
__global__ __launch_bounds__(512, 1)
void attn_mfma(const f16* __restrict__ qf, const f16* __restrict__ kf,
               const f16* __restrict__ vtf, f16* __restrict__ og)
{
    __shared__ f16 Kl[8][128][8];    // [d/8][kcol][8]
    __shared__ f16 Vl[16][64][8];    // [k/8][drow][8]
    __shared__ f16 Pl[8][16][136];   // per-wave P: [qrow][kcol], stride 136

    const int tid  = threadIdx.x;
    const int wid  = tid >> 6;       // 0..7
    const int lane = tid & 63;
    const int l16  = lane & 15;
    const int kg   = lane >> 4;      // 0..3
    // XCD co-location decode: pair (bh, half=0/1) shares lin%8 (same XCD)
    const int lin  = blockIdx.x;
    const int xcd  = lin & 7;
    const int slot = lin >> 3;
    const int bh   = xcd * 16 + (slot >> 1);
    const int q0   = (slot & 1) << 9;   // 512 q-rows per block

    const size_t bhoff = (size_t)bh << 16;   // bh * 1024 * 64
    const f16* qb = qf  + bhoff;
    const f16* kb = kf  + bhoff;
    const f16* vb = vtf + bhoff;

    // Q fragments: group g row = q0 + wid*64 + g*16 + l16
    f16x8 qfr[4][2];
#pragma unroll
    for (int g = 0; g < 4; g++) {
        const f16* qrow = qb + ((size_t)(q0 + wid * 64 + g * 16 + l16) << 6);
        qfr[g][0] = *(const f16x8*)(qrow + kg * 8);
        qfr[g][1] = *(const f16x8*)(qrow + 32 + kg * 8);
    }

    float mrow[4][4], lrow[4][4];
    f32x4 accO[4][4];
#pragma unroll
    for (int g = 0; g < 4; g++)
#pragma unroll
        for (int r = 0; r < 4; r++) {
            mrow[g][r] = -INFINITY; lrow[g][r] = 0.f;
            accO[g][r] = (f32x4)0.f;
        }

    // staging: 1024 chunks of 16B per buffer, 2 per thread (c = tid + 512j)
    f16x8 rk[2], rv[2];
#pragma unroll
    for (int j = 0; j < 2; j++) {
        const int ck = tid + 512 * j;
        rk[j] = *(const f16x8*)(kb + ((size_t)(ck & 127) << 6) + (ck >> 7) * 8);
        rv[j] = *(const f16x8*)(vb + ((size_t)(ck & 63) << 10) + (ck >> 6) * 8);
    }

    for (int kt = 0; kt < 8; kt++) {
        __syncthreads();   // previous iter's K/V fragment reads complete
#pragma unroll
        for (int j = 0; j < 2; j++) {
            const int ck = tid + 512 * j;
            *(f16x8*)&Kl[ck >> 7][ck & 127][0] = rk[j];
            *(f16x8*)&Vl[ck >> 6][ck & 63][0]  = rv[j];
        }
        __syncthreads();

        // issue next tile's global loads; latency hides under compute
        if (kt < 7) {
            const int n1 = (kt + 1) << 7;
#pragma unroll
            for (int j = 0; j < 2; j++) {
                const int ck = tid + 512 * j;
                rk[j] = *(const f16x8*)(kb + ((size_t)(n1 + (ck & 127)) << 6) + (ck >> 7) * 8);
                rv[j] = *(const f16x8*)(vb + ((size_t)(ck & 63) << 10) + n1 + (ck >> 6) * 8);
            }
        }

#pragma unroll
        for (int g = 0; g < 4; g++) {
            // ---- QK^T: group's 16 rows x 128 cols ----
            f32x4 accS[8];
#pragma unroll
            for (int t = 0; t < 8; t++) accS[t] = (f32x4)0.f;
            __builtin_amdgcn_s_setprio(1);
#pragma unroll
            for (int t = 0; t < 8; t++) {
                const f16x8 kf0 = *(const f16x8*)&Kl[kg][t * 16 + l16][0];
                const f16x8 kf1 = *(const f16x8*)&Kl[4 + kg][t * 16 + l16][0];
                accS[t] = __builtin_amdgcn_mfma_f32_16x16x32_f16(qfr[g][0], kf0, accS[t], 0, 0, 0);
                accS[t] = __builtin_amdgcn_mfma_f32_16x16x32_f16(qfr[g][1], kf1, accS[t], 0, 0, 0);
            }
            __builtin_amdgcn_s_setprio(0);

            // ---- online softmax; rows r -> q-row 4*kg + r ----
#pragma unroll
            for (int r = 0; r < 4; r++) {
                float sm = fmaxf(fmaxf(fmaxf(accS[0][r], accS[1][r]),
                                       fmaxf(accS[2][r], accS[3][r])),
                                 fmaxf(fmaxf(accS[4][r], accS[5][r]),
                                       fmaxf(accS[6][r], accS[7][r])));
                sm = fmaxf(sm, __shfl_xor(sm, 1, 16));
                sm = fmaxf(sm, __shfl_xor(sm, 2, 16));
                sm = fmaxf(sm, __shfl_xor(sm, 4, 16));
                sm = fmaxf(sm, __shfl_xor(sm, 8, 16));
                const float mn = fmaxf(mrow[g][r], sm);
                const float al = __expf(mrow[g][r] - mn);
                float p[8], rs = 0.f;
#pragma unroll
                for (int t = 0; t < 8; t++) {
                    p[t] = __expf(accS[t][r] - mn);
                    rs += p[t];
                }
                rs += __shfl_xor(rs, 1, 16);
                rs += __shfl_xor(rs, 2, 16);
                rs += __shfl_xor(rs, 4, 16);
                rs += __shfl_xor(rs, 8, 16);
                lrow[g][r] = lrow[g][r] * al + rs;
                mrow[g][r] = mn;
                accO[g][0][r] *= al;
                accO[g][1][r] *= al;
                accO[g][2][r] *= al;
                accO[g][3][r] *= al;
                const int prow = kg * 4 + r;
#pragma unroll
                for (int t = 0; t < 8; t++)
                    Pl[wid][prow][t * 16 + l16] = (f16)p[t];
            }

            // ---- PV: O(16x64) += P(16x128) * V(128x64) ----
            __builtin_amdgcn_s_setprio(1);
#pragma unroll
            for (int h = 0; h < 4; h++) {
                const f16x8 pa = *(const f16x8*)&Pl[wid][l16][h * 32 + kg * 8];
#pragma unroll
                for (int t = 0; t < 4; t++) {
                    const f16x8 vf = *(const f16x8*)&Vl[h * 4 + kg][t * 16 + l16][0];
                    accO[g][t] = __builtin_amdgcn_mfma_f32_16x16x32_f16(pa, vf, accO[g][t], 0, 0, 0);
                }
            }
            __builtin_amdgcn_s_setprio(0);
        }
    }

    // ---- epilogue: normalize, fp16 store to [B][N][C] ----
    const int b = bh >> 4, hh = bh & 15;
#pragma unroll
    for (int g = 0; g < 4; g++)
#pragma unroll
        for (int r = 0; r < 4; r++) {
            const float inv = 1.0f / lrow[g][r];
            const int n = q0 + wid * 64 + g * 16 + kg * 4 + r;
            const size_t base = ((((size_t)b << 10) + n) << 10) + hh * 64;
#pragma unroll
            for (int t = 0; t < 4; t++)
                og[base + t * 16 + l16] = (f16)(accO[g][t][r] * inv);
        }
}

// ===========================================================================
// Fallback fp32 path (baseline, audited) — used only if ws_size < 96MB.
// ===========================================================================
#define TILE 128
#define KB   16
#define LSTR (TILE + 4)

template<int MODE>
__global__ __launch_bounds__(256, 2)
void gemm_bt(const float* __restrict__ A, const float* __restrict__ Bm,
             const float* __restrict__ bias, float* __restrict__ out0,
             float* __restrict__ qg, float* __restrict__ kg, float* __restrict__ vg,
             int M, int Ncols, int K)
{
    __shared__ float As[KB][LSTR];
    __shared__ float Bs[KB][LSTR];

    const int tid = threadIdx.x;
    const int tr  = tid >> 4;
    const int tc  = tid & 15;
    const int m0  = blockIdx.y * TILE;
    const int n0  = blockIdx.x * TILE;

    const int lrow = tid >> 2;
    const int lcol = (tid & 3) << 2;

    const float* Ap = A  + (size_t)(m0 + lrow) * K + lcol;
    const float* Bp = Bm + (size_t)(n0 + lrow) * K + lcol;
    const size_t rstep = (size_t)64 * K;

    float acc[8][8];
#pragma unroll
    for (int i = 0; i < 8; i++)
#pragma unroll
        for (int j = 0; j < 8; j++) acc[i][j] = 0.f;

    for (int kt = 0; kt < K; kt += KB) {
        float4 a0 = *(const float4*)(Ap + kt);
        float4 a1 = *(const float4*)(Ap + rstep + kt);
        float4 b0 = *(const float4*)(Bp + kt);
        float4 b1 = *(const float4*)(Bp + rstep + kt);
        __syncthreads();
        As[lcol + 0][lrow]      = a0.x;
        As[lcol + 1][lrow]      = a0.y;
        As[lcol + 2][lrow]      = a0.z;
        As[lcol + 3][lrow]      = a0.w;
        As[lcol + 0][lrow + 64] = a1.x;
        As[lcol + 1][lrow + 64] = a1.y;
        As[lcol + 2][lrow + 64] = a1.z;
        As[lcol + 3][lrow + 64] = a1.w;
        Bs[lcol + 0][lrow]      = b0.x;
        Bs[lcol + 1][lrow]      = b0.y;
        Bs[lcol + 2][lrow]      = b0.z;
        Bs[lcol + 3][lrow]      = b0.w;
        Bs[lcol + 0][lrow + 64] = b1.x;
        Bs[lcol + 1][lrow + 64] = b1.y;
        Bs[lcol + 2][lrow + 64] = b1.z;
        Bs[lcol + 3][lrow + 64] = b1.w;
        __syncthreads();
#pragma unroll
        for (int kk = 0; kk < KB; kk++) {
            float ar[8], br[8];
            *(float4*)&ar[0] = *(const float4*)&As[kk][tr << 2];
            *(float4*)&ar[4] = *(const float4*)&As[kk][64 + (tr << 2)];
            *(float4*)&br[0] = *(const float4*)&Bs[kk][tc << 2];
            *(float4*)&br[4] = *(const float4*)&Bs[kk][64 + (tc << 2)];
#pragma unroll
            for (int i = 0; i < 8; i++)
#pragma unroll
                for (int j = 0; j < 8; j++)
                    acc[i][j] = fmaf(ar[i], br[j], acc[i][j]);
        }
    }

#pragma unroll
    for (int rg = 0; rg < 2; rg++) {
#pragma unroll
        for (int ri = 0; ri < 4; ri++) {
            const int m = m0 + rg * 64 + (tr << 2) + ri;
#pragma unroll
            for (int cg = 0; cg < 2; cg++) {
                const int d = n0 + cg * 64 + (tc << 2);
                const float4 bb = *(const float4*)&bias[d];
                float v0 = acc[rg * 4 + ri][cg * 4 + 0] + bb.x;
                float v1 = acc[rg * 4 + ri][cg * 4 + 1] + bb.y;
                float v2 = acc[rg * 4 + ri][cg * 4 + 2] + bb.z;
                float v3 = acc[rg * 4 + ri][cg * 4 + 3] + bb.w;
                if (MODE == 0) {
                    *(float4*)&out0[(size_t)m * Ncols + d] = make_float4(v0, v1, v2, v3);
                } else {
                    const int s  = d >> 10;
                    const int h  = (d >> 6) & 15;
                    const int dh = d & 63;
                    const int b  = m >> 10;
                    const int n  = m & 1023;
                    float* dst = (s == 0) ? qg : ((s == 1) ? kg : vg);
                    if (s == 0) { v0 *= 0.125f; v1 *= 0.125f; v2 *= 0.125f; v3 *= 0.125f; }
                    const size_t idx = (((size_t)((b << 4) + h) << 10) + n) * 64 + dh;
                    *(float4*)&dst[idx] = make_float4(v0, v1, v2, v3);
                }
            }
        }
    }
}

__global__ __launch_bounds__(256, 2)
void attn_flash_f32(const float* __restrict__ qg, const float* __restrict__ kg,
                    const float* __restrict__ vg, float* __restrict__ og)
{
    __shared__ float Qs[64][68];
    __shared__ float KPs[64][68];
    __shared__ float Vs[64][68];

    const int tid = threadIdx.x;
    const int tr  = tid >> 4;
    const int tc  = tid & 15;
    const int bh  = blockIdx.y;
    const int q0  = blockIdx.x << 6;

    const float* qb = qg + ((size_t)bh * SEQ + q0) * DHEAD;
    const float* kb = kg + (size_t)bh * SEQ * DHEAD;
    const float* vb = vg + (size_t)bh * SEQ * DHEAD;

    const int lr = tid >> 4;
    const int lc = (tid & 15) << 2;

#pragma unroll
    for (int i = 0; i < 4; i++) {
        const int r = lr + (i << 4);
        float4 t = *(const float4*)(qb + r * 64 + lc);
        Qs[lc + 0][r] = t.x;
        Qs[lc + 1][r] = t.y;
        Qs[lc + 2][r] = t.z;
        Qs[lc + 3][r] = t.w;
    }

    float m[4], l[4], acc[4][4];
#pragma unroll
    for (int i = 0; i < 4; i++) {
        m[i] = -INFINITY; l[i] = 0.f;
#pragma unroll
        for (int j = 0; j < 4; j++) acc[i][j] = 0.f;
    }

    for (int kt = 0; kt < 16; kt++) {
        __syncthreads();
        const float* kbt = kb + (size_t)(kt << 6) * 64;
        const float* vbt = vb + (size_t)(kt << 6) * 64;
#pragma unroll
        for (int i = 0; i < 4; i++) {
            const int r = lr + (i << 4);
            float4 t = *(const float4*)(kbt + r * 64 + lc);
            KPs[lc + 0][r] = t.x;
            KPs[lc + 1][r] = t.y;
            KPs[lc + 2][r] = t.z;
            KPs[lc + 3][r] = t.w;
            float4 tv = *(const float4*)(vbt + r * 64 + lc);
            *(float4*)&Vs[r][lc] = tv;
        }
        __syncthreads();

        float s[4][4];
#pragma unroll
        for (int i = 0; i < 4; i++)
#pragma unroll
            for (int j = 0; j < 4; j++) s[i][j] = 0.f;
#pragma unroll 4
        for (int d = 0; d < 64; d++) {
            float qa[4], ka[4];
            *(float4*)qa = *(const float4*)&Qs[d][tr << 2];
            *(float4*)ka = *(const float4*)&KPs[d][tc << 2];
#pragma unroll
            for (int ri = 0; ri < 4; ri++)
#pragma unroll
                for (int ci = 0; ci < 4; ci++)
                    s[ri][ci] = fmaf(qa[ri], ka[ci], s[ri][ci]);
        }
        __syncthreads();

#pragma unroll
        for (int ri = 0; ri < 4; ri++) {
            float tm = fmaxf(fmaxf(s[ri][0], s[ri][1]), fmaxf(s[ri][2], s[ri][3]));
            tm = fmaxf(tm, __shfl_xor(tm, 1, 16));
            tm = fmaxf(tm, __shfl_xor(tm, 2, 16));
            tm = fmaxf(tm, __shfl_xor(tm, 4, 16));
            tm = fmaxf(tm, __shfl_xor(tm, 8, 16));
            const float mn = fmaxf(m[ri], tm);
            const float alpha = __expf(m[ri] - mn);
            const float p0 = __expf(s[ri][0] - mn);
            const float p1 = __expf(s[ri][1] - mn);
            const float p2 = __expf(s[ri][2] - mn);
            const float p3 = __expf(s[ri][3] - mn);
            float rs = (p0 + p1) + (p2 + p3);
            rs += __shfl_xor(rs, 1, 16);
            rs += __shfl_xor(rs, 2, 16);
            rs += __shfl_xor(rs, 4, 16);
            rs += __shfl_xor(rs, 8, 16);
            l[ri] = l[ri] * alpha + rs;
            m[ri] = mn;
            acc[ri][0] *= alpha; acc[ri][1] *= alpha;
            acc[ri][2] *= alpha; acc[ri][3] *= alpha;
            *(float4*)&KPs[(tr << 2) + ri][tc << 2] = make_float4(p0, p1, p2, p3);
        }
        __syncthreads();

#pragma unroll 4
        for (int c = 0; c < 64; c += 4) {
            float pr[4][4], vv[4][4];
            *(float4*)pr[0] = *(const float4*)&KPs[(tr << 2) + 0][c];
            *(float4*)pr[1] = *(const float4*)&KPs[(tr << 2) + 1][c];
            *(float4*)pr[2] = *(const float4*)&KPs[(tr << 2) + 2][c];
            *(float4*)pr[3] = *(const float4*)&KPs[(tr << 2) + 3][c];
            *(float4*)vv[0] = *(const float4*)&Vs[c + 0][tc << 2];
            *(float4*)vv[1] = *(const float4*)&Vs[c + 1][tc << 2];
            *(float4*)vv[2] = *(const float4*)&Vs[c + 2][tc << 2];
            *(float4*)vv[3] = *(const float4*)&Vs[c + 3][tc << 2];
#pragma unroll
            for (int ri = 0; ri < 4; ri++)
#pragma unroll
                for (int j = 0; j < 4; j++) {
                    float a = acc[ri][j];
                    a = fmaf(pr[ri][0], vv[0][j], a);
                    a = fmaf(pr[ri][1], vv[1][j], a);
                    a = fmaf(pr[ri][2], vv[2][j], a);
                    a = fmaf(pr[ri][3], vv[3][j], a);
                    acc[ri][j] = a;
                }
        }
    }

    const int b = bh >> 4, h = bh & 15;
#pragma unroll
    for (int ri = 0; ri < 4; ri++) {
        const float inv = 1.0f / l[ri];
        const int n = q0 + (tr << 2) + ri;
        const size_t idx = (((size_t)b * SEQ + n) << 10) + (h << 6) + (tc << 2);
        *(float4*)&og[idx] = make_float4(acc[ri][0] * inv, acc[ri][1] * inv,
                                         acc[ri][2] * inv, acc[ri][3] * inv);
    }
}

// ===========================================================================
extern "C" void kernel_launch(void* const* d_in, const int* in_sizes, int n_in,
                              void* d_out, int out_size, void* d_ws, size_t ws_size,
                              hipStream_t stream)
{
    const float* x     = (const float*)d_in[0];   // [8,1024,1024]
    const float* w_in  = (const float*)d_in[1];   // [3072,1024]
    const float* b_in  = (const float*)d_in[2];   // [3072]
    const float* w_out = (const float*)d_in[3];   // [1024,1024]
    const float* b_out = (const float*)d_in[4];   // [1024]
    float* out = (float*)d_out;                   // [8,1024,1024]
    (void)in_sizes; (void)n_in; (void)out_size;

    const size_t MB  = 1024 * 1024;
    const size_t per = (size_t)BATCH * HEADS * SEQ * DHEAD;  // 8M elements
    const int    M   = BATCH * SEQ;                          // 8192
    char* ws = (char*)d_ws;

    if (ws_size >= 96 * MB) {
        // --- fp16 MFMA path ---
        f16* qf16  = (f16*)(ws + 0 * MB);    // 16MB [BH][N][64]
        f16* kf16  = (f16*)(ws + 16 * MB);   // 16MB [BH][N][64]
        f16* vtf16 = (f16*)(ws + 32 * MB);   // 16MB [BH][64][N]
        f16* xf16  = (f16*)(ws + 48 * MB);   // 16MB (dead after QKV GEMM)
        f16* of16  = xf16;                   // aliased: born after attention
        f16* wif16 = (f16*)(ws + 64 * MB);   // 6MB
        f16* wof16 = (f16*)(ws + 70 * MB);   // 2MB -> 72MB total

        cvt_all<<<1536, 256, 0, stream>>>(x, w_in, w_out, xf16, wif16, wof16);

        // QKV: r13/r16-r22-verified 3-buffer wide kernel (768 blocks)
        gemm_w3<1><<<dim3(3 * CDIM / 256, M / 128), 256, 0, stream>>>(
            xf16, wif16, b_in, nullptr, qf16, kf16, vtf16, 3 * CDIM, CDIM);

        // attention: QBLK=512, 1-D grid 256 with XCD co-location decode
        attn_mfma<<<dim3(256), 512, 0, stream>>>(
            qf16, kf16, vtf16, of16);

        // out-proj: same 3-buffer wide schedule, MODE 0 (256 blocks)
        gemm_w3<0><<<dim3(CDIM / 256, M / 128), 256, 0, stream>>>(
            of16, wof16, b_out, out, nullptr, nullptr, nullptr, CDIM, CDIM);
    } else {
        // --- fp32 fallback path (128MB) ---
        float* qws = (float*)d_ws;
        float* kws = qws + per;
        float* vws = kws + per;
        float* aws = vws + per;

        gemm_bt<1><<<dim3(3 * CDIM / TILE, M / TILE), 256, 0, stream>>>(
            x, w_in, b_in, nullptr, qws, kws, vws, M, 3 * CDIM, CDIM);

        attn_flash_f32<<<dim3(SEQ / 64, BATCH * HEADS), 256, 0, stream>>>(
            qws, kws, vws, aws);

        gemm_bt<0><<<dim3(CDIM / TILE, M / TILE), 256, 0, stream>>>(
            aws, w_out, b_out, out, nullptr, nullptr, nullptr, M, CDIM, CDIM);
    }
}